// Round 5
// baseline (1100.051 us; speedup 1.0000x reference)
//
#include <hip/hip_runtime.h>
#include <math.h>

#define B_ 4
#define N_ 4096
#define D_ 1024
#define H_ 16
#define DH_ 64
#define M_ 266
#define MP_ 320   // M padded to 5 chunks of 64

#define DN_ 0.35355339059327373f      // 64^-0.25
#define RATIO_ 0.06131393394849658f   // 266^-0.5
#define EPS_ 1e-4f
#define KP_ 72    // ushort row stride
#define NSPLIT_ 16
#define PARTSZ_ ((size_t)64 * M_ * 64)   // one C_u partial (all bh)

typedef __attribute__((ext_vector_type(8))) short bfrag;
typedef __attribute__((ext_vector_type(4))) float f4;

__device__ __forceinline__ unsigned f2ord(float f) {
    unsigned u = __float_as_uint(f);
    return (u & 0x80000000u) ? ~u : (u | 0x80000000u);
}
__device__ __forceinline__ float ord2f(unsigned u) {
    unsigned b = (u & 0x80000000u) ? (u & 0x7fffffffu) : ~u;
    return __uint_as_float(b);
}

__global__ void zero_kernel(float* __restrict__ p, int n) {
    int i = blockIdx.x * 256 + threadIdx.x;
    if (i < n) p[i] = 0.f;
}

__device__ __forceinline__ void split2pack(float x, float y, unsigned* hp, unsigned* lp) {
    unsigned ux = __float_as_uint(x), uy = __float_as_uint(y);
    float hx = __uint_as_float(ux & 0xffff0000u);
    float hy = __uint_as_float(uy & 0xffff0000u);
    float lx = x - hx, ly = y - hy;
    *hp = (ux >> 16) | (uy & 0xffff0000u);
    *lp = (__float_as_uint(lx) >> 16) | (__float_as_uint(ly) & 0xffff0000u);
}
__device__ __forceinline__ unsigned short bf16rne(float x) {
    unsigned u = __float_as_uint(x);
    return (unsigned short)((u + 0x7fffu + ((u >> 16) & 1u)) >> 16);
}

// async global->LDS 16B (dwordx4). LDS dst must be wave-uniform; lane writes dst+lane*16.
__device__ __forceinline__ void async_cp16(const void* g, void* l) {
    __builtin_amdgcn_global_load_lds(
        (const __attribute__((address_space(1))) void*)g,
        (__attribute__((address_space(3))) void*)l, 16, 0, 0);
}

// ---------------- one-shot split conversions (each element converted exactly once) --------
__global__ __launch_bounds__(256) void split_f32(const float* __restrict__ X,
        unsigned short* __restrict__ Xh, unsigned short* __restrict__ Xl, int n4)
{
    int i = blockIdx.x * 256 + threadIdx.x;
    if (i >= n4) return;
    const float4 v = ((const float4*)X)[i];
    unsigned h0, l0, h1, l1;
    split2pack(v.x, v.y, &h0, &l0);
    split2pack(v.z, v.w, &h1, &l1);
    ((uint2*)Xh)[i] = make_uint2(h0, h1);
    ((uint2*)Xl)[i] = make_uint2(l0, l1);
}

// 5 weights (1024x1024 each) -> Wsp: per sel, h at sel*2097152, l at +1048576 (ushort units)
__global__ __launch_bounds__(256) void split_w5(const float* __restrict__ W0,
        const float* __restrict__ W1, const float* __restrict__ W2,
        const float* __restrict__ W3, const float* __restrict__ W4,
        unsigned short* __restrict__ Wsp)
{
    int sel = blockIdx.y;
    const float* W = (sel == 0) ? W0 : (sel == 1) ? W1 : (sel == 2) ? W2 : (sel == 3) ? W3 : W4;
    unsigned short* h = Wsp + (size_t)sel * 2097152;
    unsigned short* l = h + 1048576;
    int i = blockIdx.x * 256 + threadIdx.x;   // 1024*256 threads * 4 elems = 1048576
    const float4 v = ((const float4*)W)[i];
    unsigned h0, l0, h1, l1;
    split2pack(v.x, v.y, &h0, &l0);
    split2pack(v.z, v.w, &h1, &l1);
    ((uint2*)h)[i] = make_uint2(h0, h1);
    ((uint2*)l)[i] = make_uint2(l0, l1);
}

// ---------------- fused QKV GEMM: pure-HIP 2-phase pipeline --------------------------------
// T3 minimum recipe with __syncthreads only (vmcnt(0)+lgkmcnt(0)+barrier == recipe's tile-end
// wait): STAGE(t+1) issued BEFORE tile-t compute so the end-of-tile drain overlaps 48 MFMAs.
// LDS 16B-granule swizzle (conflict-free ds_read): granule (row,slot) at slot^((row>>1)&3);
// write side = linear LDS dst + pre-swizzled GLOBAL source slot (ksw), read side = slot8.
__global__ __launch_bounds__(256) void gemm_qkv_s(
        const unsigned short* __restrict__ Ah, const unsigned short* __restrict__ Al,
        const unsigned short* __restrict__ Wsp,
        const float* __restrict__ b0, const float* __restrict__ b1, const float* __restrict__ b2,
        float* __restrict__ C0, float* __restrict__ C1, float* __restrict__ C2)
{
    __shared__ __align__(16) unsigned short Ahs[2][128 * 32];
    __shared__ __align__(16) unsigned short Als[2][128 * 32];
    __shared__ __align__(16) unsigned short Bhs[2][128 * 32];
    __shared__ __align__(16) unsigned short Bls[2][128 * 32];

    int tid = threadIdx.x;
    int sel = blockIdx.x >> 3;               // 0..2 -> q,k,v
    int bn = (blockIdx.x & 7) * 128;
    int bm = blockIdx.y * 128;
    const unsigned short* Bh = Wsp + (size_t)sel * 2097152;
    const unsigned short* Bl = Bh + 1048576;
    const float* bias = (sel == 0) ? b0 : (sel == 1) ? b1 : b2;
    float* C = (sel == 0) ? C0 : (sel == 1) ? C1 : C2;

    int lane = tid & 63;
    int w = tid >> 6;
    int wm = w >> 1, wn = w & 1;
    int ml = lane & 15, kq = lane >> 4;
    int rsub = lane >> 2;
    int ksw = (((lane & 3) ^ ((lane >> 3) & 3))) * 8;   // swizzled source K-slot (ushorts)
    int slot8 = ((kq ^ ((ml >> 1) & 3))) * 8;           // swizzled read K-slot (ushorts)

    f4 acc[4][4];
    #pragma unroll
    for (int i = 0; i < 4; ++i)
        #pragma unroll
        for (int j = 0; j < 4; ++j)
            acc[i][j] = (f4){0.f, 0.f, 0.f, 0.f};

    // 8 async loads per thread per K-tile
    auto STAGE = [&](int kt, int pb) {
        #pragma unroll
        for (int j = 0; j < 2; ++j) {
            int row = w * 32 + j * 16;                        // wave-uniform
            size_t ga = (size_t)(bm + row + rsub) * D_ + kt + ksw;
            size_t gb = (size_t)(bn + row + rsub) * D_ + kt + ksw;
            async_cp16(Ah + ga, &Ahs[pb][row * 32]);
            async_cp16(Al + ga, &Als[pb][row * 32]);
            async_cp16(Bh + gb, &Bhs[pb][row * 32]);
            async_cp16(Bl + gb, &Bls[pb][row * 32]);
        }
    };

    STAGE(0, 0);
    __syncthreads();

    for (int t = 0; t < 32; ++t) {
        int pb = t & 1;
        if (t < 31) STAGE((t + 1) * 32, pb ^ 1);   // issue next tile BEFORE compute
        bfrag ah[4], al[4], bh[4], bl[4];
        #pragma unroll
        for (int i = 0; i < 4; ++i) {
            int arow = wm * 64 + i * 16 + ml;
            ah[i] = *(const bfrag*)&Ahs[pb][arow * 32 + slot8];
            al[i] = *(const bfrag*)&Als[pb][arow * 32 + slot8];
            int brow = wn * 64 + i * 16 + ml;
            bh[i] = *(const bfrag*)&Bhs[pb][brow * 32 + slot8];
            bl[i] = *(const bfrag*)&Bls[pb][brow * 32 + slot8];
        }
        #pragma unroll
        for (int mi = 0; mi < 4; ++mi)
            #pragma unroll
            for (int ni = 0; ni < 4; ++ni) {
                acc[mi][ni] = __builtin_amdgcn_mfma_f32_16x16x32_bf16(ah[mi], bh[ni], acc[mi][ni], 0, 0, 0);
                acc[mi][ni] = __builtin_amdgcn_mfma_f32_16x16x32_bf16(al[mi], bh[ni], acc[mi][ni], 0, 0, 0);
                acc[mi][ni] = __builtin_amdgcn_mfma_f32_16x16x32_bf16(ah[mi], bl[ni], acc[mi][ni], 0, 0, 0);
            }
        __syncthreads();   // drains next-tile DMA (mostly landed under MFMA) + guards buffer reuse
    }
    #pragma unroll
    for (int ni = 0; ni < 4; ++ni) {
        int col = bn + wn * 64 + ni * 16 + ml;
        float bv = bias[col];
        #pragma unroll
        for (int mi = 0; mi < 4; ++mi) {
            int row0 = bm + wm * 64 + mi * 16 + kq * 4;
            #pragma unroll
            for (int r = 0; r < 4; ++r)
                C[(size_t)(row0 + r) * D_ + col] = acc[mi][ni][r] + bv;
        }
    }
}

// ---------------- generic NT GEMM on pre-split operands (Wo / Wfc), same 2-phase -----------
// mode 0: fp32+bias; mode 1: fp32+bias+relu; mode 2: split-bf16 write (+bias)
__global__ __launch_bounds__(256) void gemm_nt_s(
        const unsigned short* __restrict__ Ah, const unsigned short* __restrict__ Al,
        const unsigned short* __restrict__ Bh, const unsigned short* __restrict__ Bl,
        const float* __restrict__ bias, float* __restrict__ C,
        unsigned short* __restrict__ Ch, unsigned short* __restrict__ Cl, int mode)
{
    __shared__ __align__(16) unsigned short Ahs[2][128 * 32];
    __shared__ __align__(16) unsigned short Als[2][128 * 32];
    __shared__ __align__(16) unsigned short Bhs[2][128 * 32];
    __shared__ __align__(16) unsigned short Bls[2][128 * 32];

    int tid = threadIdx.x;
    int bn = blockIdx.x * 128;
    int bm = blockIdx.y * 128;
    int lane = tid & 63;
    int w = tid >> 6;
    int wm = w >> 1, wn = w & 1;
    int ml = lane & 15, kq = lane >> 4;
    int rsub = lane >> 2;
    int ksw = (((lane & 3) ^ ((lane >> 3) & 3))) * 8;
    int slot8 = ((kq ^ ((ml >> 1) & 3))) * 8;

    f4 acc[4][4];
    #pragma unroll
    for (int i = 0; i < 4; ++i)
        #pragma unroll
        for (int j = 0; j < 4; ++j)
            acc[i][j] = (f4){0.f, 0.f, 0.f, 0.f};

    auto STAGE = [&](int kt, int pb) {
        #pragma unroll
        for (int j = 0; j < 2; ++j) {
            int row = w * 32 + j * 16;
            size_t ga = (size_t)(bm + row + rsub) * D_ + kt + ksw;
            size_t gb = (size_t)(bn + row + rsub) * D_ + kt + ksw;
            async_cp16(Ah + ga, &Ahs[pb][row * 32]);
            async_cp16(Al + ga, &Als[pb][row * 32]);
            async_cp16(Bh + gb, &Bhs[pb][row * 32]);
            async_cp16(Bl + gb, &Bls[pb][row * 32]);
        }
    };

    STAGE(0, 0);
    __syncthreads();

    for (int t = 0; t < 32; ++t) {
        int pb = t & 1;
        if (t < 31) STAGE((t + 1) * 32, pb ^ 1);
        bfrag ah[4], al[4], bh[4], bl[4];
        #pragma unroll
        for (int i = 0; i < 4; ++i) {
            int arow = wm * 64 + i * 16 + ml;
            ah[i] = *(const bfrag*)&Ahs[pb][arow * 32 + slot8];
            al[i] = *(const bfrag*)&Als[pb][arow * 32 + slot8];
            int brow = wn * 64 + i * 16 + ml;
            bh[i] = *(const bfrag*)&Bhs[pb][brow * 32 + slot8];
            bl[i] = *(const bfrag*)&Bls[pb][brow * 32 + slot8];
        }
        #pragma unroll
        for (int mi = 0; mi < 4; ++mi)
            #pragma unroll
            for (int ni = 0; ni < 4; ++ni) {
                acc[mi][ni] = __builtin_amdgcn_mfma_f32_16x16x32_bf16(ah[mi], bh[ni], acc[mi][ni], 0, 0, 0);
                acc[mi][ni] = __builtin_amdgcn_mfma_f32_16x16x32_bf16(al[mi], bh[ni], acc[mi][ni], 0, 0, 0);
                acc[mi][ni] = __builtin_amdgcn_mfma_f32_16x16x32_bf16(ah[mi], bl[ni], acc[mi][ni], 0, 0, 0);
            }
        __syncthreads();
    }
    #pragma unroll
    for (int ni = 0; ni < 4; ++ni) {
        int col = bn + wn * 64 + ni * 16 + ml;
        float bv = bias[col];
        #pragma unroll
        for (int mi = 0; mi < 4; ++mi) {
            int row0 = bm + wm * 64 + mi * 16 + kq * 4;
            #pragma unroll
            for (int r = 0; r < 4; ++r) {
                float o = acc[mi][ni][r] + bv;
                size_t idx = (size_t)(row0 + r) * D_ + col;
                if (mode == 2) {
                    unsigned u = __float_as_uint(o);
                    float lo = o - __uint_as_float(u & 0xffff0000u);
                    Ch[idx] = (unsigned short)(u >> 16);
                    Cl[idx] = (unsigned short)(__float_as_uint(lo) >> 16);
                } else {
                    if (mode == 1) o = fmaxf(o, 0.f);
                    C[idx] = o;
                }
            }
        }
    }
}

// ---------------- MFMA key side, atomic-free C_u, single-bf16 phase1 ----------------
// grid (NSPLIT_=16, 64): x = n-split (256 rows), y = bh. 4 waves.
__global__ __launch_bounds__(256) void kside(
    const float* __restrict__ Kin, const float* __restrict__ Vin,
    const float* __restrict__ proj,
    float* __restrict__ S_u, float* __restrict__ Cpart, float* __restrict__ C_u,
    float* __restrict__ Vsum, unsigned int* __restrict__ mxp)
{
    __shared__ __align__(16) unsigned short Kh[64 * KP_];      // [n][d] bf16 RNE (pre-scaled by dn)
    __shared__ __align__(16) unsigned short VT[64 * KP_];      // [dh][n] bf16 RNE
    __shared__ __align__(16) unsigned short Ph[2][64 * KP_];   // proj [m][d] bf16 RNE, ping-pong
    __shared__ __align__(16) unsigned short Us[64 * KP_];      // [m][n] bf16 RNE
    __shared__ __align__(16) float Ssum[MP_];
    __shared__ float diag[64];
    float* redf = (float*)Us;   // overlay (lifetimes separated by barriers)

    int bh = blockIdx.y, b = bh >> 4, h = bh & 15;
    int s = blockIdx.x;
    int n0 = s * 256;
    int tid = threadIdx.x, lane = tid & 63, w = tid >> 6;
    int ml = lane & 15, quad = lane >> 4;

    float* dstC = (s < NSPLIT_ - 1) ? (Cpart + (size_t)s * PARTSZ_) : C_u;

    for (int i = tid; i < MP_; i += 256) Ssum[i] = 0.f;

    f4 acc[5][4];
    #pragma unroll
    for (int i = 0; i < 5; ++i)
        #pragma unroll
        for (int j = 0; j < 4; ++j) acc[i][j] = (f4){0.f, 0.f, 0.f, 0.f};
    float vs[4] = {0.f, 0.f, 0.f, 0.f};
    float lmax = -1e30f;

    for (int nc = 0; nc < 4; ++nc) {
        __syncthreads();
        // stage K (RNE, *dn), V^T (RNE), diag partials, and proj chunk 0
        #pragma unroll
        for (int l = 0; l < 4; ++l) {
            int idx = tid + 256 * l;
            int r = idx >> 4;
            int d4 = (idx & 15) * 4;
            size_t g = ((size_t)(b * N_ + n0 + nc * 64 + r)) * D_ + h * DH_ + d4;
            const float4 kv = *(const float4*)(Kin + g);
            redf[r * 17 + (tid & 15)] = kv.x * kv.x + kv.y * kv.y + kv.z * kv.z + kv.w * kv.w;
            unsigned w0 = (unsigned)bf16rne(kv.x * DN_) | ((unsigned)bf16rne(kv.y * DN_) << 16);
            unsigned w1 = (unsigned)bf16rne(kv.z * DN_) | ((unsigned)bf16rne(kv.w * DN_) << 16);
            *(uint2*)&Kh[r * KP_ + d4] = make_uint2(w0, w1);
            const float4 vv = *(const float4*)(Vin + g);
            vs[0] += vv.x; vs[1] += vv.y; vs[2] += vv.z; vs[3] += vv.w;
            VT[(d4 + 0) * KP_ + r] = bf16rne(vv.x);
            VT[(d4 + 1) * KP_ + r] = bf16rne(vv.y);
            VT[(d4 + 2) * KP_ + r] = bf16rne(vv.z);
            VT[(d4 + 3) * KP_ + r] = bf16rne(vv.w);
        }
        {   // proj chunk 0 -> Ph[0]
            #pragma unroll
            for (int l = 0; l < 2; ++l) {
                int idx = tid + 256 * l;
                int m = idx >> 3, d8 = (idx & 7) * 8;
                const float4 p0 = *(const float4*)(proj + m * 64 + d8);
                const float4 p1 = *(const float4*)(proj + m * 64 + d8 + 4);
                unsigned a0 = (unsigned)bf16rne(p0.x) | ((unsigned)bf16rne(p0.y) << 16);
                unsigned a1 = (unsigned)bf16rne(p0.z) | ((unsigned)bf16rne(p0.w) << 16);
                unsigned a2 = (unsigned)bf16rne(p1.x) | ((unsigned)bf16rne(p1.y) << 16);
                unsigned a3 = (unsigned)bf16rne(p1.z) | ((unsigned)bf16rne(p1.w) << 16);
                *(uint4*)&Ph[0][m * KP_ + d8] = make_uint4(a0, a1, a2, a3);
            }
        }
        __syncthreads();
        if (tid < 64) {
            float ss = 0.f;
            #pragma unroll
            for (int p = 0; p < 16; ++p) ss += redf[tid * 17 + p];
            diag[tid] = ss * 0.0625f;
        }
        __syncthreads();

        bfrag kh0 = *(const bfrag*)&Kh[(w * 16 + ml) * KP_ + quad * 8];
        bfrag kh1 = *(const bfrag*)&Kh[(w * 16 + ml) * KP_ + 32 + quad * 8];
        float dgv[4];
        #pragma unroll
        for (int r = 0; r < 4; ++r) dgv[r] = diag[w * 16 + quad * 4 + r];

        for (int mc = 0; mc < 5; ++mc) {
            int pb = mc & 1;
            // prefetch next proj chunk (loads overlap phase-1 MFMA)
            float4 pf[4];
            if (mc < 4) {
                #pragma unroll
                for (int l = 0; l < 2; ++l) {
                    int idx = tid + 256 * l;
                    int m = idx >> 3, d8 = (idx & 7) * 8;
                    int mg = (mc + 1) * 64 + m;
                    if (mg < M_) {
                        pf[l * 2 + 0] = *(const float4*)(proj + mg * 64 + d8);
                        pf[l * 2 + 1] = *(const float4*)(proj + mg * 64 + d8 + 4);
                    } else {
                        pf[l * 2 + 0] = make_float4(0.f, 0.f, 0.f, 0.f);
                        pf[l * 2 + 1] = make_float4(0.f, 0.f, 0.f, 0.f);
                    }
                }
            }
            // phase 1: td[n][m] tiles, single-bf16
            #pragma unroll
            for (int mt = 0; mt < 4; ++mt) {
                int mrow = mt * 16 + ml;
                bfrag ph0 = *(const bfrag*)&Ph[pb][mrow * KP_ + quad * 8];
                bfrag ph1 = *(const bfrag*)&Ph[pb][mrow * KP_ + 32 + quad * 8];
                f4 t = (f4){0.f, 0.f, 0.f, 0.f};
                t = __builtin_amdgcn_mfma_f32_16x16x32_bf16(kh0, ph0, t, 0, 0, 0);
                t = __builtin_amdgcn_mfma_f32_16x16x32_bf16(kh1, ph1, t, 0, 0, 0);
                bool mv = (mc * 64 + mrow) < M_;
                float su = 0.f;
                unsigned short up[4];
                #pragma unroll
                for (int r = 0; r < 4; ++r) {
                    float u = 0.f;
                    if (mv) {
                        float tt = t[r];
                        lmax = fmaxf(lmax, tt);
                        u = __expf(tt - dgv[r]);
                    }
                    su += u;
                    up[r] = bf16rne(u);
                }
                su += __shfl_xor(su, 16);
                su += __shfl_xor(su, 32);
                if (mv && quad == 0) atomicAdd(&Ssum[mc * 64 + mrow], su);
                unsigned w0 = (unsigned)up[0] | ((unsigned)up[1] << 16);
                unsigned w1 = (unsigned)up[2] | ((unsigned)up[3] << 16);
                *(uint2*)&Us[mrow * KP_ + w * 16 + quad * 4] = make_uint2(w0, w1);
            }
            // store prefetched proj
            if (mc < 4) {
                #pragma unroll
                for (int l = 0; l < 2; ++l) {
                    int idx = tid + 256 * l;
                    int m = idx >> 3, d8 = (idx & 7) * 8;
                    const float4 p0 = pf[l * 2 + 0], p1 = pf[l * 2 + 1];
                    unsigned a0 = (unsigned)bf16rne(p0.x) | ((unsigned)bf16rne(p0.y) << 16);
                    unsigned a1 = (unsigned)bf16rne(p0.z) | ((unsigned)bf16rne(p0.w) << 16);
                    unsigned a2 = (unsigned)bf16rne(p1.x) | ((unsigned)bf16rne(p1.y) << 16);
                    unsigned a3 = (unsigned)bf16rne(p1.z) | ((unsigned)bf16rne(p1.w) << 16);
                    *(uint4*)&Ph[1 - pb][m * KP_ + d8] = make_uint4(a0, a1, a2, a3);
                }
            }
            __syncthreads();
            // phase 2: acc[mc] += Us^T-tile @ V
            bfrag ua0 = *(const bfrag*)&Us[(w * 16 + ml) * KP_ + quad * 8];
            bfrag ua1 = *(const bfrag*)&Us[(w * 16 + ml) * KP_ + 32 + quad * 8];
            #pragma unroll
            for (int dt = 0; dt < 4; ++dt) {
                bfrag vb0 = *(const bfrag*)&VT[(dt * 16 + ml) * KP_ + quad * 8];
                bfrag vb1 = *(const bfrag*)&VT[(dt * 16 + ml) * KP_ + 32 + quad * 8];
                acc[mc][dt] = __builtin_amdgcn_mfma_f32_16x16x32_bf16(ua0, vb0, acc[mc][dt], 0, 0, 0);
                acc[mc][dt] = __builtin_amdgcn_mfma_f32_16x16x32_bf16(ua1, vb1, acc[mc][dt], 0, 0, 0);
            }
            __syncthreads();
        }
    }
    // epilogue: C_u partial, PLAIN stores (no atomics)
    #pragma unroll
    for (int mc = 0; mc < 5; ++mc)
        #pragma unroll
        for (int dt = 0; dt < 4; ++dt)
            #pragma unroll
            for (int r = 0; r < 4; ++r) {
                int m = mc * 64 + w * 16 + quad * 4 + r;
                if (m < M_)
                    dstC[((size_t)bh * M_ + m) * 64 + dt * 16 + ml] = acc[mc][dt][r];
            }
    __syncthreads();
    for (int m = tid; m < M_; m += 256)
        atomicAdd(S_u + bh * M_ + m, Ssum[m]);
    #pragma unroll
    for (int off = 32; off; off >>= 1) lmax = fmaxf(lmax, __shfl_xor(lmax, off));
    __syncthreads();
    if (lane == 0) redf[w] = lmax;
    __syncthreads();
    if (tid == 0) {
        float mxv = fmaxf(fmaxf(redf[0], redf[1]), fmaxf(redf[2], redf[3]));
        atomicMax(mxp + bh, f2ord(mxv));
    }
    for (int j = 0; j < 4; ++j) {
        __syncthreads();
        redf[tid] = vs[j];
        __syncthreads();
        if (tid < 16) {
            float ss = 0.f;
            #pragma unroll
            for (int p = 0; p < 16; ++p) ss += redf[tid + 16 * p];
            atomicAdd(Vsum + bh * 64 + tid * 4 + j, ss);
        }
    }
}

// ---------------- finalize: sum 16 partials, build ks + ctxT(split) + Cs + kss ----------------
// grid (5, 64): x = m-chunk, y = bh
__global__ __launch_bounds__(256) void finalize_kernel(
    const float* __restrict__ S_u, const float* __restrict__ Cpart, const float* __restrict__ C_u,
    const float* __restrict__ Vsum, const unsigned* __restrict__ mxp,
    float* __restrict__ ksum_f, unsigned short* __restrict__ ctxTh,
    unsigned short* __restrict__ ctxTl, float* __restrict__ Cs, float* __restrict__ kss)
{
    __shared__ float T[64 * 65];
    __shared__ float red[256];
    int mc = blockIdx.x, bh = blockIdx.y;
    int tid = threadIdx.x;
    float emx = __expf(-ord2f(mxp[bh]));

    float csacc = 0.f;   // dh = tid&63 fixed across iterations
    #pragma unroll
    for (int i = 0; i < 16; ++i) {
        int idx = i * 256 + tid;
        int dh = idx & 63, mloc = idx >> 6;
        int m = mc * 64 + mloc;
        float v = 0.f;
        if (m < M_) {
            size_t off = ((size_t)bh * M_ + m) * 64 + dh;
            float sacc = C_u[off];
            for (int sp = 0; sp < NSPLIT_ - 1; ++sp)
                sacc += Cpart[(size_t)sp * PARTSZ_ + off];
            v = RATIO_ * (emx * sacc + EPS_ * Vsum[bh * 64 + dh]);
        }
        T[mloc * 65 + dh] = v;
        csacc += v;
    }
    red[tid] = csacc;
    __syncthreads();
    if (tid < 64) atomicAdd(&Cs[bh * 64 + tid], red[tid] + red[tid + 64] + red[tid + 128] + red[tid + 192]);
    // ks + kss
    float ksl = 0.f;
    if (tid < 64) {
        int m = mc * 64 + tid;
        float kv = (m < M_) ? RATIO_ * (emx * S_u[bh * M_ + m] + EPS_ * (float)N_) : 0.f;
        ksum_f[bh * MP_ + m] = kv;
        ksl = kv;
    }
    __syncthreads();
    red[tid] = ksl;
    __syncthreads();
    if (tid == 0) {
        float ss = 0.f;
        for (int p = 0; p < 64; ++p) ss += red[p];
        atomicAdd(kss + bh, ss);
    }
    __syncthreads();
    // transposed split writes: ctxT[dh][m]
    #pragma unroll
    for (int i = 0; i < 8; ++i) {
        int idx = i * 256 + tid;
        int dh = idx >> 5, m2 = (idx & 31) * 2;
        float v0 = T[m2 * 65 + dh], v1 = T[(m2 + 1) * 65 + dh];
        unsigned u0 = __float_as_uint(v0), u1 = __float_as_uint(v1);
        float lo0 = v0 - __uint_as_float(u0 & 0xffff0000u);
        float lo1 = v1 - __uint_as_float(u1 & 0xffff0000u);
        size_t dst = ((size_t)(bh * 64 + dh)) * MP_ + mc * 64 + m2;
        *(unsigned*)&ctxTh[dst] = (u0 >> 16) | (u1 & 0xffff0000u);
        *(unsigned*)&ctxTl[dst] = (__float_as_uint(lo0) >> 16) | (__float_as_uint(lo1) & 0xffff0000u);
    }
}

// ---------------- MFMA query side (epilogue writes split-bf16 attn) ----------------
__global__ __launch_bounds__(256) void qattn(
    const float* __restrict__ Q, const float* __restrict__ proj,
    const float* __restrict__ ksum_f, const unsigned short* __restrict__ ctxTh,
    const unsigned short* __restrict__ ctxTl,
    const float* __restrict__ Cs, const float* __restrict__ kss,
    unsigned short* __restrict__ attnH, unsigned short* __restrict__ attnL)
{
    __shared__ __align__(16) unsigned short Qh[64 * KP_], Ql[64 * KP_];
    __shared__ __align__(16) unsigned short Ph[64 * KP_], Pl[64 * KP_];
    __shared__ __align__(16) unsigned short Uh[64 * KP_], Ul[64 * KP_];
    __shared__ __align__(16) float ks[MP_];
    __shared__ float diag[64];
    float* redf = (float*)Uh;

    int bh = blockIdx.y, b = bh >> 4, h = bh & 15;
    int n0 = blockIdx.x * 64;
    int tid = threadIdx.x, lane = tid & 63, w = tid >> 6;
    int ml = lane & 15, quad = lane >> 4;

    #pragma unroll
    for (int l = 0; l < 4; ++l) {
        int idx = tid + 256 * l;
        int r = idx >> 4, d4 = (idx & 15) * 4;
        size_t g = ((size_t)(b * N_ + n0 + r)) * D_ + h * DH_ + d4;
        const float4 qv = *(const float4*)(Q + g);
        redf[r * 17 + (tid & 15)] = qv.x * qv.x + qv.y * qv.y + qv.z * qv.z + qv.w * qv.w;
        unsigned h0, l0, h1, l1;
        split2pack(qv.x * DN_, qv.y * DN_, &h0, &l0);
        split2pack(qv.z * DN_, qv.w * DN_, &h1, &l1);
        *(uint2*)&Qh[r * KP_ + d4] = make_uint2(h0, h1);
        *(uint2*)&Ql[r * KP_ + d4] = make_uint2(l0, l1);
    }
    for (int m = tid; m < MP_; m += 256) ks[m] = ksum_f[bh * MP_ + m];
    __syncthreads();
    if (tid < 64) {
        float s = 0.f;
        #pragma unroll
        for (int p = 0; p < 16; ++p) s += redf[tid * 17 + p];
        diag[tid] = s * 0.0625f;
    }
    __syncthreads();

    bfrag qh0 = *(const bfrag*)&Qh[(w * 16 + ml) * KP_ + quad * 8];
    bfrag ql0 = *(const bfrag*)&Ql[(w * 16 + ml) * KP_ + quad * 8];
    bfrag qh1 = *(const bfrag*)&Qh[(w * 16 + ml) * KP_ + 32 + quad * 8];
    bfrag ql1 = *(const bfrag*)&Ql[(w * 16 + ml) * KP_ + 32 + quad * 8];
    float dg = diag[w * 16 + ml];
    float dacc = 0.f, tmax = -1e30f;
    f4 oacc[4];
    #pragma unroll
    for (int i = 0; i < 4; ++i) oacc[i] = (f4){0.f, 0.f, 0.f, 0.f};

    for (int mc = 0; mc < 5; ++mc) {
        #pragma unroll
        for (int l = 0; l < 4; ++l) {
            int idx = tid + 256 * l;
            int m = idx >> 4, d4 = (idx & 15) * 4;
            int mg = mc * 64 + m;
            float4 p = make_float4(0.f, 0.f, 0.f, 0.f);
            if (mg < M_) p = *(const float4*)(proj + mg * 64 + d4);
            unsigned h0, l0, h1, l1;
            split2pack(p.x, p.y, &h0, &l0);
            split2pack(p.z, p.w, &h1, &l1);
            *(uint2*)&Ph[m * KP_ + d4] = make_uint2(h0, h1);
            *(uint2*)&Pl[m * KP_ + d4] = make_uint2(l0, l1);
        }
        __syncthreads();
        #pragma unroll
        for (int mt = 0; mt < 4; ++mt) {
            int mrow = mt * 16 + ml;
            bfrag ph0 = *(const bfrag*)&Ph[mrow * KP_ + quad * 8];
            bfrag pl0 = *(const bfrag*)&Pl[mrow * KP_ + quad * 8];
            bfrag ph1 = *(const bfrag*)&Ph[mrow * KP_ + 32 + quad * 8];
            bfrag pl1 = *(const bfrag*)&Pl[mrow * KP_ + 32 + quad * 8];
            f4 t = (f4){0.f, 0.f, 0.f, 0.f};
            t = __builtin_amdgcn_mfma_f32_16x16x32_bf16(ph0, qh0, t, 0, 0, 0);
            t = __builtin_amdgcn_mfma_f32_16x16x32_bf16(pl0, qh0, t, 0, 0, 0);
            t = __builtin_amdgcn_mfma_f32_16x16x32_bf16(ph0, ql0, t, 0, 0, 0);
            t = __builtin_amdgcn_mfma_f32_16x16x32_bf16(ph1, qh1, t, 0, 0, 0);
            t = __builtin_amdgcn_mfma_f32_16x16x32_bf16(pl1, qh1, t, 0, 0, 0);
            t = __builtin_amdgcn_mfma_f32_16x16x32_bf16(ph1, ql1, t, 0, 0, 0);
            const float4 ksv = *(const float4*)&ks[mc * 64 + mt * 16 + quad * 4];
            float ksa[4] = {ksv.x, ksv.y, ksv.z, ksv.w};
            unsigned short uh4[4], ul4[4];
            #pragma unroll
            for (int r = 0; r < 4; ++r) {
                int mg = mc * 64 + mt * 16 + quad * 4 + r;
                float tt = t[r];
                float u = __expf(tt - dg);
                if (mg < M_) tmax = fmaxf(tmax, tt);
                dacc = fmaf(u, ksa[r], dacc);
                unsigned uu = __float_as_uint(u);
                float lo = u - __uint_as_float(uu & 0xffff0000u);
                uh4[r] = (unsigned short)(uu >> 16);
                ul4[r] = (unsigned short)(__float_as_uint(lo) >> 16);
            }
            unsigned a0 = (unsigned)uh4[0] | ((unsigned)uh4[1] << 16);
            unsigned a1 = (unsigned)uh4[2] | ((unsigned)uh4[3] << 16);
            unsigned b0 = (unsigned)ul4[0] | ((unsigned)ul4[1] << 16);
            unsigned b1 = (unsigned)ul4[2] | ((unsigned)ul4[3] << 16);
            *(uint2*)&Uh[(w * 16 + ml) * KP_ + mt * 16 + quad * 4] = make_uint2(a0, a1);
            *(uint2*)&Ul[(w * 16 + ml) * KP_ + mt * 16 + quad * 4] = make_uint2(b0, b1);
        }
        __syncthreads();
        #pragma unroll
        for (int l = 0; l < 2; ++l) {
            int idx = tid + 256 * l;
            int dh = idx >> 3, m8 = (idx & 7) * 8;
            size_t src = ((size_t)(bh * 64 + dh)) * MP_ + mc * 64 + m8;
            *(uint4*)&Ph[dh * KP_ + m8] = *(const uint4*)(ctxTh + src);
            *(uint4*)&Pl[dh * KP_ + m8] = *(const uint4*)(ctxTl + src);
        }
        __syncthreads();
        bfrag ua0h = *(const bfrag*)&Uh[(w * 16 + ml) * KP_ + quad * 8];
        bfrag ua0l = *(const bfrag*)&Ul[(w * 16 + ml) * KP_ + quad * 8];
        bfrag ua1h = *(const bfrag*)&Uh[(w * 16 + ml) * KP_ + 32 + quad * 8];
        bfrag ua1l = *(const bfrag*)&Ul[(w * 16 + ml) * KP_ + 32 + quad * 8];
        #pragma unroll
        for (int dt = 0; dt < 4; ++dt) {
            bfrag cb0h = *(const bfrag*)&Ph[(dt * 16 + ml) * KP_ + quad * 8];
            bfrag cb0l = *(const bfrag*)&Pl[(dt * 16 + ml) * KP_ + quad * 8];
            bfrag cb1h = *(const bfrag*)&Ph[(dt * 16 + ml) * KP_ + 32 + quad * 8];
            bfrag cb1l = *(const bfrag*)&Pl[(dt * 16 + ml) * KP_ + 32 + quad * 8];
            oacc[dt] = __builtin_amdgcn_mfma_f32_16x16x32_bf16(ua0h, cb0h, oacc[dt], 0, 0, 0);
            oacc[dt] = __builtin_amdgcn_mfma_f32_16x16x32_bf16(ua0l, cb0h, oacc[dt], 0, 0, 0);
            oacc[dt] = __builtin_amdgcn_mfma_f32_16x16x32_bf16(ua0h, cb0l, oacc[dt], 0, 0, 0);
            oacc[dt] = __builtin_amdgcn_mfma_f32_16x16x32_bf16(ua1h, cb1h, oacc[dt], 0, 0, 0);
            oacc[dt] = __builtin_amdgcn_mfma_f32_16x16x32_bf16(ua1l, cb1h, oacc[dt], 0, 0, 0);
            oacc[dt] = __builtin_amdgcn_mfma_f32_16x16x32_bf16(ua1h, cb1l, oacc[dt], 0, 0, 0);
        }
        __syncthreads();
    }
    dacc += __shfl_xor(dacc, 16); dacc += __shfl_xor(dacc, 32);
    tmax = fmaxf(tmax, __shfl_xor(tmax, 16));
    tmax = fmaxf(tmax, __shfl_xor(tmax, 32));
    float fac = EPS_ * __expf(tmax);
    float dinv = 1.f / (dacc + fac * kss[bh]);
    #pragma unroll
    for (int dt = 0; dt < 4; ++dt) {
        float csv = Cs[bh * 64 + dt * 16 + ml];
        #pragma unroll
        for (int r = 0; r < 4; ++r) {
            int srcl = quad * 4 + r;
            float dv = __shfl(dinv, srcl);
            float fv = __shfl(fac, srcl);
            float o = (oacc[dt][r] + fv * csv) * dv;
            int n = n0 + w * 16 + quad * 4 + r;
            size_t gi = ((size_t)(b * N_ + n)) * D_ + h * DH_ + dt * 16 + ml;
            unsigned u = __float_as_uint(o);
            float lo = o - __uint_as_float(u & 0xffff0000u);
            attnH[gi] = (unsigned short)(u >> 16);
            attnL[gi] = (unsigned short)(__float_as_uint(lo) >> 16);
        }
    }
}

// ---------------- launch ----------------
extern "C" void kernel_launch(void* const* d_in, const int* in_sizes, int n_in,
                              void* d_out, int out_size, void* d_ws, size_t ws_size,
                              hipStream_t stream)
{
    const float* x    = (const float*)d_in[0];
    const float* Wq   = (const float*)d_in[1];
    const float* bq   = (const float*)d_in[2];
    const float* Wk   = (const float*)d_in[3];
    const float* bk   = (const float*)d_in[4];
    const float* Wv   = (const float*)d_in[5];
    const float* bv   = (const float*)d_in[6];
    const float* Wo   = (const float*)d_in[7];
    const float* bo   = (const float*)d_in[8];
    const float* Wfc  = (const float*)d_in[9];
    const float* bfc  = (const float*)d_in[10];
    const float* proj = (const float*)d_in[11];
    float* out = (float*)d_out;

    float* ws = (float*)d_ws;
    const size_t nTok = (size_t)B_ * N_ * D_;
    const size_t nSu  = 64 * M_;
    const size_t nCu  = (size_t)64 * M_ * 64;
    const size_t nVs  = 64 * 64;
    const size_t nMx  = 64;
    const size_t nKsf = 64 * MP_;
    const size_t nCtx = (size_t)64 * MP_ * 64;
    const size_t nCs  = 64 * 64;

    const size_t offQ   = 0;
    const size_t offK   = nTok;
    const size_t offV   = nTok * 2;
    const size_t offSu  = nTok * 3;
    const size_t offCu  = offSu + nSu;
    const size_t offVs  = offCu + nCu;
    const size_t offMx  = offVs + nVs;
    const size_t offKsf = offMx + nMx;
    const size_t offCtx = offKsf + nKsf;
    const size_t offCs  = offCtx + nCtx;
    const size_t offKss = offCs + nCs;
    const size_t offWsp = offKss + 64;      // 5 weights split: 5 * 1048576 float-slots

    float* Q    = ws + offQ;
    float* Kb   = ws + offK;
    float* Vb   = ws + offV;
    float* S_u  = ws + offSu;
    float* C_u  = ws + offCu;
    float* Vsum = ws + offVs;
    unsigned* mx = (unsigned*)(ws + offMx);
    float* ksf  = ws + offKsf;
    unsigned short* ctxTh = (unsigned short*)(ws + offCtx);
    unsigned short* ctxTl = ctxTh + (size_t)64 * 64 * MP_;
    float* Cs   = ws + offCs;
    float* kss  = ws + offKss;
    unsigned short* Wsp = (unsigned short*)(ws + offWsp);

    // scratch overlays (stream-ordered lifetimes):
    unsigned short* xh = (unsigned short*)out;        // x split lives in d_out, dead before kside
    unsigned short* xl = xh + nTok;
    unsigned short* attnH = (unsigned short*)Kb;      // K dead after kside
    unsigned short* attnL = attnH + nTok;
    unsigned short* hbH = (unsigned short*)Vb;        // V dead after kside
    unsigned short* hbL = hbH + nTok;
    float* Cpart = out;                               // d_out as scratch for 15 C_u partials

    // zero S_u..kss (covers S_u, C_u, Vsum, mx, ksf, ctxT, Cs, kss)
    int nzero = (int)(nSu + nCu + nVs + nMx + nKsf + nCtx + nCs + 64);
    zero_kernel<<<dim3((nzero + 255) / 256), dim3(256), 0, stream>>>(S_u, nzero);

    // one-shot splits
    split_f32<<<dim3(16384), dim3(256), 0, stream>>>(x, xh, xl, (int)(nTok / 4));
    split_w5<<<dim3(1024, 5), dim3(256), 0, stream>>>(Wq, Wk, Wv, Wo, Wfc, Wsp);

    gemm_qkv_s<<<dim3(24, (B_ * N_) / 128), dim3(256), 0, stream>>>(
        xh, xl, Wsp, bq, bk, bv, Q, Kb, Vb);

    kside<<<dim3(NSPLIT_, 64), dim3(256), 0, stream>>>(Kb, Vb, proj, S_u, Cpart, C_u, Vsum, mx);
    finalize_kernel<<<dim3(5, 64), dim3(256), 0, stream>>>(S_u, Cpart, C_u, Vsum, mx, ksf, ctxTh, ctxTl, Cs, kss);
    qattn<<<dim3(64, 64), dim3(256), 0, stream>>>(Q, proj, ksf, ctxTh, ctxTl, Cs, kss, attnH, attnL);

    dim3 gg(D_ / 128, (B_ * N_) / 128);
    // Wo: split-bf16 A (attn) -> split-bf16 hbuf
    gemm_nt_s<<<gg, dim3(256), 0, stream>>>(attnH, attnL,
        Wsp + (size_t)3 * 2097152, Wsp + (size_t)3 * 2097152 + 1048576,
        bo, (float*)nullptr, hbH, hbL, 2);
    // Wfc: split-bf16 A (hbuf) -> fp32 out + relu
    gemm_nt_s<<<gg, dim3(256), 0, stream>>>(hbH, hbL,
        Wsp + (size_t)4 * 2097152, Wsp + (size_t)4 * 2097152 + 1048576,
        bfc, out, (unsigned short*)nullptr, (unsigned short*)nullptr, 1);
}

// Round 6
// 1008.630 us; speedup vs baseline: 1.0906x; 1.0906x over previous
//
#include <hip/hip_runtime.h>
#include <math.h>

#define B_ 4
#define N_ 4096
#define D_ 1024
#define H_ 16
#define DH_ 64
#define M_ 266
#define MP_ 320   // M padded to 5 chunks of 64

#define DN_ 0.35355339059327373f      // 64^-0.25
#define RATIO_ 0.06131393394849658f   // 266^-0.5
#define EPS_ 1e-4f
#define KP_ 72    // ushort row stride
#define NSPLIT_ 16
#define PARTSZ_ ((size_t)64 * M_ * 64)   // one C_u partial (all bh)

typedef __attribute__((ext_vector_type(8))) short bfrag;
typedef __attribute__((ext_vector_type(4))) float f4;

__device__ __forceinline__ unsigned f2ord(float f) {
    unsigned u = __float_as_uint(f);
    return (u & 0x80000000u) ? ~u : (u | 0x80000000u);
}
__device__ __forceinline__ float ord2f(unsigned u) {
    unsigned b = (u & 0x80000000u) ? (u & 0x7fffffffu) : ~u;
    return __uint_as_float(b);
}

__global__ void zero_kernel(float* __restrict__ p, int n) {
    int i = blockIdx.x * 256 + threadIdx.x;
    if (i < n) p[i] = 0.f;
}

__device__ __forceinline__ void split2pack(float x, float y, unsigned* hp, unsigned* lp) {
    unsigned ux = __float_as_uint(x), uy = __float_as_uint(y);
    float hx = __uint_as_float(ux & 0xffff0000u);
    float hy = __uint_as_float(uy & 0xffff0000u);
    float lx = x - hx, ly = y - hy;
    *hp = (ux >> 16) | (uy & 0xffff0000u);
    *lp = (__float_as_uint(lx) >> 16) | (__float_as_uint(ly) & 0xffff0000u);
}
__device__ __forceinline__ unsigned short bf16rne(float x) {
    unsigned u = __float_as_uint(x);
    return (unsigned short)((u + 0x7fffu + ((u >> 16) & 1u)) >> 16);
}

// async global->LDS 16B (dwordx4). LDS dst must be wave-uniform; lane writes dst+lane*16.
__device__ __forceinline__ void async_cp16(const void* g, void* l) {
    __builtin_amdgcn_global_load_lds(
        (const __attribute__((address_space(1))) void*)g,
        (__attribute__((address_space(3))) void*)l, 16, 0, 0);
}

// ---------------- one-shot split conversions (each element converted exactly once) --------
__global__ __launch_bounds__(256) void split_f32(const float* __restrict__ X,
        unsigned short* __restrict__ Xh, unsigned short* __restrict__ Xl, int n4)
{
    int i = blockIdx.x * 256 + threadIdx.x;
    if (i >= n4) return;
    const float4 v = ((const float4*)X)[i];
    unsigned h0, l0, h1, l1;
    split2pack(v.x, v.y, &h0, &l0);
    split2pack(v.z, v.w, &h1, &l1);
    ((uint2*)Xh)[i] = make_uint2(h0, h1);
    ((uint2*)Xl)[i] = make_uint2(l0, l1);
}

// 5 weights (1024x1024 each) -> Wsp: per sel, h at sel*2097152, l at +1048576 (ushort units)
__global__ __launch_bounds__(256) void split_w5(const float* __restrict__ W0,
        const float* __restrict__ W1, const float* __restrict__ W2,
        const float* __restrict__ W3, const float* __restrict__ W4,
        unsigned short* __restrict__ Wsp)
{
    int sel = blockIdx.y;
    const float* W = (sel == 0) ? W0 : (sel == 1) ? W1 : (sel == 2) ? W2 : (sel == 3) ? W3 : W4;
    unsigned short* h = Wsp + (size_t)sel * 2097152;
    unsigned short* l = h + 1048576;
    int i = blockIdx.x * 256 + threadIdx.x;   // 1024*256 threads * 4 elems = 1048576
    const float4 v = ((const float4*)W)[i];
    unsigned h0, l0, h1, l1;
    split2pack(v.x, v.y, &h0, &l0);
    split2pack(v.z, v.w, &h1, &l1);
    ((uint2*)h)[i] = make_uint2(h0, h1);
    ((uint2*)l)[i] = make_uint2(l0, l1);
}

// ---------------- fused QKV GEMM: 256x256 tile, 8 waves, stage-serial --------------------
// Traffic ∝ (1/BM+1/BN): 256² halves L2/L3->LDS staging bytes vs 128² (the measured
// bottleneck: 247 TF eff. at 10 TB/s staging).  Schedule = R1-proven stage-serial.
// LDS 16B-granule swizzle: granule (row,slot) at slot^((row>>1)&3); write side = linear
// LDS dst + pre-swizzled GLOBAL source slot (ksw), read side = slot8. Conflict-free.
__global__ __launch_bounds__(512) void gemm_qkv_s(
        const unsigned short* __restrict__ Ah, const unsigned short* __restrict__ Al,
        const unsigned short* __restrict__ Wsp,
        const float* __restrict__ b0, const float* __restrict__ b1, const float* __restrict__ b2,
        float* __restrict__ C0, float* __restrict__ C1, float* __restrict__ C2)
{
    __shared__ __align__(16) unsigned short Ahs[256 * 32];
    __shared__ __align__(16) unsigned short Als[256 * 32];
    __shared__ __align__(16) unsigned short Bhs[256 * 32];
    __shared__ __align__(16) unsigned short Bls[256 * 32];

    int tid = threadIdx.x;
    int sel = blockIdx.x >> 2;               // 0..2 -> q,k,v
    int bn = (blockIdx.x & 3) * 256;
    int bm = blockIdx.y * 256;
    const unsigned short* Bh = Wsp + (size_t)sel * 2097152;
    const unsigned short* Bl = Bh + 1048576;
    const float* bias = (sel == 0) ? b0 : (sel == 1) ? b1 : b2;
    float* C = (sel == 0) ? C0 : (sel == 1) ? C1 : C2;

    int lane = tid & 63;
    int w = tid >> 6;                        // 0..7
    int wm = w >> 2, wn = w & 3;             // per-wave output: 128 rows x 64 cols
    int ml = lane & 15, kq = lane >> 4;
    int rsub = lane >> 2;
    int ksw = (((lane & 3) ^ ((lane >> 3) & 3))) * 8;   // swizzled source K-slot (ushorts)
    int slot8 = ((kq ^ ((ml >> 1) & 3))) * 8;           // swizzled read K-slot (ushorts)

    f4 acc[8][4];
    #pragma unroll
    for (int i = 0; i < 8; ++i)
        #pragma unroll
        for (int j = 0; j < 4; ++j)
            acc[i][j] = (f4){0.f, 0.f, 0.f, 0.f};

    for (int kt = 0; kt < D_; kt += 32) {
        __syncthreads();
        #pragma unroll
        for (int j = 0; j < 2; ++j) {
            int row = w * 32 + j * 16;                        // wave-uniform, rows 0..255
            size_t ga = (size_t)(bm + row + rsub) * D_ + kt + ksw;
            size_t gb = (size_t)(bn + row + rsub) * D_ + kt + ksw;
            async_cp16(Ah + ga, &Ahs[row * 32]);
            async_cp16(Al + ga, &Als[row * 32]);
            async_cp16(Bh + gb, &Bhs[row * 32]);
            async_cp16(Bl + gb, &Bls[row * 32]);
        }
        __syncthreads();
        bfrag bh[4], bl[4];
        #pragma unroll
        for (int ni = 0; ni < 4; ++ni) {
            int brow = wn * 64 + ni * 16 + ml;
            bh[ni] = *(const bfrag*)&Bhs[brow * 32 + slot8];
            bl[ni] = *(const bfrag*)&Bls[brow * 32 + slot8];
        }
        #pragma unroll
        for (int mi = 0; mi < 8; ++mi) {
            int arow = wm * 128 + mi * 16 + ml;
            bfrag ah = *(const bfrag*)&Ahs[arow * 32 + slot8];
            bfrag al = *(const bfrag*)&Als[arow * 32 + slot8];
            #pragma unroll
            for (int ni = 0; ni < 4; ++ni) {
                acc[mi][ni] = __builtin_amdgcn_mfma_f32_16x16x32_bf16(ah, bh[ni], acc[mi][ni], 0, 0, 0);
                acc[mi][ni] = __builtin_amdgcn_mfma_f32_16x16x32_bf16(al, bh[ni], acc[mi][ni], 0, 0, 0);
                acc[mi][ni] = __builtin_amdgcn_mfma_f32_16x16x32_bf16(ah, bl[ni], acc[mi][ni], 0, 0, 0);
            }
        }
    }
    #pragma unroll
    for (int ni = 0; ni < 4; ++ni) {
        int col = bn + wn * 64 + ni * 16 + ml;
        float bv = bias[col];
        #pragma unroll
        for (int mi = 0; mi < 8; ++mi) {
            int row0 = bm + wm * 128 + mi * 16 + kq * 4;
            #pragma unroll
            for (int r = 0; r < 4; ++r)
                C[(size_t)(row0 + r) * D_ + col] = acc[mi][ni][r] + bv;
        }
    }
}

// ---------------- generic NT GEMM on pre-split operands (Wo / Wfc), 256x256 --------------
// mode 0: fp32+bias; mode 1: fp32+bias+relu; mode 2: split-bf16 write (+bias)
__global__ __launch_bounds__(512) void gemm_nt_s(
        const unsigned short* __restrict__ Ah, const unsigned short* __restrict__ Al,
        const unsigned short* __restrict__ Bh, const unsigned short* __restrict__ Bl,
        const float* __restrict__ bias, float* __restrict__ C,
        unsigned short* __restrict__ Ch, unsigned short* __restrict__ Cl, int mode)
{
    __shared__ __align__(16) unsigned short Ahs[256 * 32];
    __shared__ __align__(16) unsigned short Als[256 * 32];
    __shared__ __align__(16) unsigned short Bhs[256 * 32];
    __shared__ __align__(16) unsigned short Bls[256 * 32];

    int tid = threadIdx.x;
    int bn = blockIdx.x * 256;
    int bm = blockIdx.y * 256;
    int lane = tid & 63;
    int w = tid >> 6;
    int wm = w >> 2, wn = w & 3;
    int ml = lane & 15, kq = lane >> 4;
    int rsub = lane >> 2;
    int ksw = (((lane & 3) ^ ((lane >> 3) & 3))) * 8;
    int slot8 = ((kq ^ ((ml >> 1) & 3))) * 8;

    f4 acc[8][4];
    #pragma unroll
    for (int i = 0; i < 8; ++i)
        #pragma unroll
        for (int j = 0; j < 4; ++j)
            acc[i][j] = (f4){0.f, 0.f, 0.f, 0.f};

    for (int kt = 0; kt < D_; kt += 32) {
        __syncthreads();
        #pragma unroll
        for (int j = 0; j < 2; ++j) {
            int row = w * 32 + j * 16;
            size_t ga = (size_t)(bm + row + rsub) * D_ + kt + ksw;
            size_t gb = (size_t)(bn + row + rsub) * D_ + kt + ksw;
            async_cp16(Ah + ga, &Ahs[row * 32]);
            async_cp16(Al + ga, &Als[row * 32]);
            async_cp16(Bh + gb, &Bhs[row * 32]);
            async_cp16(Bl + gb, &Bls[row * 32]);
        }
        __syncthreads();
        bfrag bh[4], bl[4];
        #pragma unroll
        for (int ni = 0; ni < 4; ++ni) {
            int brow = wn * 64 + ni * 16 + ml;
            bh[ni] = *(const bfrag*)&Bhs[brow * 32 + slot8];
            bl[ni] = *(const bfrag*)&Bls[brow * 32 + slot8];
        }
        #pragma unroll
        for (int mi = 0; mi < 8; ++mi) {
            int arow = wm * 128 + mi * 16 + ml;
            bfrag ah = *(const bfrag*)&Ahs[arow * 32 + slot8];
            bfrag al = *(const bfrag*)&Als[arow * 32 + slot8];
            #pragma unroll
            for (int ni = 0; ni < 4; ++ni) {
                acc[mi][ni] = __builtin_amdgcn_mfma_f32_16x16x32_bf16(ah, bh[ni], acc[mi][ni], 0, 0, 0);
                acc[mi][ni] = __builtin_amdgcn_mfma_f32_16x16x32_bf16(al, bh[ni], acc[mi][ni], 0, 0, 0);
                acc[mi][ni] = __builtin_amdgcn_mfma_f32_16x16x32_bf16(ah, bl[ni], acc[mi][ni], 0, 0, 0);
            }
        }
    }
    #pragma unroll
    for (int ni = 0; ni < 4; ++ni) {
        int col = bn + wn * 64 + ni * 16 + ml;
        float bv = bias[col];
        #pragma unroll
        for (int mi = 0; mi < 8; ++mi) {
            int row0 = bm + wm * 128 + mi * 16 + kq * 4;
            #pragma unroll
            for (int r = 0; r < 4; ++r) {
                float o = acc[mi][ni][r] + bv;
                size_t idx = (size_t)(row0 + r) * D_ + col;
                if (mode == 2) {
                    unsigned u = __float_as_uint(o);
                    float lo = o - __uint_as_float(u & 0xffff0000u);
                    Ch[idx] = (unsigned short)(u >> 16);
                    Cl[idx] = (unsigned short)(__float_as_uint(lo) >> 16);
                } else {
                    if (mode == 1) o = fmaxf(o, 0.f);
                    C[idx] = o;
                }
            }
        }
    }
}

// ---------------- MFMA key side, atomic-free C_u, single-bf16 phase1 ----------------
// grid (NSPLIT_=16, 64): x = n-split (256 rows), y = bh. 4 waves.
__global__ __launch_bounds__(256) void kside(
    const float* __restrict__ Kin, const float* __restrict__ Vin,
    const float* __restrict__ proj,
    float* __restrict__ S_u, float* __restrict__ Cpart, float* __restrict__ C_u,
    float* __restrict__ Vsum, unsigned int* __restrict__ mxp)
{
    __shared__ __align__(16) unsigned short Kh[64 * KP_];      // [n][d] bf16 RNE (pre-scaled by dn)
    __shared__ __align__(16) unsigned short VT[64 * KP_];      // [dh][n] bf16 RNE
    __shared__ __align__(16) unsigned short Ph[2][64 * KP_];   // proj [m][d] bf16 RNE, ping-pong
    __shared__ __align__(16) unsigned short Us[64 * KP_];      // [m][n] bf16 RNE
    __shared__ __align__(16) float Ssum[MP_];
    __shared__ float diag[64];
    float* redf = (float*)Us;   // overlay (lifetimes separated by barriers)

    int bh = blockIdx.y, b = bh >> 4, h = bh & 15;
    int s = blockIdx.x;
    int n0 = s * 256;
    int tid = threadIdx.x, lane = tid & 63, w = tid >> 6;
    int ml = lane & 15, quad = lane >> 4;

    float* dstC = (s < NSPLIT_ - 1) ? (Cpart + (size_t)s * PARTSZ_) : C_u;

    for (int i = tid; i < MP_; i += 256) Ssum[i] = 0.f;

    f4 acc[5][4];
    #pragma unroll
    for (int i = 0; i < 5; ++i)
        #pragma unroll
        for (int j = 0; j < 4; ++j) acc[i][j] = (f4){0.f, 0.f, 0.f, 0.f};
    float vs[4] = {0.f, 0.f, 0.f, 0.f};
    float lmax = -1e30f;

    for (int nc = 0; nc < 4; ++nc) {
        __syncthreads();
        // stage K (RNE, *dn), V^T (RNE), diag partials, and proj chunk 0
        #pragma unroll
        for (int l = 0; l < 4; ++l) {
            int idx = tid + 256 * l;
            int r = idx >> 4;
            int d4 = (idx & 15) * 4;
            size_t g = ((size_t)(b * N_ + n0 + nc * 64 + r)) * D_ + h * DH_ + d4;
            const float4 kv = *(const float4*)(Kin + g);
            redf[r * 17 + (tid & 15)] = kv.x * kv.x + kv.y * kv.y + kv.z * kv.z + kv.w * kv.w;
            unsigned w0 = (unsigned)bf16rne(kv.x * DN_) | ((unsigned)bf16rne(kv.y * DN_) << 16);
            unsigned w1 = (unsigned)bf16rne(kv.z * DN_) | ((unsigned)bf16rne(kv.w * DN_) << 16);
            *(uint2*)&Kh[r * KP_ + d4] = make_uint2(w0, w1);
            const float4 vv = *(const float4*)(Vin + g);
            vs[0] += vv.x; vs[1] += vv.y; vs[2] += vv.z; vs[3] += vv.w;
            VT[(d4 + 0) * KP_ + r] = bf16rne(vv.x);
            VT[(d4 + 1) * KP_ + r] = bf16rne(vv.y);
            VT[(d4 + 2) * KP_ + r] = bf16rne(vv.z);
            VT[(d4 + 3) * KP_ + r] = bf16rne(vv.w);
        }
        {   // proj chunk 0 -> Ph[0]
            #pragma unroll
            for (int l = 0; l < 2; ++l) {
                int idx = tid + 256 * l;
                int m = idx >> 3, d8 = (idx & 7) * 8;
                const float4 p0 = *(const float4*)(proj + m * 64 + d8);
                const float4 p1 = *(const float4*)(proj + m * 64 + d8 + 4);
                unsigned a0 = (unsigned)bf16rne(p0.x) | ((unsigned)bf16rne(p0.y) << 16);
                unsigned a1 = (unsigned)bf16rne(p0.z) | ((unsigned)bf16rne(p0.w) << 16);
                unsigned a2 = (unsigned)bf16rne(p1.x) | ((unsigned)bf16rne(p1.y) << 16);
                unsigned a3 = (unsigned)bf16rne(p1.z) | ((unsigned)bf16rne(p1.w) << 16);
                *(uint4*)&Ph[0][m * KP_ + d8] = make_uint4(a0, a1, a2, a3);
            }
        }
        __syncthreads();
        if (tid < 64) {
            float ss = 0.f;
            #pragma unroll
            for (int p = 0; p < 16; ++p) ss += redf[tid * 17 + p];
            diag[tid] = ss * 0.0625f;
        }
        __syncthreads();

        bfrag kh0 = *(const bfrag*)&Kh[(w * 16 + ml) * KP_ + quad * 8];
        bfrag kh1 = *(const bfrag*)&Kh[(w * 16 + ml) * KP_ + 32 + quad * 8];
        float dgv[4];
        #pragma unroll
        for (int r = 0; r < 4; ++r) dgv[r] = diag[w * 16 + quad * 4 + r];

        for (int mc = 0; mc < 5; ++mc) {
            int pb = mc & 1;
            // prefetch next proj chunk (loads overlap phase-1 MFMA)
            float4 pf[4];
            if (mc < 4) {
                #pragma unroll
                for (int l = 0; l < 2; ++l) {
                    int idx = tid + 256 * l;
                    int m = idx >> 3, d8 = (idx & 7) * 8;
                    int mg = (mc + 1) * 64 + m;
                    if (mg < M_) {
                        pf[l * 2 + 0] = *(const float4*)(proj + mg * 64 + d8);
                        pf[l * 2 + 1] = *(const float4*)(proj + mg * 64 + d8 + 4);
                    } else {
                        pf[l * 2 + 0] = make_float4(0.f, 0.f, 0.f, 0.f);
                        pf[l * 2 + 1] = make_float4(0.f, 0.f, 0.f, 0.f);
                    }
                }
            }
            // phase 1: td[n][m] tiles, single-bf16
            #pragma unroll
            for (int mt = 0; mt < 4; ++mt) {
                int mrow = mt * 16 + ml;
                bfrag ph0 = *(const bfrag*)&Ph[pb][mrow * KP_ + quad * 8];
                bfrag ph1 = *(const bfrag*)&Ph[pb][mrow * KP_ + 32 + quad * 8];
                f4 t = (f4){0.f, 0.f, 0.f, 0.f};
                t = __builtin_amdgcn_mfma_f32_16x16x32_bf16(kh0, ph0, t, 0, 0, 0);
                t = __builtin_amdgcn_mfma_f32_16x16x32_bf16(kh1, ph1, t, 0, 0, 0);
                bool mv = (mc * 64 + mrow) < M_;
                float su = 0.f;
                unsigned short up[4];
                #pragma unroll
                for (int r = 0; r < 4; ++r) {
                    float u = 0.f;
                    if (mv) {
                        float tt = t[r];
                        lmax = fmaxf(lmax, tt);
                        u = __expf(tt - dgv[r]);
                    }
                    su += u;
                    up[r] = bf16rne(u);
                }
                su += __shfl_xor(su, 16);
                su += __shfl_xor(su, 32);
                if (mv && quad == 0) atomicAdd(&Ssum[mc * 64 + mrow], su);
                unsigned w0 = (unsigned)up[0] | ((unsigned)up[1] << 16);
                unsigned w1 = (unsigned)up[2] | ((unsigned)up[3] << 16);
                *(uint2*)&Us[mrow * KP_ + w * 16 + quad * 4] = make_uint2(w0, w1);
            }
            // store prefetched proj
            if (mc < 4) {
                #pragma unroll
                for (int l = 0; l < 2; ++l) {
                    int idx = tid + 256 * l;
                    int m = idx >> 3, d8 = (idx & 7) * 8;
                    const float4 p0 = pf[l * 2 + 0], p1 = pf[l * 2 + 1];
                    unsigned a0 = (unsigned)bf16rne(p0.x) | ((unsigned)bf16rne(p0.y) << 16);
                    unsigned a1 = (unsigned)bf16rne(p0.z) | ((unsigned)bf16rne(p0.w) << 16);
                    unsigned a2 = (unsigned)bf16rne(p1.x) | ((unsigned)bf16rne(p1.y) << 16);
                    unsigned a3 = (unsigned)bf16rne(p1.z) | ((unsigned)bf16rne(p1.w) << 16);
                    *(uint4*)&Ph[1 - pb][m * KP_ + d8] = make_uint4(a0, a1, a2, a3);
                }
            }
            __syncthreads();
            // phase 2: acc[mc] += Us^T-tile @ V
            bfrag ua0 = *(const bfrag*)&Us[(w * 16 + ml) * KP_ + quad * 8];
            bfrag ua1 = *(const bfrag*)&Us[(w * 16 + ml) * KP_ + 32 + quad * 8];
            #pragma unroll
            for (int dt = 0; dt < 4; ++dt) {
                bfrag vb0 = *(const bfrag*)&VT[(dt * 16 + ml) * KP_ + quad * 8];
                bfrag vb1 = *(const bfrag*)&VT[(dt * 16 + ml) * KP_ + 32 + quad * 8];
                acc[mc][dt] = __builtin_amdgcn_mfma_f32_16x16x32_bf16(ua0, vb0, acc[mc][dt], 0, 0, 0);
                acc[mc][dt] = __builtin_amdgcn_mfma_f32_16x16x32_bf16(ua1, vb1, acc[mc][dt], 0, 0, 0);
            }
            __syncthreads();
        }
    }
    // epilogue: C_u partial, PLAIN stores (no atomics)
    #pragma unroll
    for (int mc = 0; mc < 5; ++mc)
        #pragma unroll
        for (int dt = 0; dt < 4; ++dt)
            #pragma unroll
            for (int r = 0; r < 4; ++r) {
                int m = mc * 64 + w * 16 + quad * 4 + r;
                if (m < M_)
                    dstC[((size_t)bh * M_ + m) * 64 + dt * 16 + ml] = acc[mc][dt][r];
            }
    __syncthreads();
    for (int m = tid; m < M_; m += 256)
        atomicAdd(S_u + bh * M_ + m, Ssum[m]);
    #pragma unroll
    for (int off = 32; off; off >>= 1) lmax = fmaxf(lmax, __shfl_xor(lmax, off));
    __syncthreads();
    if (lane == 0) redf[w] = lmax;
    __syncthreads();
    if (tid == 0) {
        float mxv = fmaxf(fmaxf(redf[0], redf[1]), fmaxf(redf[2], redf[3]));
        atomicMax(mxp + bh, f2ord(mxv));
    }
    for (int j = 0; j < 4; ++j) {
        __syncthreads();
        redf[tid] = vs[j];
        __syncthreads();
        if (tid < 16) {
            float ss = 0.f;
            #pragma unroll
            for (int p = 0; p < 16; ++p) ss += redf[tid + 16 * p];
            atomicAdd(Vsum + bh * 64 + tid * 4 + j, ss);
        }
    }
}

// ---------------- finalize: sum 16 partials, build ks + ctxT(split) + Cs + kss ----------------
// grid (5, 64): x = m-chunk, y = bh
__global__ __launch_bounds__(256) void finalize_kernel(
    const float* __restrict__ S_u, const float* __restrict__ Cpart, const float* __restrict__ C_u,
    const float* __restrict__ Vsum, const unsigned* __restrict__ mxp,
    float* __restrict__ ksum_f, unsigned short* __restrict__ ctxTh,
    unsigned short* __restrict__ ctxTl, float* __restrict__ Cs, float* __restrict__ kss)
{
    __shared__ float T[64 * 65];
    __shared__ float red[256];
    int mc = blockIdx.x, bh = blockIdx.y;
    int tid = threadIdx.x;
    float emx = __expf(-ord2f(mxp[bh]));

    float csacc = 0.f;   // dh = tid&63 fixed across iterations
    #pragma unroll
    for (int i = 0; i < 16; ++i) {
        int idx = i * 256 + tid;
        int dh = idx & 63, mloc = idx >> 6;
        int m = mc * 64 + mloc;
        float v = 0.f;
        if (m < M_) {
            size_t off = ((size_t)bh * M_ + m) * 64 + dh;
            float sacc = C_u[off];
            for (int sp = 0; sp < NSPLIT_ - 1; ++sp)
                sacc += Cpart[(size_t)sp * PARTSZ_ + off];
            v = RATIO_ * (emx * sacc + EPS_ * Vsum[bh * 64 + dh]);
        }
        T[mloc * 65 + dh] = v;
        csacc += v;
    }
    red[tid] = csacc;
    __syncthreads();
    if (tid < 64) atomicAdd(&Cs[bh * 64 + tid], red[tid] + red[tid + 64] + red[tid + 128] + red[tid + 192]);
    // ks + kss
    float ksl = 0.f;
    if (tid < 64) {
        int m = mc * 64 + tid;
        float kv = (m < M_) ? RATIO_ * (emx * S_u[bh * M_ + m] + EPS_ * (float)N_) : 0.f;
        ksum_f[bh * MP_ + m] = kv;
        ksl = kv;
    }
    __syncthreads();
    red[tid] = ksl;
    __syncthreads();
    if (tid == 0) {
        float ss = 0.f;
        for (int p = 0; p < 64; ++p) ss += red[p];
        atomicAdd(kss + bh, ss);
    }
    __syncthreads();
    // transposed split writes: ctxT[dh][m]
    #pragma unroll
    for (int i = 0; i < 8; ++i) {
        int idx = i * 256 + tid;
        int dh = idx >> 5, m2 = (idx & 31) * 2;
        float v0 = T[m2 * 65 + dh], v1 = T[(m2 + 1) * 65 + dh];
        unsigned u0 = __float_as_uint(v0), u1 = __float_as_uint(v1);
        float lo0 = v0 - __uint_as_float(u0 & 0xffff0000u);
        float lo1 = v1 - __uint_as_float(u1 & 0xffff0000u);
        size_t dst = ((size_t)(bh * 64 + dh)) * MP_ + mc * 64 + m2;
        *(unsigned*)&ctxTh[dst] = (u0 >> 16) | (u1 & 0xffff0000u);
        *(unsigned*)&ctxTl[dst] = (__float_as_uint(lo0) >> 16) | (__float_as_uint(lo1) & 0xffff0000u);
    }
}

// ---------------- MFMA query side (epilogue writes split-bf16 attn) ----------------
__global__ __launch_bounds__(256) void qattn(
    const float* __restrict__ Q, const float* __restrict__ proj,
    const float* __restrict__ ksum_f, const unsigned short* __restrict__ ctxTh,
    const unsigned short* __restrict__ ctxTl,
    const float* __restrict__ Cs, const float* __restrict__ kss,
    unsigned short* __restrict__ attnH, unsigned short* __restrict__ attnL)
{
    __shared__ __align__(16) unsigned short Qh[64 * KP_], Ql[64 * KP_];
    __shared__ __align__(16) unsigned short Ph[64 * KP_], Pl[64 * KP_];
    __shared__ __align__(16) unsigned short Uh[64 * KP_], Ul[64 * KP_];
    __shared__ __align__(16) float ks[MP_];
    __shared__ float diag[64];
    float* redf = (float*)Uh;

    int bh = blockIdx.y, b = bh >> 4, h = bh & 15;
    int n0 = blockIdx.x * 64;
    int tid = threadIdx.x, lane = tid & 63, w = tid >> 6;
    int ml = lane & 15, quad = lane >> 4;

    #pragma unroll
    for (int l = 0; l < 4; ++l) {
        int idx = tid + 256 * l;
        int r = idx >> 4, d4 = (idx & 15) * 4;
        size_t g = ((size_t)(b * N_ + n0 + r)) * D_ + h * DH_ + d4;
        const float4 qv = *(const float4*)(Q + g);
        redf[r * 17 + (tid & 15)] = qv.x * qv.x + qv.y * qv.y + qv.z * qv.z + qv.w * qv.w;
        unsigned h0, l0, h1, l1;
        split2pack(qv.x * DN_, qv.y * DN_, &h0, &l0);
        split2pack(qv.z * DN_, qv.w * DN_, &h1, &l1);
        *(uint2*)&Qh[r * KP_ + d4] = make_uint2(h0, h1);
        *(uint2*)&Ql[r * KP_ + d4] = make_uint2(l0, l1);
    }
    for (int m = tid; m < MP_; m += 256) ks[m] = ksum_f[bh * MP_ + m];
    __syncthreads();
    if (tid < 64) {
        float s = 0.f;
        #pragma unroll
        for (int p = 0; p < 16; ++p) s += redf[tid * 17 + p];
        diag[tid] = s * 0.0625f;
    }
    __syncthreads();

    bfrag qh0 = *(const bfrag*)&Qh[(w * 16 + ml) * KP_ + quad * 8];
    bfrag ql0 = *(const bfrag*)&Ql[(w * 16 + ml) * KP_ + quad * 8];
    bfrag qh1 = *(const bfrag*)&Qh[(w * 16 + ml) * KP_ + 32 + quad * 8];
    bfrag ql1 = *(const bfrag*)&Ql[(w * 16 + ml) * KP_ + 32 + quad * 8];
    float dg = diag[w * 16 + ml];
    float dacc = 0.f, tmax = -1e30f;
    f4 oacc[4];
    #pragma unroll
    for (int i = 0; i < 4; ++i) oacc[i] = (f4){0.f, 0.f, 0.f, 0.f};

    for (int mc = 0; mc < 5; ++mc) {
        #pragma unroll
        for (int l = 0; l < 4; ++l) {
            int idx = tid + 256 * l;
            int m = idx >> 4, d4 = (idx & 15) * 4;
            int mg = mc * 64 + m;
            float4 p = make_float4(0.f, 0.f, 0.f, 0.f);
            if (mg < M_) p = *(const float4*)(proj + mg * 64 + d4);
            unsigned h0, l0, h1, l1;
            split2pack(p.x, p.y, &h0, &l0);
            split2pack(p.z, p.w, &h1, &l1);
            *(uint2*)&Ph[m * KP_ + d4] = make_uint2(h0, h1);
            *(uint2*)&Pl[m * KP_ + d4] = make_uint2(l0, l1);
        }
        __syncthreads();
        #pragma unroll
        for (int mt = 0; mt < 4; ++mt) {
            int mrow = mt * 16 + ml;
            bfrag ph0 = *(const bfrag*)&Ph[mrow * KP_ + quad * 8];
            bfrag pl0 = *(const bfrag*)&Pl[mrow * KP_ + quad * 8];
            bfrag ph1 = *(const bfrag*)&Ph[mrow * KP_ + 32 + quad * 8];
            bfrag pl1 = *(const bfrag*)&Pl[mrow * KP_ + 32 + quad * 8];
            f4 t = (f4){0.f, 0.f, 0.f, 0.f};
            t = __builtin_amdgcn_mfma_f32_16x16x32_bf16(ph0, qh0, t, 0, 0, 0);
            t = __builtin_amdgcn_mfma_f32_16x16x32_bf16(pl0, qh0, t, 0, 0, 0);
            t = __builtin_amdgcn_mfma_f32_16x16x32_bf16(ph0, ql0, t, 0, 0, 0);
            t = __builtin_amdgcn_mfma_f32_16x16x32_bf16(ph1, qh1, t, 0, 0, 0);
            t = __builtin_amdgcn_mfma_f32_16x16x32_bf16(pl1, qh1, t, 0, 0, 0);
            t = __builtin_amdgcn_mfma_f32_16x16x32_bf16(ph1, ql1, t, 0, 0, 0);
            const float4 ksv = *(const float4*)&ks[mc * 64 + mt * 16 + quad * 4];
            float ksa[4] = {ksv.x, ksv.y, ksv.z, ksv.w};
            unsigned short uh4[4], ul4[4];
            #pragma unroll
            for (int r = 0; r < 4; ++r) {
                int mg = mc * 64 + mt * 16 + quad * 4 + r;
                float tt = t[r];
                float u = __expf(tt - dg);
                if (mg < M_) tmax = fmaxf(tmax, tt);
                dacc = fmaf(u, ksa[r], dacc);
                unsigned uu = __float_as_uint(u);
                float lo = u - __uint_as_float(uu & 0xffff0000u);
                uh4[r] = (unsigned short)(uu >> 16);
                ul4[r] = (unsigned short)(__float_as_uint(lo) >> 16);
            }
            unsigned a0 = (unsigned)uh4[0] | ((unsigned)uh4[1] << 16);
            unsigned a1 = (unsigned)uh4[2] | ((unsigned)uh4[3] << 16);
            unsigned b0 = (unsigned)ul4[0] | ((unsigned)ul4[1] << 16);
            unsigned b1 = (unsigned)ul4[2] | ((unsigned)ul4[3] << 16);
            *(uint2*)&Uh[(w * 16 + ml) * KP_ + mt * 16 + quad * 4] = make_uint2(a0, a1);
            *(uint2*)&Ul[(w * 16 + ml) * KP_ + mt * 16 + quad * 4] = make_uint2(b0, b1);
        }
        __syncthreads();
        #pragma unroll
        for (int l = 0; l < 2; ++l) {
            int idx = tid + 256 * l;
            int dh = idx >> 3, m8 = (idx & 7) * 8;
            size_t src = ((size_t)(bh * 64 + dh)) * MP_ + mc * 64 + m8;
            *(uint4*)&Ph[dh * KP_ + m8] = *(const uint4*)(ctxTh + src);
            *(uint4*)&Pl[dh * KP_ + m8] = *(const uint4*)(ctxTl + src);
        }
        __syncthreads();
        bfrag ua0h = *(const bfrag*)&Uh[(w * 16 + ml) * KP_ + quad * 8];
        bfrag ua0l = *(const bfrag*)&Ul[(w * 16 + ml) * KP_ + quad * 8];
        bfrag ua1h = *(const bfrag*)&Uh[(w * 16 + ml) * KP_ + 32 + quad * 8];
        bfrag ua1l = *(const bfrag*)&Ul[(w * 16 + ml) * KP_ + 32 + quad * 8];
        #pragma unroll
        for (int dt = 0; dt < 4; ++dt) {
            bfrag cb0h = *(const bfrag*)&Ph[(dt * 16 + ml) * KP_ + quad * 8];
            bfrag cb0l = *(const bfrag*)&Pl[(dt * 16 + ml) * KP_ + quad * 8];
            bfrag cb1h = *(const bfrag*)&Ph[(dt * 16 + ml) * KP_ + 32 + quad * 8];
            bfrag cb1l = *(const bfrag*)&Pl[(dt * 16 + ml) * KP_ + 32 + quad * 8];
            oacc[dt] = __builtin_amdgcn_mfma_f32_16x16x32_bf16(ua0h, cb0h, oacc[dt], 0, 0, 0);
            oacc[dt] = __builtin_amdgcn_mfma_f32_16x16x32_bf16(ua0l, cb0h, oacc[dt], 0, 0, 0);
            oacc[dt] = __builtin_amdgcn_mfma_f32_16x16x32_bf16(ua0h, cb0l, oacc[dt], 0, 0, 0);
            oacc[dt] = __builtin_amdgcn_mfma_f32_16x16x32_bf16(ua1h, cb1h, oacc[dt], 0, 0, 0);
            oacc[dt] = __builtin_amdgcn_mfma_f32_16x16x32_bf16(ua1l, cb1h, oacc[dt], 0, 0, 0);
            oacc[dt] = __builtin_amdgcn_mfma_f32_16x16x32_bf16(ua1h, cb1l, oacc[dt], 0, 0, 0);
        }
        __syncthreads();
    }
    dacc += __shfl_xor(dacc, 16); dacc += __shfl_xor(dacc, 32);
    tmax = fmaxf(tmax, __shfl_xor(tmax, 16));
    tmax = fmaxf(tmax, __shfl_xor(tmax, 32));
    float fac = EPS_ * __expf(tmax);
    float dinv = 1.f / (dacc + fac * kss[bh]);
    #pragma unroll
    for (int dt = 0; dt < 4; ++dt) {
        float csv = Cs[bh * 64 + dt * 16 + ml];
        #pragma unroll
        for (int r = 0; r < 4; ++r) {
            int srcl = quad * 4 + r;
            float dv = __shfl(dinv, srcl);
            float fv = __shfl(fac, srcl);
            float o = (oacc[dt][r] + fv * csv) * dv;
            int n = n0 + w * 16 + quad * 4 + r;
            size_t gi = ((size_t)(b * N_ + n)) * D_ + h * DH_ + dt * 16 + ml;
            unsigned u = __float_as_uint(o);
            float lo = o - __uint_as_float(u & 0xffff0000u);
            attnH[gi] = (unsigned short)(u >> 16);
            attnL[gi] = (unsigned short)(__float_as_uint(lo) >> 16);
        }
    }
}

// ---------------- launch ----------------
extern "C" void kernel_launch(void* const* d_in, const int* in_sizes, int n_in,
                              void* d_out, int out_size, void* d_ws, size_t ws_size,
                              hipStream_t stream)
{
    const float* x    = (const float*)d_in[0];
    const float* Wq   = (const float*)d_in[1];
    const float* bq   = (const float*)d_in[2];
    const float* Wk   = (const float*)d_in[3];
    const float* bk   = (const float*)d_in[4];
    const float* Wv   = (const float*)d_in[5];
    const float* bv   = (const float*)d_in[6];
    const float* Wo   = (const float*)d_in[7];
    const float* bo   = (const float*)d_in[8];
    const float* Wfc  = (const float*)d_in[9];
    const float* bfc  = (const float*)d_in[10];
    const float* proj = (const float*)d_in[11];
    float* out = (float*)d_out;

    float* ws = (float*)d_ws;
    const size_t nTok = (size_t)B_ * N_ * D_;
    const size_t nSu  = 64 * M_;
    const size_t nCu  = (size_t)64 * M_ * 64;
    const size_t nVs  = 64 * 64;
    const size_t nMx  = 64;
    const size_t nKsf = 64 * MP_;
    const size_t nCtx = (size_t)64 * MP_ * 64;
    const size_t nCs  = 64 * 64;

    const size_t offQ   = 0;
    const size_t offK   = nTok;
    const size_t offV   = nTok * 2;
    const size_t offSu  = nTok * 3;
    const size_t offCu  = offSu + nSu;
    const size_t offVs  = offCu + nCu;
    const size_t offMx  = offVs + nVs;
    const size_t offKsf = offMx + nMx;
    const size_t offCtx = offKsf + nKsf;
    const size_t offCs  = offCtx + nCtx;
    const size_t offKss = offCs + nCs;
    const size_t offWsp = offKss + 64;      // 5 weights split: 5 * 1048576 float-slots

    float* Q    = ws + offQ;
    float* Kb   = ws + offK;
    float* Vb   = ws + offV;
    float* S_u  = ws + offSu;
    float* C_u  = ws + offCu;
    float* Vsum = ws + offVs;
    unsigned* mx = (unsigned*)(ws + offMx);
    float* ksf  = ws + offKsf;
    unsigned short* ctxTh = (unsigned short*)(ws + offCtx);
    unsigned short* ctxTl = ctxTh + (size_t)64 * 64 * MP_;
    float* Cs   = ws + offCs;
    float* kss  = ws + offKss;
    unsigned short* Wsp = (unsigned short*)(ws + offWsp);

    // scratch overlays (stream-ordered lifetimes):
    unsigned short* xh = (unsigned short*)out;        // x split lives in d_out, dead before kside
    unsigned short* xl = xh + nTok;
    unsigned short* attnH = (unsigned short*)Kb;      // K dead after kside
    unsigned short* attnL = attnH + nTok;
    unsigned short* hbH = (unsigned short*)Vb;        // V dead after kside
    unsigned short* hbL = hbH + nTok;
    float* Cpart = out;                               // d_out as scratch for 15 C_u partials

    // zero S_u..kss (covers S_u, C_u, Vsum, mx, ksf, ctxT, Cs, kss)
    int nzero = (int)(nSu + nCu + nVs + nMx + nKsf + nCtx + nCs + 64);
    zero_kernel<<<dim3((nzero + 255) / 256), dim3(256), 0, stream>>>(S_u, nzero);

    // one-shot splits
    split_f32<<<dim3(16384), dim3(256), 0, stream>>>(x, xh, xl, (int)(nTok / 4));
    split_w5<<<dim3(1024, 5), dim3(256), 0, stream>>>(Wq, Wk, Wv, Wo, Wfc, Wsp);

    gemm_qkv_s<<<dim3(12, (B_ * N_) / 256), dim3(512), 0, stream>>>(
        xh, xl, Wsp, bq, bk, bv, Q, Kb, Vb);

    kside<<<dim3(NSPLIT_, 64), dim3(256), 0, stream>>>(Kb, Vb, proj, S_u, Cpart, C_u, Vsum, mx);
    finalize_kernel<<<dim3(5, 64), dim3(256), 0, stream>>>(S_u, Cpart, C_u, Vsum, mx, ksf, ctxTh, ctxTl, Cs, kss);
    qattn<<<dim3(64, 64), dim3(256), 0, stream>>>(Q, proj, ksf, ctxTh, ctxTl, Cs, kss, attnH, attnL);

    dim3 gg(D_ / 256, (B_ * N_) / 256);
    // Wo: split-bf16 A (attn) -> split-bf16 hbuf
    gemm_nt_s<<<gg, dim3(512), 0, stream>>>(attnH, attnL,
        Wsp + (size_t)3 * 2097152, Wsp + (size_t)3 * 2097152 + 1048576,
        bo, (float*)nullptr, hbH, hbL, 2);
    // Wfc: split-bf16 A (hbuf) -> fp32 out + relu
    gemm_nt_s<<<gg, dim3(512), 0, stream>>>(hbH, hbL,
        Wsp + (size_t)4 * 2097152, Wsp + (size_t)4 * 2097152 + 1048576,
        bfc, out, (unsigned short*)nullptr, (unsigned short*)nullptr, 1);
}

// Round 7
// 988.068 us; speedup vs baseline: 1.1133x; 1.0208x over previous
//
#include <hip/hip_runtime.h>
#include <math.h>

#define B_ 4
#define N_ 4096
#define D_ 1024
#define H_ 16
#define DH_ 64
#define M_ 266
#define MP_ 320   // M padded to 5 chunks of 64

#define DN_ 0.35355339059327373f      // 64^-0.25
#define RATIO_ 0.06131393394849658f   // 266^-0.5
#define EPS_ 1e-4f
#define KP_ 72    // ushort row stride
#define NSPLIT_ 16
#define PARTSZ_ ((size_t)64 * M_ * 64)   // one C_u partial (all bh)

typedef __attribute__((ext_vector_type(8))) short bfrag;
typedef __attribute__((ext_vector_type(4))) float f4;

__device__ __forceinline__ unsigned f2ord(float f) {
    unsigned u = __float_as_uint(f);
    return (u & 0x80000000u) ? ~u : (u | 0x80000000u);
}
__device__ __forceinline__ float ord2f(unsigned u) {
    unsigned b = (u & 0x80000000u) ? (u & 0x7fffffffu) : ~u;
    return __uint_as_float(b);
}

__global__ void zero_kernel(float* __restrict__ p, int n) {
    int i = blockIdx.x * 256 + threadIdx.x;
    if (i < n) p[i] = 0.f;
}

__device__ __forceinline__ void split2pack(float x, float y, unsigned* hp, unsigned* lp) {
    unsigned ux = __float_as_uint(x), uy = __float_as_uint(y);
    float hx = __uint_as_float(ux & 0xffff0000u);
    float hy = __uint_as_float(uy & 0xffff0000u);
    float lx = x - hx, ly = y - hy;
    *hp = (ux >> 16) | (uy & 0xffff0000u);
    *lp = (__float_as_uint(lx) >> 16) | (__float_as_uint(ly) & 0xffff0000u);
}
__device__ __forceinline__ unsigned short bf16rne(float x) {
    unsigned u = __float_as_uint(x);
    return (unsigned short)((u + 0x7fffu + ((u >> 16) & 1u)) >> 16);
}

// async global->LDS 16B (dwordx4). LDS dst must be wave-uniform; lane writes dst+lane*16.
__device__ __forceinline__ void async_cp16(const void* g, void* l) {
    __builtin_amdgcn_global_load_lds(
        (const __attribute__((address_space(1))) void*)g,
        (__attribute__((address_space(3))) void*)l, 16, 0, 0);
}

// ---------------- one-shot split conversions (each element converted exactly once) --------
__global__ __launch_bounds__(256) void split_f32(const float* __restrict__ X,
        unsigned short* __restrict__ Xh, unsigned short* __restrict__ Xl, int n4)
{
    int i = blockIdx.x * 256 + threadIdx.x;
    if (i >= n4) return;
    const float4 v = ((const float4*)X)[i];
    unsigned h0, l0, h1, l1;
    split2pack(v.x, v.y, &h0, &l0);
    split2pack(v.z, v.w, &h1, &l1);
    ((uint2*)Xh)[i] = make_uint2(h0, h1);
    ((uint2*)Xl)[i] = make_uint2(l0, l1);
}

// 5 weights (1024x1024 each) -> Wsp: per sel, h at sel*2097152, l at +1048576 (ushort units)
__global__ __launch_bounds__(256) void split_w5(const float* __restrict__ W0,
        const float* __restrict__ W1, const float* __restrict__ W2,
        const float* __restrict__ W3, const float* __restrict__ W4,
        unsigned short* __restrict__ Wsp)
{
    int sel = blockIdx.y;
    const float* W = (sel == 0) ? W0 : (sel == 1) ? W1 : (sel == 2) ? W2 : (sel == 3) ? W3 : W4;
    unsigned short* h = Wsp + (size_t)sel * 2097152;
    unsigned short* l = h + 1048576;
    int i = blockIdx.x * 256 + threadIdx.x;   // 1024*256 threads * 4 elems = 1048576
    const float4 v = ((const float4*)W)[i];
    unsigned h0, l0, h1, l1;
    split2pack(v.x, v.y, &h0, &l0);
    split2pack(v.z, v.w, &h1, &l1);
    ((uint2*)h)[i] = make_uint2(h0, h1);
    ((uint2*)l)[i] = make_uint2(l0, l1);
}

// proj (266x64) pre-converted ONCE, padded to MP_ rows with zeros:
//   projR  : bf16 RNE (kside phase-1 operand)
//   projHg/projLg : truncate-split hi/lo (qattn phase-1 operand)
// Removes per-block re-split in kside (1024 blocks) and qattn (4096 blocks x5 chunks).
// Bit-identical values to the previous in-kernel conversion.
__global__ __launch_bounds__(256) void presplit_proj(const float* __restrict__ proj,
        unsigned short* __restrict__ projR, unsigned short* __restrict__ projHg,
        unsigned short* __restrict__ projLg)
{
    int i = blockIdx.x * 256 + threadIdx.x;   // 80 blocks * 256 = 20480 = MP_*64
    int m = i >> 6, d = i & 63;
    float v = (m < M_) ? proj[m * 64 + d] : 0.f;
    projR[i] = bf16rne(v);
    unsigned u = __float_as_uint(v);
    float lo = v - __uint_as_float(u & 0xffff0000u);
    projHg[i] = (unsigned short)(u >> 16);
    projLg[i] = (unsigned short)(__float_as_uint(lo) >> 16);
}

// ---------------- fused QKV GEMM (128x128 stage-serial, proven 313us) ----------------------
// LDS 16B-granule swizzle: granule (row,slot) at slot^((row>>1)&3); write side = linear LDS
// dst + pre-swizzled GLOBAL source slot (ksw), read side = slot8. Conflict-free (verified R2).
__global__ __launch_bounds__(256) void gemm_qkv_s(
        const unsigned short* __restrict__ Ah, const unsigned short* __restrict__ Al,
        const unsigned short* __restrict__ Wsp,
        const float* __restrict__ b0, const float* __restrict__ b1, const float* __restrict__ b2,
        float* __restrict__ C0, float* __restrict__ C1, float* __restrict__ C2)
{
    __shared__ __align__(16) unsigned short Ahs[128 * 32];
    __shared__ __align__(16) unsigned short Als[128 * 32];
    __shared__ __align__(16) unsigned short Bhs[128 * 32];
    __shared__ __align__(16) unsigned short Bls[128 * 32];

    int tid = threadIdx.x;
    int sel = blockIdx.x >> 3;               // 0..2 -> q,k,v
    int bn = (blockIdx.x & 7) * 128;
    int bm = blockIdx.y * 128;
    const unsigned short* Bh = Wsp + (size_t)sel * 2097152;
    const unsigned short* Bl = Bh + 1048576;
    const float* bias = (sel == 0) ? b0 : (sel == 1) ? b1 : b2;
    float* C = (sel == 0) ? C0 : (sel == 1) ? C1 : C2;

    int lane = tid & 63;
    int w = tid >> 6;
    int wm = w >> 1, wn = w & 1;
    int ml = lane & 15, kq = lane >> 4;
    int rsub = lane >> 2;
    int ksw = (((lane & 3) ^ ((lane >> 3) & 3))) * 8;   // swizzled source K-slot (ushorts)
    int slot8 = ((kq ^ ((ml >> 1) & 3))) * 8;           // swizzled read K-slot (ushorts)

    f4 acc[4][4];
    #pragma unroll
    for (int i = 0; i < 4; ++i)
        #pragma unroll
        for (int j = 0; j < 4; ++j)
            acc[i][j] = (f4){0.f, 0.f, 0.f, 0.f};

    for (int kt = 0; kt < D_; kt += 32) {
        __syncthreads();
        #pragma unroll
        for (int j = 0; j < 2; ++j) {
            int row = w * 32 + j * 16;                        // wave-uniform
            size_t ga = (size_t)(bm + row + rsub) * D_ + kt + ksw;
            size_t gb = (size_t)(bn + row + rsub) * D_ + kt + ksw;
            async_cp16(Ah + ga, &Ahs[row * 32]);
            async_cp16(Al + ga, &Als[row * 32]);
            async_cp16(Bh + gb, &Bhs[row * 32]);
            async_cp16(Bl + gb, &Bls[row * 32]);
        }
        __syncthreads();
        bfrag ah[4], al[4], bh[4], bl[4];
        #pragma unroll
        for (int i = 0; i < 4; ++i) {
            int arow = wm * 64 + i * 16 + ml;
            ah[i] = *(const bfrag*)&Ahs[arow * 32 + slot8];
            al[i] = *(const bfrag*)&Als[arow * 32 + slot8];
            int brow = wn * 64 + i * 16 + ml;
            bh[i] = *(const bfrag*)&Bhs[brow * 32 + slot8];
            bl[i] = *(const bfrag*)&Bls[brow * 32 + slot8];
        }
        #pragma unroll
        for (int mi = 0; mi < 4; ++mi)
            #pragma unroll
            for (int ni = 0; ni < 4; ++ni) {
                acc[mi][ni] = __builtin_amdgcn_mfma_f32_16x16x32_bf16(ah[mi], bh[ni], acc[mi][ni], 0, 0, 0);
                acc[mi][ni] = __builtin_amdgcn_mfma_f32_16x16x32_bf16(al[mi], bh[ni], acc[mi][ni], 0, 0, 0);
                acc[mi][ni] = __builtin_amdgcn_mfma_f32_16x16x32_bf16(ah[mi], bl[ni], acc[mi][ni], 0, 0, 0);
            }
    }
    #pragma unroll
    for (int ni = 0; ni < 4; ++ni) {
        int col = bn + wn * 64 + ni * 16 + ml;
        float bv = bias[col];
        #pragma unroll
        for (int mi = 0; mi < 4; ++mi) {
            int row0 = bm + wm * 64 + mi * 16 + kq * 4;
            #pragma unroll
            for (int r = 0; r < 4; ++r)
                C[(size_t)(row0 + r) * D_ + col] = acc[mi][ni][r] + bv;
        }
    }
}

// ---------------- generic NT GEMM on pre-split operands (Wo / Wfc) ----------------
// mode 0: fp32+bias; mode 1: fp32+bias+relu; mode 2: split-bf16 write (+bias)
__global__ __launch_bounds__(256) void gemm_nt_s(
        const unsigned short* __restrict__ Ah, const unsigned short* __restrict__ Al,
        const unsigned short* __restrict__ Bh, const unsigned short* __restrict__ Bl,
        const float* __restrict__ bias, float* __restrict__ C,
        unsigned short* __restrict__ Ch, unsigned short* __restrict__ Cl, int mode)
{
    __shared__ __align__(16) unsigned short Ahs[128 * 32];
    __shared__ __align__(16) unsigned short Als[128 * 32];
    __shared__ __align__(16) unsigned short Bhs[128 * 32];
    __shared__ __align__(16) unsigned short Bls[128 * 32];

    int tid = threadIdx.x;
    int bn = blockIdx.x * 128;
    int bm = blockIdx.y * 128;
    int lane = tid & 63;
    int w = tid >> 6;
    int wm = w >> 1, wn = w & 1;
    int ml = lane & 15, kq = lane >> 4;
    int rsub = lane >> 2;
    int ksw = (((lane & 3) ^ ((lane >> 3) & 3))) * 8;
    int slot8 = ((kq ^ ((ml >> 1) & 3))) * 8;

    f4 acc[4][4];
    #pragma unroll
    for (int i = 0; i < 4; ++i)
        #pragma unroll
        for (int j = 0; j < 4; ++j)
            acc[i][j] = (f4){0.f, 0.f, 0.f, 0.f};

    for (int kt = 0; kt < D_; kt += 32) {
        __syncthreads();
        #pragma unroll
        for (int j = 0; j < 2; ++j) {
            int row = w * 32 + j * 16;
            size_t ga = (size_t)(bm + row + rsub) * D_ + kt + ksw;
            size_t gb = (size_t)(bn + row + rsub) * D_ + kt + ksw;
            async_cp16(Ah + ga, &Ahs[row * 32]);
            async_cp16(Al + ga, &Als[row * 32]);
            async_cp16(Bh + gb, &Bhs[row * 32]);
            async_cp16(Bl + gb, &Bls[row * 32]);
        }
        __syncthreads();
        bfrag ah[4], al[4], bh[4], bl[4];
        #pragma unroll
        for (int i = 0; i < 4; ++i) {
            int arow = wm * 64 + i * 16 + ml;
            ah[i] = *(const bfrag*)&Ahs[arow * 32 + slot8];
            al[i] = *(const bfrag*)&Als[arow * 32 + slot8];
            int brow = wn * 64 + i * 16 + ml;
            bh[i] = *(const bfrag*)&Bhs[brow * 32 + slot8];
            bl[i] = *(const bfrag*)&Bls[brow * 32 + slot8];
        }
        #pragma unroll
        for (int mi = 0; mi < 4; ++mi)
            #pragma unroll
            for (int ni = 0; ni < 4; ++ni) {
                acc[mi][ni] = __builtin_amdgcn_mfma_f32_16x16x32_bf16(ah[mi], bh[ni], acc[mi][ni], 0, 0, 0);
                acc[mi][ni] = __builtin_amdgcn_mfma_f32_16x16x32_bf16(al[mi], bh[ni], acc[mi][ni], 0, 0, 0);
                acc[mi][ni] = __builtin_amdgcn_mfma_f32_16x16x32_bf16(ah[mi], bl[ni], acc[mi][ni], 0, 0, 0);
            }
    }
    #pragma unroll
    for (int ni = 0; ni < 4; ++ni) {
        int col = bn + wn * 64 + ni * 16 + ml;
        float bv = bias[col];
        #pragma unroll
        for (int mi = 0; mi < 4; ++mi) {
            int row0 = bm + wm * 64 + mi * 16 + kq * 4;
            #pragma unroll
            for (int r = 0; r < 4; ++r) {
                float o = acc[mi][ni][r] + bv;
                size_t idx = (size_t)(row0 + r) * D_ + col;
                if (mode == 2) {
                    unsigned u = __float_as_uint(o);
                    float lo = o - __uint_as_float(u & 0xffff0000u);
                    Ch[idx] = (unsigned short)(u >> 16);
                    Cl[idx] = (unsigned short)(__float_as_uint(lo) >> 16);
                } else {
                    if (mode == 1) o = fmaxf(o, 0.f);
                    C[idx] = o;
                }
            }
        }
    }
}

// ---------------- MFMA key side, atomic-free C_u, single-bf16 phase1 ----------------
// grid (NSPLIT_=16, 64): x = n-split (256 rows), y = bh. 4 waves.
// proj now pre-RNE'd globally (projR, padded/zero-filled): staging is a pure uint4 copy.
__global__ __launch_bounds__(256) void kside(
    const float* __restrict__ Kin, const float* __restrict__ Vin,
    const unsigned short* __restrict__ projR,
    float* __restrict__ S_u, float* __restrict__ Cpart, float* __restrict__ C_u,
    float* __restrict__ Vsum, unsigned int* __restrict__ mxp)
{
    __shared__ __align__(16) unsigned short Kh[64 * KP_];      // [n][d] bf16 RNE (pre-scaled by dn)
    __shared__ __align__(16) unsigned short VT[64 * KP_];      // [dh][n] bf16 RNE
    __shared__ __align__(16) unsigned short Ph[2][64 * KP_];   // proj [m][d] bf16 RNE, ping-pong
    __shared__ __align__(16) unsigned short Us[64 * KP_];      // [m][n] bf16 RNE
    __shared__ __align__(16) float Ssum[MP_];
    __shared__ float diag[64];
    float* redf = (float*)Us;   // overlay (lifetimes separated by barriers)

    int bh = blockIdx.y, b = bh >> 4, h = bh & 15;
    int s = blockIdx.x;
    int n0 = s * 256;
    int tid = threadIdx.x, lane = tid & 63, w = tid >> 6;
    int ml = lane & 15, quad = lane >> 4;

    float* dstC = (s < NSPLIT_ - 1) ? (Cpart + (size_t)s * PARTSZ_) : C_u;

    for (int i = tid; i < MP_; i += 256) Ssum[i] = 0.f;

    f4 acc[5][4];
    #pragma unroll
    for (int i = 0; i < 5; ++i)
        #pragma unroll
        for (int j = 0; j < 4; ++j) acc[i][j] = (f4){0.f, 0.f, 0.f, 0.f};
    float vs[4] = {0.f, 0.f, 0.f, 0.f};
    float lmax = -1e30f;

    for (int nc = 0; nc < 4; ++nc) {
        __syncthreads();
        // stage K (RNE, *dn), V^T (RNE), diag partials, and proj chunk 0 (copy)
        #pragma unroll
        for (int l = 0; l < 4; ++l) {
            int idx = tid + 256 * l;
            int r = idx >> 4;
            int d4 = (idx & 15) * 4;
            size_t g = ((size_t)(b * N_ + n0 + nc * 64 + r)) * D_ + h * DH_ + d4;
            const float4 kv = *(const float4*)(Kin + g);
            redf[r * 17 + (tid & 15)] = kv.x * kv.x + kv.y * kv.y + kv.z * kv.z + kv.w * kv.w;
            unsigned w0 = (unsigned)bf16rne(kv.x * DN_) | ((unsigned)bf16rne(kv.y * DN_) << 16);
            unsigned w1 = (unsigned)bf16rne(kv.z * DN_) | ((unsigned)bf16rne(kv.w * DN_) << 16);
            *(uint2*)&Kh[r * KP_ + d4] = make_uint2(w0, w1);
            const float4 vv = *(const float4*)(Vin + g);
            vs[0] += vv.x; vs[1] += vv.y; vs[2] += vv.z; vs[3] += vv.w;
            VT[(d4 + 0) * KP_ + r] = bf16rne(vv.x);
            VT[(d4 + 1) * KP_ + r] = bf16rne(vv.y);
            VT[(d4 + 2) * KP_ + r] = bf16rne(vv.z);
            VT[(d4 + 3) * KP_ + r] = bf16rne(vv.w);
        }
        {   // proj chunk 0 -> Ph[0] (pure copy)
            #pragma unroll
            for (int l = 0; l < 2; ++l) {
                int idx = tid + 256 * l;
                int m = idx >> 3, d8 = (idx & 7) * 8;
                *(uint4*)&Ph[0][m * KP_ + d8] = *(const uint4*)(projR + m * 64 + d8);
            }
        }
        __syncthreads();
        if (tid < 64) {
            float ss = 0.f;
            #pragma unroll
            for (int p = 0; p < 16; ++p) ss += redf[tid * 17 + p];
            diag[tid] = ss * 0.0625f;
        }
        __syncthreads();

        bfrag kh0 = *(const bfrag*)&Kh[(w * 16 + ml) * KP_ + quad * 8];
        bfrag kh1 = *(const bfrag*)&Kh[(w * 16 + ml) * KP_ + 32 + quad * 8];
        float dgv[4];
        #pragma unroll
        for (int r = 0; r < 4; ++r) dgv[r] = diag[w * 16 + quad * 4 + r];

        for (int mc = 0; mc < 5; ++mc) {
            int pb = mc & 1;
            // prefetch next proj chunk (copy; overlaps phase-1 MFMA)
            uint4 pf2[2];
            if (mc < 4) {
                #pragma unroll
                for (int l = 0; l < 2; ++l) {
                    int idx = tid + 256 * l;
                    int m = idx >> 3, d8 = (idx & 7) * 8;
                    int mg = (mc + 1) * 64 + m;      // < MP_, zero-padded
                    pf2[l] = *(const uint4*)(projR + mg * 64 + d8);
                }
            }
            // phase 1: td[n][m] tiles, single-bf16
            #pragma unroll
            for (int mt = 0; mt < 4; ++mt) {
                int mrow = mt * 16 + ml;
                bfrag ph0 = *(const bfrag*)&Ph[pb][mrow * KP_ + quad * 8];
                bfrag ph1 = *(const bfrag*)&Ph[pb][mrow * KP_ + 32 + quad * 8];
                f4 t = (f4){0.f, 0.f, 0.f, 0.f};
                t = __builtin_amdgcn_mfma_f32_16x16x32_bf16(kh0, ph0, t, 0, 0, 0);
                t = __builtin_amdgcn_mfma_f32_16x16x32_bf16(kh1, ph1, t, 0, 0, 0);
                bool mv = (mc * 64 + mrow) < M_;
                float su = 0.f;
                unsigned short up[4];
                #pragma unroll
                for (int r = 0; r < 4; ++r) {
                    float u = 0.f;
                    if (mv) {
                        float tt = t[r];
                        lmax = fmaxf(lmax, tt);
                        u = __expf(tt - dgv[r]);
                    }
                    su += u;
                    up[r] = bf16rne(u);
                }
                su += __shfl_xor(su, 16);
                su += __shfl_xor(su, 32);
                if (mv && quad == 0) atomicAdd(&Ssum[mc * 64 + mrow], su);
                unsigned w0 = (unsigned)up[0] | ((unsigned)up[1] << 16);
                unsigned w1 = (unsigned)up[2] | ((unsigned)up[3] << 16);
                *(uint2*)&Us[mrow * KP_ + w * 16 + quad * 4] = make_uint2(w0, w1);
            }
            // store prefetched proj
            if (mc < 4) {
                #pragma unroll
                for (int l = 0; l < 2; ++l) {
                    int idx = tid + 256 * l;
                    int m = idx >> 3, d8 = (idx & 7) * 8;
                    *(uint4*)&Ph[1 - pb][m * KP_ + d8] = pf2[l];
                }
            }
            __syncthreads();
            // phase 2: acc[mc] += Us^T-tile @ V
            bfrag ua0 = *(const bfrag*)&Us[(w * 16 + ml) * KP_ + quad * 8];
            bfrag ua1 = *(const bfrag*)&Us[(w * 16 + ml) * KP_ + 32 + quad * 8];
            #pragma unroll
            for (int dt = 0; dt < 4; ++dt) {
                bfrag vb0 = *(const bfrag*)&VT[(dt * 16 + ml) * KP_ + quad * 8];
                bfrag vb1 = *(const bfrag*)&VT[(dt * 16 + ml) * KP_ + 32 + quad * 8];
                acc[mc][dt] = __builtin_amdgcn_mfma_f32_16x16x32_bf16(ua0, vb0, acc[mc][dt], 0, 0, 0);
                acc[mc][dt] = __builtin_amdgcn_mfma_f32_16x16x32_bf16(ua1, vb1, acc[mc][dt], 0, 0, 0);
            }
            __syncthreads();
        }
    }
    // epilogue: C_u partial, PLAIN stores (no atomics)
    #pragma unroll
    for (int mc = 0; mc < 5; ++mc)
        #pragma unroll
        for (int dt = 0; dt < 4; ++dt)
            #pragma unroll
            for (int r = 0; r < 4; ++r) {
                int m = mc * 64 + w * 16 + quad * 4 + r;
                if (m < M_)
                    dstC[((size_t)bh * M_ + m) * 64 + dt * 16 + ml] = acc[mc][dt][r];
            }
    __syncthreads();
    for (int m = tid; m < M_; m += 256)
        atomicAdd(S_u + bh * M_ + m, Ssum[m]);
    #pragma unroll
    for (int off = 32; off; off >>= 1) lmax = fmaxf(lmax, __shfl_xor(lmax, off));
    __syncthreads();
    if (lane == 0) redf[w] = lmax;
    __syncthreads();
    if (tid == 0) {
        float mxv = fmaxf(fmaxf(redf[0], redf[1]), fmaxf(redf[2], redf[3]));
        atomicMax(mxp + bh, f2ord(mxv));
    }
    for (int j = 0; j < 4; ++j) {
        __syncthreads();
        redf[tid] = vs[j];
        __syncthreads();
        if (tid < 16) {
            float ss = 0.f;
            #pragma unroll
            for (int p = 0; p < 16; ++p) ss += redf[tid + 16 * p];
            atomicAdd(Vsum + bh * 64 + tid * 4 + j, ss);
        }
    }
}

// ---------------- finalize: sum 16 partials, build ks + ctxT(split) + Cs + kss ----------------
// grid (5, 64): x = m-chunk, y = bh
__global__ __launch_bounds__(256) void finalize_kernel(
    const float* __restrict__ S_u, const float* __restrict__ Cpart, const float* __restrict__ C_u,
    const float* __restrict__ Vsum, const unsigned* __restrict__ mxp,
    float* __restrict__ ksum_f, unsigned short* __restrict__ ctxTh,
    unsigned short* __restrict__ ctxTl, float* __restrict__ Cs, float* __restrict__ kss)
{
    __shared__ float T[64 * 65];
    __shared__ float red[256];
    int mc = blockIdx.x, bh = blockIdx.y;
    int tid = threadIdx.x;
    float emx = __expf(-ord2f(mxp[bh]));

    float csacc = 0.f;   // dh = tid&63 fixed across iterations
    #pragma unroll
    for (int i = 0; i < 16; ++i) {
        int idx = i * 256 + tid;
        int dh = idx & 63, mloc = idx >> 6;
        int m = mc * 64 + mloc;
        float v = 0.f;
        if (m < M_) {
            size_t off = ((size_t)bh * M_ + m) * 64 + dh;
            float sacc = C_u[off];
            for (int sp = 0; sp < NSPLIT_ - 1; ++sp)
                sacc += Cpart[(size_t)sp * PARTSZ_ + off];
            v = RATIO_ * (emx * sacc + EPS_ * Vsum[bh * 64 + dh]);
        }
        T[mloc * 65 + dh] = v;
        csacc += v;
    }
    red[tid] = csacc;
    __syncthreads();
    if (tid < 64) atomicAdd(&Cs[bh * 64 + tid], red[tid] + red[tid + 64] + red[tid + 128] + red[tid + 192]);
    // ks + kss
    float ksl = 0.f;
    if (tid < 64) {
        int m = mc * 64 + tid;
        float kv = (m < M_) ? RATIO_ * (emx * S_u[bh * M_ + m] + EPS_ * (float)N_) : 0.f;
        ksum_f[bh * MP_ + m] = kv;
        ksl = kv;
    }
    __syncthreads();
    red[tid] = ksl;
    __syncthreads();
    if (tid == 0) {
        float ss = 0.f;
        for (int p = 0; p < 64; ++p) ss += red[p];
        atomicAdd(kss + bh, ss);
    }
    __syncthreads();
    // transposed split writes: ctxT[dh][m]
    #pragma unroll
    for (int i = 0; i < 8; ++i) {
        int idx = i * 256 + tid;
        int dh = idx >> 5, m2 = (idx & 31) * 2;
        float v0 = T[m2 * 65 + dh], v1 = T[(m2 + 1) * 65 + dh];
        unsigned u0 = __float_as_uint(v0), u1 = __float_as_uint(v1);
        float lo0 = v0 - __uint_as_float(u0 & 0xffff0000u);
        float lo1 = v1 - __uint_as_float(u1 & 0xffff0000u);
        size_t dst = ((size_t)(bh * 64 + dh)) * MP_ + mc * 64 + m2;
        *(unsigned*)&ctxTh[dst] = (u0 >> 16) | (u1 & 0xffff0000u);
        *(unsigned*)&ctxTl[dst] = (__float_as_uint(lo0) >> 16) | (__float_as_uint(lo1) & 0xffff0000u);
    }
}

// ---------------- MFMA query side (pre-split proj; epilogue writes split-bf16 attn) --------
__global__ __launch_bounds__(256) void qattn(
    const float* __restrict__ Q, const unsigned short* __restrict__ projHg,
    const unsigned short* __restrict__ projLg,
    const float* __restrict__ ksum_f, const unsigned short* __restrict__ ctxTh,
    const unsigned short* __restrict__ ctxTl,
    const float* __restrict__ Cs, const float* __restrict__ kss,
    unsigned short* __restrict__ attnH, unsigned short* __restrict__ attnL)
{
    __shared__ __align__(16) unsigned short Qh[64 * KP_], Ql[64 * KP_];
    __shared__ __align__(16) unsigned short Ph[64 * KP_], Pl[64 * KP_];
    __shared__ __align__(16) unsigned short Uh[64 * KP_], Ul[64 * KP_];
    __shared__ __align__(16) float ks[MP_];
    __shared__ float diag[64];
    float* redf = (float*)Uh;

    int bh = blockIdx.y, b = bh >> 4, h = bh & 15;
    int n0 = blockIdx.x * 64;
    int tid = threadIdx.x, lane = tid & 63, w = tid >> 6;
    int ml = lane & 15, quad = lane >> 4;

    #pragma unroll
    for (int l = 0; l < 4; ++l) {
        int idx = tid + 256 * l;
        int r = idx >> 4, d4 = (idx & 15) * 4;
        size_t g = ((size_t)(b * N_ + n0 + r)) * D_ + h * DH_ + d4;
        const float4 qv = *(const float4*)(Q + g);
        redf[r * 17 + (tid & 15)] = qv.x * qv.x + qv.y * qv.y + qv.z * qv.z + qv.w * qv.w;
        unsigned h0, l0, h1, l1;
        split2pack(qv.x * DN_, qv.y * DN_, &h0, &l0);
        split2pack(qv.z * DN_, qv.w * DN_, &h1, &l1);
        *(uint2*)&Qh[r * KP_ + d4] = make_uint2(h0, h1);
        *(uint2*)&Ql[r * KP_ + d4] = make_uint2(l0, l1);
    }
    for (int m = tid; m < MP_; m += 256) ks[m] = ksum_f[bh * MP_ + m];
    __syncthreads();
    if (tid < 64) {
        float s = 0.f;
        #pragma unroll
        for (int p = 0; p < 16; ++p) s += redf[tid * 17 + p];
        diag[tid] = s * 0.0625f;
    }
    __syncthreads();

    bfrag qh0 = *(const bfrag*)&Qh[(w * 16 + ml) * KP_ + quad * 8];
    bfrag ql0 = *(const bfrag*)&Ql[(w * 16 + ml) * KP_ + quad * 8];
    bfrag qh1 = *(const bfrag*)&Qh[(w * 16 + ml) * KP_ + 32 + quad * 8];
    bfrag ql1 = *(const bfrag*)&Ql[(w * 16 + ml) * KP_ + 32 + quad * 8];
    float dg = diag[w * 16 + ml];
    float dacc = 0.f, tmax = -1e30f;
    f4 oacc[4];
    #pragma unroll
    for (int i = 0; i < 4; ++i) oacc[i] = (f4){0.f, 0.f, 0.f, 0.f};

    for (int mc = 0; mc < 5; ++mc) {
        // proj chunk stage: pure uint4 copy from pre-split padded arrays
        #pragma unroll
        for (int l = 0; l < 2; ++l) {
            int idx = tid + 256 * l;
            int m = idx >> 3, d8 = (idx & 7) * 8;
            int mg = mc * 64 + m;                    // < MP_, zero-padded
            *(uint4*)&Ph[m * KP_ + d8] = *(const uint4*)(projHg + mg * 64 + d8);
            *(uint4*)&Pl[m * KP_ + d8] = *(const uint4*)(projLg + mg * 64 + d8);
        }
        __syncthreads();
        #pragma unroll
        for (int mt = 0; mt < 4; ++mt) {
            int mrow = mt * 16 + ml;
            bfrag ph0 = *(const bfrag*)&Ph[mrow * KP_ + quad * 8];
            bfrag pl0 = *(const bfrag*)&Pl[mrow * KP_ + quad * 8];
            bfrag ph1 = *(const bfrag*)&Ph[mrow * KP_ + 32 + quad * 8];
            bfrag pl1 = *(const bfrag*)&Pl[mrow * KP_ + 32 + quad * 8];
            f4 t = (f4){0.f, 0.f, 0.f, 0.f};
            t = __builtin_amdgcn_mfma_f32_16x16x32_bf16(ph0, qh0, t, 0, 0, 0);
            t = __builtin_amdgcn_mfma_f32_16x16x32_bf16(pl0, qh0, t, 0, 0, 0);
            t = __builtin_amdgcn_mfma_f32_16x16x32_bf16(ph0, ql0, t, 0, 0, 0);
            t = __builtin_amdgcn_mfma_f32_16x16x32_bf16(ph1, qh1, t, 0, 0, 0);
            t = __builtin_amdgcn_mfma_f32_16x16x32_bf16(pl1, qh1, t, 0, 0, 0);
            t = __builtin_amdgcn_mfma_f32_16x16x32_bf16(ph1, ql1, t, 0, 0, 0);
            const float4 ksv = *(const float4*)&ks[mc * 64 + mt * 16 + quad * 4];
            float ksa[4] = {ksv.x, ksv.y, ksv.z, ksv.w};
            unsigned short uh4[4], ul4[4];
            #pragma unroll
            for (int r = 0; r < 4; ++r) {
                int mg = mc * 64 + mt * 16 + quad * 4 + r;
                float tt = t[r];
                float u = __expf(tt - dg);
                if (mg < M_) tmax = fmaxf(tmax, tt);
                dacc = fmaf(u, ksa[r], dacc);
                unsigned uu = __float_as_uint(u);
                float lo = u - __uint_as_float(uu & 0xffff0000u);
                uh4[r] = (unsigned short)(uu >> 16);
                ul4[r] = (unsigned short)(__float_as_uint(lo) >> 16);
            }
            unsigned a0 = (unsigned)uh4[0] | ((unsigned)uh4[1] << 16);
            unsigned a1 = (unsigned)uh4[2] | ((unsigned)uh4[3] << 16);
            unsigned b0 = (unsigned)ul4[0] | ((unsigned)ul4[1] << 16);
            unsigned b1 = (unsigned)ul4[2] | ((unsigned)ul4[3] << 16);
            *(uint2*)&Uh[(w * 16 + ml) * KP_ + mt * 16 + quad * 4] = make_uint2(a0, a1);
            *(uint2*)&Ul[(w * 16 + ml) * KP_ + mt * 16 + quad * 4] = make_uint2(b0, b1);
        }
        __syncthreads();
        #pragma unroll
        for (int l = 0; l < 2; ++l) {
            int idx = tid + 256 * l;
            int dh = idx >> 3, m8 = (idx & 7) * 8;
            size_t src = ((size_t)(bh * 64 + dh)) * MP_ + mc * 64 + m8;
            *(uint4*)&Ph[dh * KP_ + m8] = *(const uint4*)(ctxTh + src);
            *(uint4*)&Pl[dh * KP_ + m8] = *(const uint4*)(ctxTl + src);
        }
        __syncthreads();
        bfrag ua0h = *(const bfrag*)&Uh[(w * 16 + ml) * KP_ + quad * 8];
        bfrag ua0l = *(const bfrag*)&Ul[(w * 16 + ml) * KP_ + quad * 8];
        bfrag ua1h = *(const bfrag*)&Uh[(w * 16 + ml) * KP_ + 32 + quad * 8];
        bfrag ua1l = *(const bfrag*)&Ul[(w * 16 + ml) * KP_ + 32 + quad * 8];
        #pragma unroll
        for (int dt = 0; dt < 4; ++dt) {
            bfrag cb0h = *(const bfrag*)&Ph[(dt * 16 + ml) * KP_ + quad * 8];
            bfrag cb0l = *(const bfrag*)&Pl[(dt * 16 + ml) * KP_ + quad * 8];
            bfrag cb1h = *(const bfrag*)&Ph[(dt * 16 + ml) * KP_ + 32 + quad * 8];
            bfrag cb1l = *(const bfrag*)&Pl[(dt * 16 + ml) * KP_ + 32 + quad * 8];
            oacc[dt] = __builtin_amdgcn_mfma_f32_16x16x32_bf16(ua0h, cb0h, oacc[dt], 0, 0, 0);
            oacc[dt] = __builtin_amdgcn_mfma_f32_16x16x32_bf16(ua0l, cb0h, oacc[dt], 0, 0, 0);
            oacc[dt] = __builtin_amdgcn_mfma_f32_16x16x32_bf16(ua0h, cb0l, oacc[dt], 0, 0, 0);
            oacc[dt] = __builtin_amdgcn_mfma_f32_16x16x32_bf16(ua1h, cb1h, oacc[dt], 0, 0, 0);
            oacc[dt] = __builtin_amdgcn_mfma_f32_16x16x32_bf16(ua1l, cb1h, oacc[dt], 0, 0, 0);
            oacc[dt] = __builtin_amdgcn_mfma_f32_16x16x32_bf16(ua1h, cb1l, oacc[dt], 0, 0, 0);
        }
        __syncthreads();
    }
    dacc += __shfl_xor(dacc, 16); dacc += __shfl_xor(dacc, 32);
    tmax = fmaxf(tmax, __shfl_xor(tmax, 16));
    tmax = fmaxf(tmax, __shfl_xor(tmax, 32));
    float fac = EPS_ * __expf(tmax);
    float dinv = 1.f / (dacc + fac * kss[bh]);
    #pragma unroll
    for (int dt = 0; dt < 4; ++dt) {
        float csv = Cs[bh * 64 + dt * 16 + ml];
        #pragma unroll
        for (int r = 0; r < 4; ++r) {
            int srcl = quad * 4 + r;
            float dv = __shfl(dinv, srcl);
            float fv = __shfl(fac, srcl);
            float o = (oacc[dt][r] + fv * csv) * dv;
            int n = n0 + w * 16 + quad * 4 + r;
            size_t gi = ((size_t)(b * N_ + n)) * D_ + h * DH_ + dt * 16 + ml;
            unsigned u = __float_as_uint(o);
            float lo = o - __uint_as_float(u & 0xffff0000u);
            attnH[gi] = (unsigned short)(u >> 16);
            attnL[gi] = (unsigned short)(__float_as_uint(lo) >> 16);
        }
    }
}

// ---------------- launch ----------------
extern "C" void kernel_launch(void* const* d_in, const int* in_sizes, int n_in,
                              void* d_out, int out_size, void* d_ws, size_t ws_size,
                              hipStream_t stream)
{
    const float* x    = (const float*)d_in[0];
    const float* Wq   = (const float*)d_in[1];
    const float* bq   = (const float*)d_in[2];
    const float* Wk   = (const float*)d_in[3];
    const float* bk   = (const float*)d_in[4];
    const float* Wv   = (const float*)d_in[5];
    const float* bv   = (const float*)d_in[6];
    const float* Wo   = (const float*)d_in[7];
    const float* bo   = (const float*)d_in[8];
    const float* Wfc  = (const float*)d_in[9];
    const float* bfc  = (const float*)d_in[10];
    const float* proj = (const float*)d_in[11];
    float* out = (float*)d_out;

    float* ws = (float*)d_ws;
    const size_t nTok = (size_t)B_ * N_ * D_;
    const size_t nSu  = 64 * M_;
    const size_t nCu  = (size_t)64 * M_ * 64;
    const size_t nVs  = 64 * 64;
    const size_t nMx  = 64;
    const size_t nKsf = 64 * MP_;
    const size_t nCtx = (size_t)64 * MP_ * 64;
    const size_t nCs  = 64 * 64;

    const size_t offQ   = 0;
    const size_t offK   = nTok;
    const size_t offV   = nTok * 2;
    const size_t offSu  = nTok * 3;
    const size_t offCu  = offSu + nSu;
    const size_t offVs  = offCu + nCu;
    const size_t offMx  = offVs + nVs;
    const size_t offKsf = offMx + nMx;
    const size_t offCtx = offKsf + nKsf;
    const size_t offCs  = offCtx + nCtx;
    const size_t offKss = offCs + nCs;
    const size_t offWsp = offKss + 64;              // 5 weights split: 5 * 1048576 float-slots
    const size_t offPrj = offWsp + 5242880;         // proj pre-split: 3 * 20480 ushorts

    float* Q    = ws + offQ;
    float* Kb   = ws + offK;
    float* Vb   = ws + offV;
    float* S_u  = ws + offSu;
    float* C_u  = ws + offCu;
    float* Vsum = ws + offVs;
    unsigned* mx = (unsigned*)(ws + offMx);
    float* ksf  = ws + offKsf;
    unsigned short* ctxTh = (unsigned short*)(ws + offCtx);
    unsigned short* ctxTl = ctxTh + (size_t)64 * 64 * MP_;
    float* Cs   = ws + offCs;
    float* kss  = ws + offKss;
    unsigned short* Wsp = (unsigned short*)(ws + offWsp);
    unsigned short* projR  = (unsigned short*)(ws + offPrj);
    unsigned short* projHg = projR + (size_t)MP_ * 64;
    unsigned short* projLg = projHg + (size_t)MP_ * 64;

    // scratch overlays (stream-ordered lifetimes):
    unsigned short* xh = (unsigned short*)out;        // x split lives in d_out, dead before kside
    unsigned short* xl = xh + nTok;
    unsigned short* attnH = (unsigned short*)Kb;      // K dead after kside
    unsigned short* attnL = attnH + nTok;
    unsigned short* hbH = (unsigned short*)Vb;        // V dead after kside
    unsigned short* hbL = hbH + nTok;
    float* Cpart = out;                               // d_out as scratch for 15 C_u partials

    // zero S_u..kss (covers S_u, C_u, Vsum, mx, ksf, ctxT, Cs, kss)
    int nzero = (int)(nSu + nCu + nVs + nMx + nKsf + nCtx + nCs + 64);
    zero_kernel<<<dim3((nzero + 255) / 256), dim3(256), 0, stream>>>(S_u, nzero);

    // one-shot conversions
    split_f32<<<dim3(16384), dim3(256), 0, stream>>>(x, xh, xl, (int)(nTok / 4));
    split_w5<<<dim3(1024, 5), dim3(256), 0, stream>>>(Wq, Wk, Wv, Wo, Wfc, Wsp);
    presplit_proj<<<dim3(80), dim3(256), 0, stream>>>(proj, projR, projHg, projLg);

    gemm_qkv_s<<<dim3(24, (B_ * N_) / 128), dim3(256), 0, stream>>>(
        xh, xl, Wsp, bq, bk, bv, Q, Kb, Vb);

    kside<<<dim3(NSPLIT_, 64), dim3(256), 0, stream>>>(Kb, Vb, projR, S_u, Cpart, C_u, Vsum, mx);
    finalize_kernel<<<dim3(5, 64), dim3(256), 0, stream>>>(S_u, Cpart, C_u, Vsum, mx, ksf, ctxTh, ctxTl, Cs, kss);
    qattn<<<dim3(64, 64), dim3(256), 0, stream>>>(Q, projHg, projLg, ksf, ctxTh, ctxTl, Cs, kss, attnH, attnL);

    dim3 gg(D_ / 128, (B_ * N_) / 128);
    // Wo: split-bf16 A (attn) -> split-bf16 hbuf
    gemm_nt_s<<<gg, dim3(256), 0, stream>>>(attnH, attnL,
        Wsp + (size_t)3 * 2097152, Wsp + (size_t)3 * 2097152 + 1048576,
        bo, (float*)nullptr, hbH, hbL, 2);
    // Wfc: split-bf16 A (hbuf) -> fp32 out + relu
    gemm_nt_s<<<gg, dim3(256), 0, stream>>>(hbH, hbL,
        Wsp + (size_t)4 * 2097152, Wsp + (size_t)4 * 2097152 + 1048576,
        bfc, out, (unsigned short*)nullptr, (unsigned short*)nullptr, 1);
}

// Round 8
// 972.902 us; speedup vs baseline: 1.1307x; 1.0156x over previous
//
#include <hip/hip_runtime.h>
#include <math.h>

#define B_ 4
#define N_ 4096
#define D_ 1024
#define H_ 16
#define DH_ 64
#define M_ 266
#define MP_ 320   // M padded to 5 chunks of 64

#define DN_ 0.35355339059327373f      // 64^-0.25
#define RATIO_ 0.06131393394849658f   // 266^-0.5
#define EPS_ 1e-4f
#define KP_ 72    // ushort row stride
#define NSPLIT_ 16
#define PARTSZ_ ((size_t)64 * M_ * 64)   // one C_u partial (all bh)

typedef __attribute__((ext_vector_type(8))) short bfrag;
typedef __attribute__((ext_vector_type(4))) float f4;

__device__ __forceinline__ unsigned f2ord(float f) {
    unsigned u = __float_as_uint(f);
    return (u & 0x80000000u) ? ~u : (u | 0x80000000u);
}
__device__ __forceinline__ float ord2f(unsigned u) {
    unsigned b = (u & 0x80000000u) ? (u & 0x7fffffffu) : ~u;
    return __uint_as_float(b);
}

__global__ void zero_kernel(float* __restrict__ p, int n) {
    int i = blockIdx.x * 256 + threadIdx.x;
    if (i < n) p[i] = 0.f;
}

__device__ __forceinline__ void split2pack(float x, float y, unsigned* hp, unsigned* lp) {
    unsigned ux = __float_as_uint(x), uy = __float_as_uint(y);
    float hx = __uint_as_float(ux & 0xffff0000u);
    float hy = __uint_as_float(uy & 0xffff0000u);
    float lx = x - hx, ly = y - hy;
    *hp = (ux >> 16) | (uy & 0xffff0000u);
    *lp = (__float_as_uint(lx) >> 16) | (__float_as_uint(ly) & 0xffff0000u);
}
__device__ __forceinline__ unsigned short bf16rne(float x) {
    unsigned u = __float_as_uint(x);
    return (unsigned short)((u + 0x7fffu + ((u >> 16) & 1u)) >> 16);
}

// async global->LDS 16B (dwordx4). LDS dst must be wave-uniform; lane writes dst+lane*16.
__device__ __forceinline__ void async_cp16(const void* g, void* l) {
    __builtin_amdgcn_global_load_lds(
        (const __attribute__((address_space(1))) void*)g,
        (__attribute__((address_space(3))) void*)l, 16, 0, 0);
}

// ---------------- one-shot split conversions (each element converted exactly once) --------
__global__ __launch_bounds__(256) void split_f32(const float* __restrict__ X,
        unsigned short* __restrict__ Xh, unsigned short* __restrict__ Xl, int n4)
{
    int i = blockIdx.x * 256 + threadIdx.x;
    if (i >= n4) return;
    const float4 v = ((const float4*)X)[i];
    unsigned h0, l0, h1, l1;
    split2pack(v.x, v.y, &h0, &l0);
    split2pack(v.z, v.w, &h1, &l1);
    ((uint2*)Xh)[i] = make_uint2(h0, h1);
    ((uint2*)Xl)[i] = make_uint2(l0, l1);
}

// 5 weights (1024x1024 each) -> Wsp: per sel, h at sel*2097152, l at +1048576 (ushort units)
__global__ __launch_bounds__(256) void split_w5(const float* __restrict__ W0,
        const float* __restrict__ W1, const float* __restrict__ W2,
        const float* __restrict__ W3, const float* __restrict__ W4,
        unsigned short* __restrict__ Wsp)
{
    int sel = blockIdx.y;
    const float* W = (sel == 0) ? W0 : (sel == 1) ? W1 : (sel == 2) ? W2 : (sel == 3) ? W3 : W4;
    unsigned short* h = Wsp + (size_t)sel * 2097152;
    unsigned short* l = h + 1048576;
    int i = blockIdx.x * 256 + threadIdx.x;   // 1024*256 threads * 4 elems = 1048576
    const float4 v = ((const float4*)W)[i];
    unsigned h0, l0, h1, l1;
    split2pack(v.x, v.y, &h0, &l0);
    split2pack(v.z, v.w, &h1, &l1);
    ((uint2*)h)[i] = make_uint2(h0, h1);
    ((uint2*)l)[i] = make_uint2(l0, l1);
}

// proj (266x64) pre-converted ONCE, padded to MP_ rows with zeros.
__global__ __launch_bounds__(256) void presplit_proj(const float* __restrict__ proj,
        unsigned short* __restrict__ projR, unsigned short* __restrict__ projHg,
        unsigned short* __restrict__ projLg)
{
    int i = blockIdx.x * 256 + threadIdx.x;   // 80 blocks * 256 = 20480 = MP_*64
    int m = i >> 6, d = i & 63;
    float v = (m < M_) ? proj[m * 64 + d] : 0.f;
    projR[i] = bf16rne(v);
    unsigned u = __float_as_uint(v);
    float lo = v - __uint_as_float(u & 0xffff0000u);
    projHg[i] = (unsigned short)(u >> 16);
    projLg[i] = (unsigned short)(__float_as_uint(lo) >> 16);
}

// ---------------- fused QKV GEMM (128x128 stage-serial, proven 310us) ----------------------
__global__ __launch_bounds__(256) void gemm_qkv_s(
        const unsigned short* __restrict__ Ah, const unsigned short* __restrict__ Al,
        const unsigned short* __restrict__ Wsp,
        const float* __restrict__ b0, const float* __restrict__ b1, const float* __restrict__ b2,
        float* __restrict__ C0, float* __restrict__ C1, float* __restrict__ C2)
{
    __shared__ __align__(16) unsigned short Ahs[128 * 32];
    __shared__ __align__(16) unsigned short Als[128 * 32];
    __shared__ __align__(16) unsigned short Bhs[128 * 32];
    __shared__ __align__(16) unsigned short Bls[128 * 32];

    int tid = threadIdx.x;
    int sel = blockIdx.x >> 3;               // 0..2 -> q,k,v
    int bn = (blockIdx.x & 7) * 128;
    int bm = blockIdx.y * 128;
    const unsigned short* Bh = Wsp + (size_t)sel * 2097152;
    const unsigned short* Bl = Bh + 1048576;
    const float* bias = (sel == 0) ? b0 : (sel == 1) ? b1 : b2;
    float* C = (sel == 0) ? C0 : (sel == 1) ? C1 : C2;

    int lane = tid & 63;
    int w = tid >> 6;
    int wm = w >> 1, wn = w & 1;
    int ml = lane & 15, kq = lane >> 4;
    int rsub = lane >> 2;
    int ksw = (((lane & 3) ^ ((lane >> 3) & 3))) * 8;   // swizzled source K-slot (ushorts)
    int slot8 = ((kq ^ ((ml >> 1) & 3))) * 8;           // swizzled read K-slot (ushorts)

    f4 acc[4][4];
    #pragma unroll
    for (int i = 0; i < 4; ++i)
        #pragma unroll
        for (int j = 0; j < 4; ++j)
            acc[i][j] = (f4){0.f, 0.f, 0.f, 0.f};

    for (int kt = 0; kt < D_; kt += 32) {
        __syncthreads();
        #pragma unroll
        for (int j = 0; j < 2; ++j) {
            int row = w * 32 + j * 16;                        // wave-uniform
            size_t ga = (size_t)(bm + row + rsub) * D_ + kt + ksw;
            size_t gb = (size_t)(bn + row + rsub) * D_ + kt + ksw;
            async_cp16(Ah + ga, &Ahs[row * 32]);
            async_cp16(Al + ga, &Als[row * 32]);
            async_cp16(Bh + gb, &Bhs[row * 32]);
            async_cp16(Bl + gb, &Bls[row * 32]);
        }
        __syncthreads();
        bfrag ah[4], al[4], bh[4], bl[4];
        #pragma unroll
        for (int i = 0; i < 4; ++i) {
            int arow = wm * 64 + i * 16 + ml;
            ah[i] = *(const bfrag*)&Ahs[arow * 32 + slot8];
            al[i] = *(const bfrag*)&Als[arow * 32 + slot8];
            int brow = wn * 64 + i * 16 + ml;
            bh[i] = *(const bfrag*)&Bhs[brow * 32 + slot8];
            bl[i] = *(const bfrag*)&Bls[brow * 32 + slot8];
        }
        #pragma unroll
        for (int mi = 0; mi < 4; ++mi)
            #pragma unroll
            for (int ni = 0; ni < 4; ++ni) {
                acc[mi][ni] = __builtin_amdgcn_mfma_f32_16x16x32_bf16(ah[mi], bh[ni], acc[mi][ni], 0, 0, 0);
                acc[mi][ni] = __builtin_amdgcn_mfma_f32_16x16x32_bf16(al[mi], bh[ni], acc[mi][ni], 0, 0, 0);
                acc[mi][ni] = __builtin_amdgcn_mfma_f32_16x16x32_bf16(ah[mi], bl[ni], acc[mi][ni], 0, 0, 0);
            }
    }
    #pragma unroll
    for (int ni = 0; ni < 4; ++ni) {
        int col = bn + wn * 64 + ni * 16 + ml;
        float bv = bias[col];
        #pragma unroll
        for (int mi = 0; mi < 4; ++mi) {
            int row0 = bm + wm * 64 + mi * 16 + kq * 4;
            #pragma unroll
            for (int r = 0; r < 4; ++r)
                C[(size_t)(row0 + r) * D_ + col] = acc[mi][ni][r] + bv;
        }
    }
}

// ---------------- generic NT GEMM on pre-split operands (Wo / Wfc) ----------------
// mode 0: fp32+bias; mode 1: fp32+bias+relu; mode 2: split-bf16 write (+bias)
__global__ __launch_bounds__(256) void gemm_nt_s(
        const unsigned short* __restrict__ Ah, const unsigned short* __restrict__ Al,
        const unsigned short* __restrict__ Bh, const unsigned short* __restrict__ Bl,
        const float* __restrict__ bias, float* __restrict__ C,
        unsigned short* __restrict__ Ch, unsigned short* __restrict__ Cl, int mode)
{
    __shared__ __align__(16) unsigned short Ahs[128 * 32];
    __shared__ __align__(16) unsigned short Als[128 * 32];
    __shared__ __align__(16) unsigned short Bhs[128 * 32];
    __shared__ __align__(16) unsigned short Bls[128 * 32];

    int tid = threadIdx.x;
    int bn = blockIdx.x * 128;
    int bm = blockIdx.y * 128;
    int lane = tid & 63;
    int w = tid >> 6;
    int wm = w >> 1, wn = w & 1;
    int ml = lane & 15, kq = lane >> 4;
    int rsub = lane >> 2;
    int ksw = (((lane & 3) ^ ((lane >> 3) & 3))) * 8;
    int slot8 = ((kq ^ ((ml >> 1) & 3))) * 8;

    f4 acc[4][4];
    #pragma unroll
    for (int i = 0; i < 4; ++i)
        #pragma unroll
        for (int j = 0; j < 4; ++j)
            acc[i][j] = (f4){0.f, 0.f, 0.f, 0.f};

    for (int kt = 0; kt < D_; kt += 32) {
        __syncthreads();
        #pragma unroll
        for (int j = 0; j < 2; ++j) {
            int row = w * 32 + j * 16;
            size_t ga = (size_t)(bm + row + rsub) * D_ + kt + ksw;
            size_t gb = (size_t)(bn + row + rsub) * D_ + kt + ksw;
            async_cp16(Ah + ga, &Ahs[row * 32]);
            async_cp16(Al + ga, &Als[row * 32]);
            async_cp16(Bh + gb, &Bhs[row * 32]);
            async_cp16(Bl + gb, &Bls[row * 32]);
        }
        __syncthreads();
        bfrag ah[4], al[4], bh[4], bl[4];
        #pragma unroll
        for (int i = 0; i < 4; ++i) {
            int arow = wm * 64 + i * 16 + ml;
            ah[i] = *(const bfrag*)&Ahs[arow * 32 + slot8];
            al[i] = *(const bfrag*)&Als[arow * 32 + slot8];
            int brow = wn * 64 + i * 16 + ml;
            bh[i] = *(const bfrag*)&Bhs[brow * 32 + slot8];
            bl[i] = *(const bfrag*)&Bls[brow * 32 + slot8];
        }
        #pragma unroll
        for (int mi = 0; mi < 4; ++mi)
            #pragma unroll
            for (int ni = 0; ni < 4; ++ni) {
                acc[mi][ni] = __builtin_amdgcn_mfma_f32_16x16x32_bf16(ah[mi], bh[ni], acc[mi][ni], 0, 0, 0);
                acc[mi][ni] = __builtin_amdgcn_mfma_f32_16x16x32_bf16(al[mi], bh[ni], acc[mi][ni], 0, 0, 0);
                acc[mi][ni] = __builtin_amdgcn_mfma_f32_16x16x32_bf16(ah[mi], bl[ni], acc[mi][ni], 0, 0, 0);
            }
    }
    #pragma unroll
    for (int ni = 0; ni < 4; ++ni) {
        int col = bn + wn * 64 + ni * 16 + ml;
        float bv = bias[col];
        #pragma unroll
        for (int mi = 0; mi < 4; ++mi) {
            int row0 = bm + wm * 64 + mi * 16 + kq * 4;
            #pragma unroll
            for (int r = 0; r < 4; ++r) {
                float o = acc[mi][ni][r] + bv;
                size_t idx = (size_t)(row0 + r) * D_ + col;
                if (mode == 2) {
                    unsigned u = __float_as_uint(o);
                    float lo = o - __uint_as_float(u & 0xffff0000u);
                    Ch[idx] = (unsigned short)(u >> 16);
                    Cl[idx] = (unsigned short)(__float_as_uint(lo) >> 16);
                } else {
                    if (mode == 1) o = fmaxf(o, 0.f);
                    C[idx] = o;
                }
            }
        }
    }
}

// ---------------- MFMA key side, atomic-free C_u, single-bf16 phase1 ----------------
// grid (NSPLIT_=16, 64): x = n-split (256 rows), y = bh. 4 waves.
__global__ __launch_bounds__(256) void kside(
    const float* __restrict__ Kin, const float* __restrict__ Vin,
    const unsigned short* __restrict__ projR,
    float* __restrict__ S_u, float* __restrict__ Cpart, float* __restrict__ C_u,
    float* __restrict__ Vsum, unsigned int* __restrict__ mxp)
{
    __shared__ __align__(16) unsigned short Kh[64 * KP_];      // [n][d] bf16 RNE (pre-scaled by dn)
    __shared__ __align__(16) unsigned short VT[64 * KP_];      // [dh][n] bf16 RNE
    __shared__ __align__(16) unsigned short Ph[2][64 * KP_];   // proj [m][d] bf16 RNE, ping-pong
    __shared__ __align__(16) unsigned short Us[64 * KP_];      // [m][n] bf16 RNE
    __shared__ __align__(16) float Ssum[MP_];
    __shared__ float diag[64];
    float* redf = (float*)Us;   // overlay (lifetimes separated by barriers)

    int bh = blockIdx.y, b = bh >> 4, h = bh & 15;
    int s = blockIdx.x;
    int n0 = s * 256;
    int tid = threadIdx.x, lane = tid & 63, w = tid >> 6;
    int ml = lane & 15, quad = lane >> 4;

    float* dstC = (s < NSPLIT_ - 1) ? (Cpart + (size_t)s * PARTSZ_) : C_u;

    for (int i = tid; i < MP_; i += 256) Ssum[i] = 0.f;

    f4 acc[5][4];
    #pragma unroll
    for (int i = 0; i < 5; ++i)
        #pragma unroll
        for (int j = 0; j < 4; ++j) acc[i][j] = (f4){0.f, 0.f, 0.f, 0.f};
    float vs[4] = {0.f, 0.f, 0.f, 0.f};
    float lmax = -1e30f;

    for (int nc = 0; nc < 4; ++nc) {
        __syncthreads();
        // stage K (RNE, *dn), V^T (RNE), diag partials, and proj chunk 0 (copy)
        #pragma unroll
        for (int l = 0; l < 4; ++l) {
            int idx = tid + 256 * l;
            int r = idx >> 4;
            int d4 = (idx & 15) * 4;
            size_t g = ((size_t)(b * N_ + n0 + nc * 64 + r)) * D_ + h * DH_ + d4;
            const float4 kv = *(const float4*)(Kin + g);
            redf[r * 17 + (tid & 15)] = kv.x * kv.x + kv.y * kv.y + kv.z * kv.z + kv.w * kv.w;
            unsigned w0 = (unsigned)bf16rne(kv.x * DN_) | ((unsigned)bf16rne(kv.y * DN_) << 16);
            unsigned w1 = (unsigned)bf16rne(kv.z * DN_) | ((unsigned)bf16rne(kv.w * DN_) << 16);
            *(uint2*)&Kh[r * KP_ + d4] = make_uint2(w0, w1);
            const float4 vv = *(const float4*)(Vin + g);
            vs[0] += vv.x; vs[1] += vv.y; vs[2] += vv.z; vs[3] += vv.w;
            VT[(d4 + 0) * KP_ + r] = bf16rne(vv.x);
            VT[(d4 + 1) * KP_ + r] = bf16rne(vv.y);
            VT[(d4 + 2) * KP_ + r] = bf16rne(vv.z);
            VT[(d4 + 3) * KP_ + r] = bf16rne(vv.w);
        }
        {   // proj chunk 0 -> Ph[0] (pure copy)
            #pragma unroll
            for (int l = 0; l < 2; ++l) {
                int idx = tid + 256 * l;
                int m = idx >> 3, d8 = (idx & 7) * 8;
                *(uint4*)&Ph[0][m * KP_ + d8] = *(const uint4*)(projR + m * 64 + d8);
            }
        }
        __syncthreads();
        if (tid < 64) {
            float ss = 0.f;
            #pragma unroll
            for (int p = 0; p < 16; ++p) ss += redf[tid * 17 + p];
            diag[tid] = ss * 0.0625f;
        }
        __syncthreads();

        bfrag kh0 = *(const bfrag*)&Kh[(w * 16 + ml) * KP_ + quad * 8];
        bfrag kh1 = *(const bfrag*)&Kh[(w * 16 + ml) * KP_ + 32 + quad * 8];
        float dgv[4];
        #pragma unroll
        for (int r = 0; r < 4; ++r) dgv[r] = diag[w * 16 + quad * 4 + r];

        for (int mc = 0; mc < 5; ++mc) {
            int pb = mc & 1;
            // prefetch next proj chunk (copy; overlaps phase-1 MFMA)
            uint4 pf2[2];
            if (mc < 4) {
                #pragma unroll
                for (int l = 0; l < 2; ++l) {
                    int idx = tid + 256 * l;
                    int m = idx >> 3, d8 = (idx & 7) * 8;
                    int mg = (mc + 1) * 64 + m;      // < MP_, zero-padded
                    pf2[l] = *(const uint4*)(projR + mg * 64 + d8);
                }
            }
            // phase 1: td[n][m] tiles, single-bf16
            #pragma unroll
            for (int mt = 0; mt < 4; ++mt) {
                int mrow = mt * 16 + ml;
                bfrag ph0 = *(const bfrag*)&Ph[pb][mrow * KP_ + quad * 8];
                bfrag ph1 = *(const bfrag*)&Ph[pb][mrow * KP_ + 32 + quad * 8];
                f4 t = (f4){0.f, 0.f, 0.f, 0.f};
                t = __builtin_amdgcn_mfma_f32_16x16x32_bf16(kh0, ph0, t, 0, 0, 0);
                t = __builtin_amdgcn_mfma_f32_16x16x32_bf16(kh1, ph1, t, 0, 0, 0);
                bool mv = (mc * 64 + mrow) < M_;
                float su = 0.f;
                unsigned short up[4];
                #pragma unroll
                for (int r = 0; r < 4; ++r) {
                    float u = 0.f;
                    if (mv) {
                        float tt = t[r];
                        lmax = fmaxf(lmax, tt);
                        u = __expf(tt - dgv[r]);
                    }
                    su += u;
                    up[r] = bf16rne(u);
                }
                su += __shfl_xor(su, 16);
                su += __shfl_xor(su, 32);
                if (mv && quad == 0) atomicAdd(&Ssum[mc * 64 + mrow], su);
                unsigned w0 = (unsigned)up[0] | ((unsigned)up[1] << 16);
                unsigned w1 = (unsigned)up[2] | ((unsigned)up[3] << 16);
                *(uint2*)&Us[mrow * KP_ + w * 16 + quad * 4] = make_uint2(w0, w1);
            }
            // store prefetched proj
            if (mc < 4) {
                #pragma unroll
                for (int l = 0; l < 2; ++l) {
                    int idx = tid + 256 * l;
                    int m = idx >> 3, d8 = (idx & 7) * 8;
                    *(uint4*)&Ph[1 - pb][m * KP_ + d8] = pf2[l];
                }
            }
            __syncthreads();
            // phase 2: acc[mc] += Us^T-tile @ V
            bfrag ua0 = *(const bfrag*)&Us[(w * 16 + ml) * KP_ + quad * 8];
            bfrag ua1 = *(const bfrag*)&Us[(w * 16 + ml) * KP_ + 32 + quad * 8];
            #pragma unroll
            for (int dt = 0; dt < 4; ++dt) {
                bfrag vb0 = *(const bfrag*)&VT[(dt * 16 + ml) * KP_ + quad * 8];
                bfrag vb1 = *(const bfrag*)&VT[(dt * 16 + ml) * KP_ + 32 + quad * 8];
                acc[mc][dt] = __builtin_amdgcn_mfma_f32_16x16x32_bf16(ua0, vb0, acc[mc][dt], 0, 0, 0);
                acc[mc][dt] = __builtin_amdgcn_mfma_f32_16x16x32_bf16(ua1, vb1, acc[mc][dt], 0, 0, 0);
            }
            __syncthreads();
        }
    }
    // epilogue: C_u partial, PLAIN stores (no atomics)
    #pragma unroll
    for (int mc = 0; mc < 5; ++mc)
        #pragma unroll
        for (int dt = 0; dt < 4; ++dt)
            #pragma unroll
            for (int r = 0; r < 4; ++r) {
                int m = mc * 64 + w * 16 + quad * 4 + r;
                if (m < M_)
                    dstC[((size_t)bh * M_ + m) * 64 + dt * 16 + ml] = acc[mc][dt][r];
            }
    __syncthreads();
    for (int m = tid; m < M_; m += 256)
        atomicAdd(S_u + bh * M_ + m, Ssum[m]);
    #pragma unroll
    for (int off = 32; off; off >>= 1) lmax = fmaxf(lmax, __shfl_xor(lmax, off));
    __syncthreads();
    if (lane == 0) redf[w] = lmax;
    __syncthreads();
    if (tid == 0) {
        float mxv = fmaxf(fmaxf(redf[0], redf[1]), fmaxf(redf[2], redf[3]));
        atomicMax(mxp + bh, f2ord(mxv));
    }
    for (int j = 0; j < 4; ++j) {
        __syncthreads();
        redf[tid] = vs[j];
        __syncthreads();
        if (tid < 16) {
            float ss = 0.f;
            #pragma unroll
            for (int p = 0; p < 16; ++p) ss += redf[tid + 16 * p];
            atomicAdd(Vsum + bh * 64 + tid * 4 + j, ss);
        }
    }
}

// ---------------- finalize: sum 16 partials, build ks + ctxT(split) + Cs + kss ----------------
// grid (5, 64): x = m-chunk, y = bh
__global__ __launch_bounds__(256) void finalize_kernel(
    const float* __restrict__ S_u, const float* __restrict__ Cpart, const float* __restrict__ C_u,
    const float* __restrict__ Vsum, const unsigned* __restrict__ mxp,
    float* __restrict__ ksum_f, unsigned short* __restrict__ ctxTh,
    unsigned short* __restrict__ ctxTl, float* __restrict__ Cs, float* __restrict__ kss)
{
    __shared__ float T[64 * 65];
    __shared__ float red[256];
    int mc = blockIdx.x, bh = blockIdx.y;
    int tid = threadIdx.x;
    float emx = __expf(-ord2f(mxp[bh]));

    float csacc = 0.f;   // dh = tid&63 fixed across iterations
    #pragma unroll
    for (int i = 0; i < 16; ++i) {
        int idx = i * 256 + tid;
        int dh = idx & 63, mloc = idx >> 6;
        int m = mc * 64 + mloc;
        float v = 0.f;
        if (m < M_) {
            size_t off = ((size_t)bh * M_ + m) * 64 + dh;
            float sacc = C_u[off];
            for (int sp = 0; sp < NSPLIT_ - 1; ++sp)
                sacc += Cpart[(size_t)sp * PARTSZ_ + off];
            v = RATIO_ * (emx * sacc + EPS_ * Vsum[bh * 64 + dh]);
        }
        T[mloc * 65 + dh] = v;
        csacc += v;
    }
    red[tid] = csacc;
    __syncthreads();
    if (tid < 64) atomicAdd(&Cs[bh * 64 + tid], red[tid] + red[tid + 64] + red[tid + 128] + red[tid + 192]);
    // ks + kss
    float ksl = 0.f;
    if (tid < 64) {
        int m = mc * 64 + tid;
        float kv = (m < M_) ? RATIO_ * (emx * S_u[bh * M_ + m] + EPS_ * (float)N_) : 0.f;
        ksum_f[bh * MP_ + m] = kv;
        ksl = kv;
    }
    __syncthreads();
    red[tid] = ksl;
    __syncthreads();
    if (tid == 0) {
        float ss = 0.f;
        for (int p = 0; p < 64; ++p) ss += red[p];
        atomicAdd(kss + bh, ss);
    }
    __syncthreads();
    // transposed split writes: ctxT[dh][m]
    #pragma unroll
    for (int i = 0; i < 8; ++i) {
        int idx = i * 256 + tid;
        int dh = idx >> 5, m2 = (idx & 31) * 2;
        float v0 = T[m2 * 65 + dh], v1 = T[(m2 + 1) * 65 + dh];
        unsigned u0 = __float_as_uint(v0), u1 = __float_as_uint(v1);
        float lo0 = v0 - __uint_as_float(u0 & 0xffff0000u);
        float lo1 = v1 - __uint_as_float(u1 & 0xffff0000u);
        size_t dst = ((size_t)(bh * 64 + dh)) * MP_ + mc * 64 + m2;
        *(unsigned*)&ctxTh[dst] = (u0 >> 16) | (u1 & 0xffff0000u);
        *(unsigned*)&ctxTl[dst] = (__float_as_uint(lo0) >> 16) | (__float_as_uint(lo1) & 0xffff0000u);
    }
}

// ---------------- MFMA query side: T14 async-stage split, 2 barriers/chunk ----------------
// Dedicated ctx LDS (Chs/Cls) so proj isn't clobbered per chunk; ctx[mc] loads issued
// BEFORE phase-1 MFMA (latency hides under compute); proj[mc+1] loads issued BEFORE
// phase-2 MFMA, written to LDS after (all waves are past phase-1 reads by then).
// LDS = 73.5 KB -> 2 blocks/CU (was 57 KB / 2 blocks, same occupancy, half the barriers).
__global__ __launch_bounds__(256) void qattn(
    const float* __restrict__ Q, const unsigned short* __restrict__ projHg,
    const unsigned short* __restrict__ projLg,
    const float* __restrict__ ksum_f, const unsigned short* __restrict__ ctxTh,
    const unsigned short* __restrict__ ctxTl,
    const float* __restrict__ Cs, const float* __restrict__ kss,
    unsigned short* __restrict__ attnH, unsigned short* __restrict__ attnL)
{
    __shared__ __align__(16) unsigned short Qh[64 * KP_], Ql[64 * KP_];
    __shared__ __align__(16) unsigned short Ph[64 * KP_], Pl[64 * KP_];     // proj chunk
    __shared__ __align__(16) unsigned short Chs[64 * KP_], Cls[64 * KP_];   // ctx chunk
    __shared__ __align__(16) unsigned short Uh[64 * KP_], Ul[64 * KP_];
    __shared__ __align__(16) float ks[MP_];
    __shared__ float diag[64];
    float* redf = (float*)Uh;

    int bh = blockIdx.y, b = bh >> 4, h = bh & 15;
    int n0 = blockIdx.x * 64;
    int tid = threadIdx.x, lane = tid & 63, w = tid >> 6;
    int ml = lane & 15, quad = lane >> 4;

    // initial stage: Q split + sq-sums + ks + proj chunk 0 copy
    #pragma unroll
    for (int l = 0; l < 4; ++l) {
        int idx = tid + 256 * l;
        int r = idx >> 4, d4 = (idx & 15) * 4;
        size_t g = ((size_t)(b * N_ + n0 + r)) * D_ + h * DH_ + d4;
        const float4 qv = *(const float4*)(Q + g);
        redf[r * 17 + (tid & 15)] = qv.x * qv.x + qv.y * qv.y + qv.z * qv.z + qv.w * qv.w;
        unsigned h0, l0, h1, l1;
        split2pack(qv.x * DN_, qv.y * DN_, &h0, &l0);
        split2pack(qv.z * DN_, qv.w * DN_, &h1, &l1);
        *(uint2*)&Qh[r * KP_ + d4] = make_uint2(h0, h1);
        *(uint2*)&Ql[r * KP_ + d4] = make_uint2(l0, l1);
    }
    #pragma unroll
    for (int l = 0; l < 2; ++l) {
        int idx = tid + 256 * l;
        int m = idx >> 3, d8 = (idx & 7) * 8;
        *(uint4*)&Ph[m * KP_ + d8] = *(const uint4*)(projHg + m * 64 + d8);
        *(uint4*)&Pl[m * KP_ + d8] = *(const uint4*)(projLg + m * 64 + d8);
    }
    for (int m = tid; m < MP_; m += 256) ks[m] = ksum_f[bh * MP_ + m];
    __syncthreads();
    if (tid < 64) {
        float s = 0.f;
        #pragma unroll
        for (int p = 0; p < 16; ++p) s += redf[tid * 17 + p];
        diag[tid] = s * 0.0625f;
    }
    __syncthreads();

    bfrag qh0 = *(const bfrag*)&Qh[(w * 16 + ml) * KP_ + quad * 8];
    bfrag ql0 = *(const bfrag*)&Ql[(w * 16 + ml) * KP_ + quad * 8];
    bfrag qh1 = *(const bfrag*)&Qh[(w * 16 + ml) * KP_ + 32 + quad * 8];
    bfrag ql1 = *(const bfrag*)&Ql[(w * 16 + ml) * KP_ + 32 + quad * 8];
    float dg = diag[w * 16 + ml];
    float dacc = 0.f, tmax = -1e30f;
    f4 oacc[4];
    #pragma unroll
    for (int i = 0; i < 4; ++i) oacc[i] = (f4){0.f, 0.f, 0.f, 0.f};

    int cidx0 = tid, cidx1 = tid + 256;
    int cdh0 = cidx0 >> 3, cm80 = (cidx0 & 7) * 8;
    int cdh1 = cidx1 >> 3, cm81 = (cidx1 & 7) * 8;

    for (int mc = 0; mc < 5; ++mc) {
        // 1. issue ctx[mc] global loads -> regs (latency hides under phase-1)
        size_t csrc0 = ((size_t)(bh * 64 + cdh0)) * MP_ + mc * 64 + cm80;
        size_t csrc1 = ((size_t)(bh * 64 + cdh1)) * MP_ + mc * 64 + cm81;
        uint4 c0 = *(const uint4*)(ctxTh + csrc0);
        uint4 c1 = *(const uint4*)(ctxTl + csrc0);
        uint4 c2 = *(const uint4*)(ctxTh + csrc1);
        uint4 c3 = *(const uint4*)(ctxTl + csrc1);

        // 2. phase 1: td tiles (reads Ph/Pl + Q frags), writes U rows (wave-private)
        #pragma unroll
        for (int mt = 0; mt < 4; ++mt) {
            int mrow = mt * 16 + ml;
            bfrag ph0 = *(const bfrag*)&Ph[mrow * KP_ + quad * 8];
            bfrag pl0 = *(const bfrag*)&Pl[mrow * KP_ + quad * 8];
            bfrag ph1 = *(const bfrag*)&Ph[mrow * KP_ + 32 + quad * 8];
            bfrag pl1 = *(const bfrag*)&Pl[mrow * KP_ + 32 + quad * 8];
            f4 t = (f4){0.f, 0.f, 0.f, 0.f};
            t = __builtin_amdgcn_mfma_f32_16x16x32_bf16(ph0, qh0, t, 0, 0, 0);
            t = __builtin_amdgcn_mfma_f32_16x16x32_bf16(pl0, qh0, t, 0, 0, 0);
            t = __builtin_amdgcn_mfma_f32_16x16x32_bf16(ph0, ql0, t, 0, 0, 0);
            t = __builtin_amdgcn_mfma_f32_16x16x32_bf16(ph1, qh1, t, 0, 0, 0);
            t = __builtin_amdgcn_mfma_f32_16x16x32_bf16(pl1, qh1, t, 0, 0, 0);
            t = __builtin_amdgcn_mfma_f32_16x16x32_bf16(ph1, ql1, t, 0, 0, 0);
            const float4 ksv = *(const float4*)&ks[mc * 64 + mt * 16 + quad * 4];
            float ksa[4] = {ksv.x, ksv.y, ksv.z, ksv.w};
            unsigned short uh4[4], ul4[4];
            #pragma unroll
            for (int r = 0; r < 4; ++r) {
                int mg = mc * 64 + mt * 16 + quad * 4 + r;
                float tt = t[r];
                float u = __expf(tt - dg);
                if (mg < M_) tmax = fmaxf(tmax, tt);
                dacc = fmaf(u, ksa[r], dacc);
                unsigned uu = __float_as_uint(u);
                float lo = u - __uint_as_float(uu & 0xffff0000u);
                uh4[r] = (unsigned short)(uu >> 16);
                ul4[r] = (unsigned short)(__float_as_uint(lo) >> 16);
            }
            unsigned a0 = (unsigned)uh4[0] | ((unsigned)uh4[1] << 16);
            unsigned a1 = (unsigned)uh4[2] | ((unsigned)uh4[3] << 16);
            unsigned b0 = (unsigned)ul4[0] | ((unsigned)ul4[1] << 16);
            unsigned b1 = (unsigned)ul4[2] | ((unsigned)ul4[3] << 16);
            *(uint2*)&Uh[(w * 16 + ml) * KP_ + mt * 16 + quad * 4] = make_uint2(a0, a1);
            *(uint2*)&Ul[(w * 16 + ml) * KP_ + mt * 16 + quad * 4] = make_uint2(b0, b1);
        }
        // 3. ctx regs -> dedicated LDS
        *(uint4*)&Chs[cdh0 * KP_ + cm80] = c0;
        *(uint4*)&Cls[cdh0 * KP_ + cm80] = c1;
        *(uint4*)&Chs[cdh1 * KP_ + cm81] = c2;
        *(uint4*)&Cls[cdh1 * KP_ + cm81] = c3;
        __syncthreads();

        // 4. issue proj[mc+1] global loads -> regs (latency hides under phase-2)
        uint4 p0, p1, p2, p3;
        if (mc < 4) {
            int mg0 = (mc + 1) * 64 + (cidx0 >> 3);
            int mg1 = (mc + 1) * 64 + (cidx1 >> 3);
            p0 = *(const uint4*)(projHg + mg0 * 64 + cm80);
            p1 = *(const uint4*)(projLg + mg0 * 64 + cm80);
            p2 = *(const uint4*)(projHg + mg1 * 64 + cm81);
            p3 = *(const uint4*)(projLg + mg1 * 64 + cm81);
        }
        // 5. phase 2: oacc += U-tile @ ctx-tile
        bfrag ua0h = *(const bfrag*)&Uh[(w * 16 + ml) * KP_ + quad * 8];
        bfrag ua0l = *(const bfrag*)&Ul[(w * 16 + ml) * KP_ + quad * 8];
        bfrag ua1h = *(const bfrag*)&Uh[(w * 16 + ml) * KP_ + 32 + quad * 8];
        bfrag ua1l = *(const bfrag*)&Ul[(w * 16 + ml) * KP_ + 32 + quad * 8];
        #pragma unroll
        for (int dt = 0; dt < 4; ++dt) {
            bfrag cb0h = *(const bfrag*)&Chs[(dt * 16 + ml) * KP_ + quad * 8];
            bfrag cb0l = *(const bfrag*)&Cls[(dt * 16 + ml) * KP_ + quad * 8];
            bfrag cb1h = *(const bfrag*)&Chs[(dt * 16 + ml) * KP_ + 32 + quad * 8];
            bfrag cb1l = *(const bfrag*)&Cls[(dt * 16 + ml) * KP_ + 32 + quad * 8];
            oacc[dt] = __builtin_amdgcn_mfma_f32_16x16x32_bf16(ua0h, cb0h, oacc[dt], 0, 0, 0);
            oacc[dt] = __builtin_amdgcn_mfma_f32_16x16x32_bf16(ua0l, cb0h, oacc[dt], 0, 0, 0);
            oacc[dt] = __builtin_amdgcn_mfma_f32_16x16x32_bf16(ua0h, cb0l, oacc[dt], 0, 0, 0);
            oacc[dt] = __builtin_amdgcn_mfma_f32_16x16x32_bf16(ua1h, cb1h, oacc[dt], 0, 0, 0);
            oacc[dt] = __builtin_amdgcn_mfma_f32_16x16x32_bf16(ua1l, cb1h, oacc[dt], 0, 0, 0);
            oacc[dt] = __builtin_amdgcn_mfma_f32_16x16x32_bf16(ua1h, cb1l, oacc[dt], 0, 0, 0);
        }
        // 6. proj regs -> LDS (safe: barrier above means all waves finished phase-1 reads)
        if (mc < 4) {
            *(uint4*)&Ph[(cidx0 >> 3) * KP_ + cm80] = p0;
            *(uint4*)&Pl[(cidx0 >> 3) * KP_ + cm80] = p1;
            *(uint4*)&Ph[(cidx1 >> 3) * KP_ + cm81] = p2;
            *(uint4*)&Pl[(cidx1 >> 3) * KP_ + cm81] = p3;
        }
        __syncthreads();
    }
    dacc += __shfl_xor(dacc, 16); dacc += __shfl_xor(dacc, 32);
    tmax = fmaxf(tmax, __shfl_xor(tmax, 16));
    tmax = fmaxf(tmax, __shfl_xor(tmax, 32));
    float fac = EPS_ * __expf(tmax);
    float dinv = 1.f / (dacc + fac * kss[bh]);
    #pragma unroll
    for (int dt = 0; dt < 4; ++dt) {
        float csv = Cs[bh * 64 + dt * 16 + ml];
        #pragma unroll
        for (int r = 0; r < 4; ++r) {
            int srcl = quad * 4 + r;
            float dv = __shfl(dinv, srcl);
            float fv = __shfl(fac, srcl);
            float o = (oacc[dt][r] + fv * csv) * dv;
            int n = n0 + w * 16 + quad * 4 + r;
            size_t gi = ((size_t)(b * N_ + n)) * D_ + h * DH_ + dt * 16 + ml;
            unsigned u = __float_as_uint(o);
            float lo = o - __uint_as_float(u & 0xffff0000u);
            attnH[gi] = (unsigned short)(u >> 16);
            attnL[gi] = (unsigned short)(__float_as_uint(lo) >> 16);
        }
    }
}

// ---------------- launch ----------------
extern "C" void kernel_launch(void* const* d_in, const int* in_sizes, int n_in,
                              void* d_out, int out_size, void* d_ws, size_t ws_size,
                              hipStream_t stream)
{
    const float* x    = (const float*)d_in[0];
    const float* Wq   = (const float*)d_in[1];
    const float* bq   = (const float*)d_in[2];
    const float* Wk   = (const float*)d_in[3];
    const float* bk   = (const float*)d_in[4];
    const float* Wv   = (const float*)d_in[5];
    const float* bv   = (const float*)d_in[6];
    const float* Wo   = (const float*)d_in[7];
    const float* bo   = (const float*)d_in[8];
    const float* Wfc  = (const float*)d_in[9];
    const float* bfc  = (const float*)d_in[10];
    const float* proj = (const float*)d_in[11];
    float* out = (float*)d_out;

    float* ws = (float*)d_ws;
    const size_t nTok = (size_t)B_ * N_ * D_;
    const size_t nSu  = 64 * M_;
    const size_t nCu  = (size_t)64 * M_ * 64;
    const size_t nVs  = 64 * 64;
    const size_t nMx  = 64;
    const size_t nKsf = 64 * MP_;
    const size_t nCtx = (size_t)64 * MP_ * 64;
    const size_t nCs  = 64 * 64;

    const size_t offQ   = 0;
    const size_t offK   = nTok;
    const size_t offV   = nTok * 2;
    const size_t offSu  = nTok * 3;
    const size_t offCu  = offSu + nSu;
    const size_t offVs  = offCu + nCu;
    const size_t offMx  = offVs + nVs;
    const size_t offKsf = offMx + nMx;
    const size_t offCtx = offKsf + nKsf;
    const size_t offCs  = offCtx + nCtx;
    const size_t offKss = offCs + nCs;
    const size_t offWsp = offKss + 64;              // 5 weights split: 5 * 1048576 float-slots
    const size_t offPrj = offWsp + 5242880;         // proj pre-split: 3 * 20480 ushorts

    float* Q    = ws + offQ;
    float* Kb   = ws + offK;
    float* Vb   = ws + offV;
    float* S_u  = ws + offSu;
    float* C_u  = ws + offCu;
    float* Vsum = ws + offVs;
    unsigned* mx = (unsigned*)(ws + offMx);
    float* ksf  = ws + offKsf;
    unsigned short* ctxTh = (unsigned short*)(ws + offCtx);
    unsigned short* ctxTl = ctxTh + (size_t)64 * 64 * MP_;
    float* Cs   = ws + offCs;
    float* kss  = ws + offKss;
    unsigned short* Wsp = (unsigned short*)(ws + offWsp);
    unsigned short* projR  = (unsigned short*)(ws + offPrj);
    unsigned short* projHg = projR + (size_t)MP_ * 64;
    unsigned short* projLg = projHg + (size_t)MP_ * 64;

    // scratch overlays (stream-ordered lifetimes):
    unsigned short* xh = (unsigned short*)out;        // x split lives in d_out, dead before kside
    unsigned short* xl = xh + nTok;
    unsigned short* attnH = (unsigned short*)Kb;      // K dead after kside
    unsigned short* attnL = attnH + nTok;
    unsigned short* hbH = (unsigned short*)Vb;        // V dead after kside
    unsigned short* hbL = hbH + nTok;
    float* Cpart = out;                               // d_out as scratch for 15 C_u partials

    // zero S_u..kss (covers S_u, C_u, Vsum, mx, ksf, ctxT, Cs, kss)
    int nzero = (int)(nSu + nCu + nVs + nMx + nKsf + nCtx + nCs + 64);
    zero_kernel<<<dim3((nzero + 255) / 256), dim3(256), 0, stream>>>(S_u, nzero);

    // one-shot conversions
    split_f32<<<dim3(16384), dim3(256), 0, stream>>>(x, xh, xl, (int)(nTok / 4));
    split_w5<<<dim3(1024, 5), dim3(256), 0, stream>>>(Wq, Wk, Wv, Wo, Wfc, Wsp);
    presplit_proj<<<dim3(80), dim3(256), 0, stream>>>(proj, projR, projHg, projLg);

    gemm_qkv_s<<<dim3(24, (B_ * N_) / 128), dim3(256), 0, stream>>>(
        xh, xl, Wsp, bq, bk, bv, Q, Kb, Vb);

    kside<<<dim3(NSPLIT_, 64), dim3(256), 0, stream>>>(Kb, Vb, projR, S_u, Cpart, C_u, Vsum, mx);
    finalize_kernel<<<dim3(5, 64), dim3(256), 0, stream>>>(S_u, Cpart, C_u, Vsum, mx, ksf, ctxTh, ctxTl, Cs, kss);
    qattn<<<dim3(64, 64), dim3(256), 0, stream>>>(Q, projHg, projLg, ksf, ctxTh, ctxTl, Cs, kss, attnH, attnL);

    dim3 gg(D_ / 128, (B_ * N_) / 128);
    // Wo: split-bf16 A (attn) -> split-bf16 hbuf
    gemm_nt_s<<<gg, dim3(256), 0, stream>>>(attnH, attnL,
        Wsp + (size_t)3 * 2097152, Wsp + (size_t)3 * 2097152 + 1048576,
        bo, (float*)nullptr, hbH, hbL, 2);
    // Wfc: split-bf16 A (hbuf) -> fp32 out + relu
    gemm_nt_s<<<gg, dim3(256), 0, stream>>>(hbH, hbL,
        Wsp + (size_t)4 * 2097152, Wsp + (size_t)4 * 2097152 + 1048576,
        bfc, out, (unsigned short*)nullptr, (unsigned short*)nullptr, 1);
}

// Round 9
// 972.370 us; speedup vs baseline: 1.1313x; 1.0005x over previous
//
#include <hip/hip_runtime.h>
#include <math.h>

#define B_ 4
#define N_ 4096
#define D_ 1024
#define H_ 16
#define DH_ 64
#define M_ 266
#define MP_ 320   // M padded to 5 chunks of 64

#define DN_ 0.35355339059327373f      // 64^-0.25
#define RATIO_ 0.06131393394849658f   // 266^-0.5
#define EPS_ 1e-4f
#define KP_ 72    // ushort row stride
#define NSPLIT_ 16
#define PARTSZ_ ((size_t)64 * M_ * 64)   // one C_u partial (all bh)

typedef __attribute__((ext_vector_type(8))) short bfrag;
typedef __attribute__((ext_vector_type(4))) float f4;

__device__ __forceinline__ unsigned f2ord(float f) {
    unsigned u = __float_as_uint(f);
    return (u & 0x80000000u) ? ~u : (u | 0x80000000u);
}
__device__ __forceinline__ float ord2f(unsigned u) {
    unsigned b = (u & 0x80000000u) ? (u & 0x7fffffffu) : ~u;
    return __uint_as_float(b);
}

__global__ void zero_kernel(float* __restrict__ p, int n) {
    int i = blockIdx.x * 256 + threadIdx.x;
    if (i < n) p[i] = 0.f;
}

__device__ __forceinline__ void split2pack(float x, float y, unsigned* hp, unsigned* lp) {
    unsigned ux = __float_as_uint(x), uy = __float_as_uint(y);
    float hx = __uint_as_float(ux & 0xffff0000u);
    float hy = __uint_as_float(uy & 0xffff0000u);
    float lx = x - hx, ly = y - hy;
    *hp = (ux >> 16) | (uy & 0xffff0000u);
    *lp = (__float_as_uint(lx) >> 16) | (__float_as_uint(ly) & 0xffff0000u);
}
__device__ __forceinline__ unsigned short bf16rne(float x) {
    unsigned u = __float_as_uint(x);
    return (unsigned short)((u + 0x7fffu + ((u >> 16) & 1u)) >> 16);
}

// async global->LDS 16B (dwordx4). LDS dst must be wave-uniform; lane writes dst+lane*16.
__device__ __forceinline__ void async_cp16(const void* g, void* l) {
    __builtin_amdgcn_global_load_lds(
        (const __attribute__((address_space(1))) void*)g,
        (__attribute__((address_space(3))) void*)l, 16, 0, 0);
}

// ---------------- one-shot split conversions (each element converted exactly once) --------
__global__ __launch_bounds__(256) void split_f32(const float* __restrict__ X,
        unsigned short* __restrict__ Xh, unsigned short* __restrict__ Xl, int n4)
{
    int i = blockIdx.x * 256 + threadIdx.x;
    if (i >= n4) return;
    const float4 v = ((const float4*)X)[i];
    unsigned h0, l0, h1, l1;
    split2pack(v.x, v.y, &h0, &l0);
    split2pack(v.z, v.w, &h1, &l1);
    ((uint2*)Xh)[i] = make_uint2(h0, h1);
    ((uint2*)Xl)[i] = make_uint2(l0, l1);
}

// 5 weights (1024x1024 each) -> Wsp: per sel, h at sel*2097152, l at +1048576 (ushort units)
__global__ __launch_bounds__(256) void split_w5(const float* __restrict__ W0,
        const float* __restrict__ W1, const float* __restrict__ W2,
        const float* __restrict__ W3, const float* __restrict__ W4,
        unsigned short* __restrict__ Wsp)
{
    int sel = blockIdx.y;
    const float* W = (sel == 0) ? W0 : (sel == 1) ? W1 : (sel == 2) ? W2 : (sel == 3) ? W3 : W4;
    unsigned short* h = Wsp + (size_t)sel * 2097152;
    unsigned short* l = h + 1048576;
    int i = blockIdx.x * 256 + threadIdx.x;   // 1024*256 threads * 4 elems = 1048576
    const float4 v = ((const float4*)W)[i];
    unsigned h0, l0, h1, l1;
    split2pack(v.x, v.y, &h0, &l0);
    split2pack(v.z, v.w, &h1, &l1);
    ((uint2*)h)[i] = make_uint2(h0, h1);
    ((uint2*)l)[i] = make_uint2(l0, l1);
}

// proj (266x64) pre-converted ONCE, padded to MP_ rows with zeros.
__global__ __launch_bounds__(256) void presplit_proj(const float* __restrict__ proj,
        unsigned short* __restrict__ projR, unsigned short* __restrict__ projHg,
        unsigned short* __restrict__ projLg)
{
    int i = blockIdx.x * 256 + threadIdx.x;   // 80 blocks * 256 = 20480 = MP_*64
    int m = i >> 6, d = i & 63;
    float v = (m < M_) ? proj[m * 64 + d] : 0.f;
    projR[i] = bf16rne(v);
    unsigned u = __float_as_uint(v);
    float lo = v - __uint_as_float(u & 0xffff0000u);
    projHg[i] = (unsigned short)(u >> 16);
    projLg[i] = (unsigned short)(__float_as_uint(lo) >> 16);
}

// ---------------- fused QKV GEMM (128x128 stage-serial, proven 310us) ----------------------
__global__ __launch_bounds__(256) void gemm_qkv_s(
        const unsigned short* __restrict__ Ah, const unsigned short* __restrict__ Al,
        const unsigned short* __restrict__ Wsp,
        const float* __restrict__ b0, const float* __restrict__ b1, const float* __restrict__ b2,
        float* __restrict__ C0, float* __restrict__ C1, float* __restrict__ C2)
{
    __shared__ __align__(16) unsigned short Ahs[128 * 32];
    __shared__ __align__(16) unsigned short Als[128 * 32];
    __shared__ __align__(16) unsigned short Bhs[128 * 32];
    __shared__ __align__(16) unsigned short Bls[128 * 32];

    int tid = threadIdx.x;
    int sel = blockIdx.x >> 3;               // 0..2 -> q,k,v
    int bn = (blockIdx.x & 7) * 128;
    int bm = blockIdx.y * 128;
    const unsigned short* Bh = Wsp + (size_t)sel * 2097152;
    const unsigned short* Bl = Bh + 1048576;
    const float* bias = (sel == 0) ? b0 : (sel == 1) ? b1 : b2;
    float* C = (sel == 0) ? C0 : (sel == 1) ? C1 : C2;

    int lane = tid & 63;
    int w = tid >> 6;
    int wm = w >> 1, wn = w & 1;
    int ml = lane & 15, kq = lane >> 4;
    int rsub = lane >> 2;
    int ksw = (((lane & 3) ^ ((lane >> 3) & 3))) * 8;   // swizzled source K-slot (ushorts)
    int slot8 = ((kq ^ ((ml >> 1) & 3))) * 8;           // swizzled read K-slot (ushorts)

    f4 acc[4][4];
    #pragma unroll
    for (int i = 0; i < 4; ++i)
        #pragma unroll
        for (int j = 0; j < 4; ++j)
            acc[i][j] = (f4){0.f, 0.f, 0.f, 0.f};

    for (int kt = 0; kt < D_; kt += 32) {
        __syncthreads();
        #pragma unroll
        for (int j = 0; j < 2; ++j) {
            int row = w * 32 + j * 16;                        // wave-uniform
            size_t ga = (size_t)(bm + row + rsub) * D_ + kt + ksw;
            size_t gb = (size_t)(bn + row + rsub) * D_ + kt + ksw;
            async_cp16(Ah + ga, &Ahs[row * 32]);
            async_cp16(Al + ga, &Als[row * 32]);
            async_cp16(Bh + gb, &Bhs[row * 32]);
            async_cp16(Bl + gb, &Bls[row * 32]);
        }
        __syncthreads();
        bfrag ah[4], al[4], bh[4], bl[4];
        #pragma unroll
        for (int i = 0; i < 4; ++i) {
            int arow = wm * 64 + i * 16 + ml;
            ah[i] = *(const bfrag*)&Ahs[arow * 32 + slot8];
            al[i] = *(const bfrag*)&Als[arow * 32 + slot8];
            int brow = wn * 64 + i * 16 + ml;
            bh[i] = *(const bfrag*)&Bhs[brow * 32 + slot8];
            bl[i] = *(const bfrag*)&Bls[brow * 32 + slot8];
        }
        #pragma unroll
        for (int mi = 0; mi < 4; ++mi)
            #pragma unroll
            for (int ni = 0; ni < 4; ++ni) {
                acc[mi][ni] = __builtin_amdgcn_mfma_f32_16x16x32_bf16(ah[mi], bh[ni], acc[mi][ni], 0, 0, 0);
                acc[mi][ni] = __builtin_amdgcn_mfma_f32_16x16x32_bf16(al[mi], bh[ni], acc[mi][ni], 0, 0, 0);
                acc[mi][ni] = __builtin_amdgcn_mfma_f32_16x16x32_bf16(ah[mi], bl[ni], acc[mi][ni], 0, 0, 0);
            }
    }
    #pragma unroll
    for (int ni = 0; ni < 4; ++ni) {
        int col = bn + wn * 64 + ni * 16 + ml;
        float bv = bias[col];
        #pragma unroll
        for (int mi = 0; mi < 4; ++mi) {
            int row0 = bm + wm * 64 + mi * 16 + kq * 4;
            #pragma unroll
            for (int r = 0; r < 4; ++r)
                C[(size_t)(row0 + r) * D_ + col] = acc[mi][ni][r] + bv;
        }
    }
}

// ---------------- generic NT GEMM on pre-split operands (Wo / Wfc) ----------------
// mode 0: fp32+bias; mode 1: fp32+bias+relu; mode 2: split-bf16 write (+bias)
__global__ __launch_bounds__(256) void gemm_nt_s(
        const unsigned short* __restrict__ Ah, const unsigned short* __restrict__ Al,
        const unsigned short* __restrict__ Bh, const unsigned short* __restrict__ Bl,
        const float* __restrict__ bias, float* __restrict__ C,
        unsigned short* __restrict__ Ch, unsigned short* __restrict__ Cl, int mode)
{
    __shared__ __align__(16) unsigned short Ahs[128 * 32];
    __shared__ __align__(16) unsigned short Als[128 * 32];
    __shared__ __align__(16) unsigned short Bhs[128 * 32];
    __shared__ __align__(16) unsigned short Bls[128 * 32];

    int tid = threadIdx.x;
    int bn = blockIdx.x * 128;
    int bm = blockIdx.y * 128;
    int lane = tid & 63;
    int w = tid >> 6;
    int wm = w >> 1, wn = w & 1;
    int ml = lane & 15, kq = lane >> 4;
    int rsub = lane >> 2;
    int ksw = (((lane & 3) ^ ((lane >> 3) & 3))) * 8;
    int slot8 = ((kq ^ ((ml >> 1) & 3))) * 8;

    f4 acc[4][4];
    #pragma unroll
    for (int i = 0; i < 4; ++i)
        #pragma unroll
        for (int j = 0; j < 4; ++j)
            acc[i][j] = (f4){0.f, 0.f, 0.f, 0.f};

    for (int kt = 0; kt < D_; kt += 32) {
        __syncthreads();
        #pragma unroll
        for (int j = 0; j < 2; ++j) {
            int row = w * 32 + j * 16;
            size_t ga = (size_t)(bm + row + rsub) * D_ + kt + ksw;
            size_t gb = (size_t)(bn + row + rsub) * D_ + kt + ksw;
            async_cp16(Ah + ga, &Ahs[row * 32]);
            async_cp16(Al + ga, &Als[row * 32]);
            async_cp16(Bh + gb, &Bhs[row * 32]);
            async_cp16(Bl + gb, &Bls[row * 32]);
        }
        __syncthreads();
        bfrag ah[4], al[4], bh[4], bl[4];
        #pragma unroll
        for (int i = 0; i < 4; ++i) {
            int arow = wm * 64 + i * 16 + ml;
            ah[i] = *(const bfrag*)&Ahs[arow * 32 + slot8];
            al[i] = *(const bfrag*)&Als[arow * 32 + slot8];
            int brow = wn * 64 + i * 16 + ml;
            bh[i] = *(const bfrag*)&Bhs[brow * 32 + slot8];
            bl[i] = *(const bfrag*)&Bls[brow * 32 + slot8];
        }
        #pragma unroll
        for (int mi = 0; mi < 4; ++mi)
            #pragma unroll
            for (int ni = 0; ni < 4; ++ni) {
                acc[mi][ni] = __builtin_amdgcn_mfma_f32_16x16x32_bf16(ah[mi], bh[ni], acc[mi][ni], 0, 0, 0);
                acc[mi][ni] = __builtin_amdgcn_mfma_f32_16x16x32_bf16(al[mi], bh[ni], acc[mi][ni], 0, 0, 0);
                acc[mi][ni] = __builtin_amdgcn_mfma_f32_16x16x32_bf16(ah[mi], bl[ni], acc[mi][ni], 0, 0, 0);
            }
    }
    #pragma unroll
    for (int ni = 0; ni < 4; ++ni) {
        int col = bn + wn * 64 + ni * 16 + ml;
        float bv = bias[col];
        #pragma unroll
        for (int mi = 0; mi < 4; ++mi) {
            int row0 = bm + wm * 64 + mi * 16 + kq * 4;
            #pragma unroll
            for (int r = 0; r < 4; ++r) {
                float o = acc[mi][ni][r] + bv;
                size_t idx = (size_t)(row0 + r) * D_ + col;
                if (mode == 2) {
                    unsigned u = __float_as_uint(o);
                    float lo = o - __uint_as_float(u & 0xffff0000u);
                    Ch[idx] = (unsigned short)(u >> 16);
                    Cl[idx] = (unsigned short)(__float_as_uint(lo) >> 16);
                } else {
                    if (mode == 1) o = fmaxf(o, 0.f);
                    C[idx] = o;
                }
            }
        }
    }
}

// ---------------- MFMA key side, atomic-free C_u, single-bf16 phase1 ----------------
// grid (NSPLIT_=16, 64): x = n-split (256 rows), y = bh. 4 waves.
__global__ __launch_bounds__(256) void kside(
    const float* __restrict__ Kin, const float* __restrict__ Vin,
    const unsigned short* __restrict__ projR,
    float* __restrict__ S_u, float* __restrict__ Cpart, float* __restrict__ C_u,
    float* __restrict__ Vsum, unsigned int* __restrict__ mxp)
{
    __shared__ __align__(16) unsigned short Kh[64 * KP_];      // [n][d] bf16 RNE (pre-scaled by dn)
    __shared__ __align__(16) unsigned short VT[64 * KP_];      // [dh][n] bf16 RNE
    __shared__ __align__(16) unsigned short Ph[2][64 * KP_];   // proj [m][d] bf16 RNE, ping-pong
    __shared__ __align__(16) unsigned short Us[64 * KP_];      // [m][n] bf16 RNE
    __shared__ __align__(16) float Ssum[MP_];
    __shared__ float diag[64];
    float* redf = (float*)Us;   // overlay (lifetimes separated by barriers)

    int bh = blockIdx.y, b = bh >> 4, h = bh & 15;
    int s = blockIdx.x;
    int n0 = s * 256;
    int tid = threadIdx.x, lane = tid & 63, w = tid >> 6;
    int ml = lane & 15, quad = lane >> 4;

    float* dstC = (s < NSPLIT_ - 1) ? (Cpart + (size_t)s * PARTSZ_) : C_u;

    for (int i = tid; i < MP_; i += 256) Ssum[i] = 0.f;

    f4 acc[5][4];
    #pragma unroll
    for (int i = 0; i < 5; ++i)
        #pragma unroll
        for (int j = 0; j < 4; ++j) acc[i][j] = (f4){0.f, 0.f, 0.f, 0.f};
    float vs[4] = {0.f, 0.f, 0.f, 0.f};
    float lmax = -1e30f;

    for (int nc = 0; nc < 4; ++nc) {
        __syncthreads();
        // stage K (RNE, *dn), V^T (RNE), diag partials, and proj chunk 0 (copy)
        #pragma unroll
        for (int l = 0; l < 4; ++l) {
            int idx = tid + 256 * l;
            int r = idx >> 4;
            int d4 = (idx & 15) * 4;
            size_t g = ((size_t)(b * N_ + n0 + nc * 64 + r)) * D_ + h * DH_ + d4;
            const float4 kv = *(const float4*)(Kin + g);
            redf[r * 17 + (tid & 15)] = kv.x * kv.x + kv.y * kv.y + kv.z * kv.z + kv.w * kv.w;
            unsigned w0 = (unsigned)bf16rne(kv.x * DN_) | ((unsigned)bf16rne(kv.y * DN_) << 16);
            unsigned w1 = (unsigned)bf16rne(kv.z * DN_) | ((unsigned)bf16rne(kv.w * DN_) << 16);
            *(uint2*)&Kh[r * KP_ + d4] = make_uint2(w0, w1);
            const float4 vv = *(const float4*)(Vin + g);
            vs[0] += vv.x; vs[1] += vv.y; vs[2] += vv.z; vs[3] += vv.w;
            VT[(d4 + 0) * KP_ + r] = bf16rne(vv.x);
            VT[(d4 + 1) * KP_ + r] = bf16rne(vv.y);
            VT[(d4 + 2) * KP_ + r] = bf16rne(vv.z);
            VT[(d4 + 3) * KP_ + r] = bf16rne(vv.w);
        }
        {   // proj chunk 0 -> Ph[0] (pure copy)
            #pragma unroll
            for (int l = 0; l < 2; ++l) {
                int idx = tid + 256 * l;
                int m = idx >> 3, d8 = (idx & 7) * 8;
                *(uint4*)&Ph[0][m * KP_ + d8] = *(const uint4*)(projR + m * 64 + d8);
            }
        }
        __syncthreads();
        if (tid < 64) {
            float ss = 0.f;
            #pragma unroll
            for (int p = 0; p < 16; ++p) ss += redf[tid * 17 + p];
            diag[tid] = ss * 0.0625f;
        }
        __syncthreads();

        bfrag kh0 = *(const bfrag*)&Kh[(w * 16 + ml) * KP_ + quad * 8];
        bfrag kh1 = *(const bfrag*)&Kh[(w * 16 + ml) * KP_ + 32 + quad * 8];
        float dgv[4];
        #pragma unroll
        for (int r = 0; r < 4; ++r) dgv[r] = diag[w * 16 + quad * 4 + r];

        for (int mc = 0; mc < 5; ++mc) {
            int pb = mc & 1;
            // prefetch next proj chunk (copy; overlaps phase-1 MFMA)
            uint4 pf2[2];
            if (mc < 4) {
                #pragma unroll
                for (int l = 0; l < 2; ++l) {
                    int idx = tid + 256 * l;
                    int m = idx >> 3, d8 = (idx & 7) * 8;
                    int mg = (mc + 1) * 64 + m;      // < MP_, zero-padded
                    pf2[l] = *(const uint4*)(projR + mg * 64 + d8);
                }
            }
            // phase 1: td[n][m] tiles, single-bf16
            #pragma unroll
            for (int mt = 0; mt < 4; ++mt) {
                int mrow = mt * 16 + ml;
                bfrag ph0 = *(const bfrag*)&Ph[pb][mrow * KP_ + quad * 8];
                bfrag ph1 = *(const bfrag*)&Ph[pb][mrow * KP_ + 32 + quad * 8];
                f4 t = (f4){0.f, 0.f, 0.f, 0.f};
                t = __builtin_amdgcn_mfma_f32_16x16x32_bf16(kh0, ph0, t, 0, 0, 0);
                t = __builtin_amdgcn_mfma_f32_16x16x32_bf16(kh1, ph1, t, 0, 0, 0);
                bool mv = (mc * 64 + mrow) < M_;
                float su = 0.f;
                unsigned short up[4];
                #pragma unroll
                for (int r = 0; r < 4; ++r) {
                    float u = 0.f;
                    if (mv) {
                        float tt = t[r];
                        lmax = fmaxf(lmax, tt);
                        u = __expf(tt - dgv[r]);
                    }
                    su += u;
                    up[r] = bf16rne(u);
                }
                su += __shfl_xor(su, 16);
                su += __shfl_xor(su, 32);
                if (mv && quad == 0) atomicAdd(&Ssum[mc * 64 + mrow], su);
                unsigned w0 = (unsigned)up[0] | ((unsigned)up[1] << 16);
                unsigned w1 = (unsigned)up[2] | ((unsigned)up[3] << 16);
                *(uint2*)&Us[mrow * KP_ + w * 16 + quad * 4] = make_uint2(w0, w1);
            }
            // store prefetched proj
            if (mc < 4) {
                #pragma unroll
                for (int l = 0; l < 2; ++l) {
                    int idx = tid + 256 * l;
                    int m = idx >> 3, d8 = (idx & 7) * 8;
                    *(uint4*)&Ph[1 - pb][m * KP_ + d8] = pf2[l];
                }
            }
            __syncthreads();
            // phase 2: acc[mc] += Us^T-tile @ V
            bfrag ua0 = *(const bfrag*)&Us[(w * 16 + ml) * KP_ + quad * 8];
            bfrag ua1 = *(const bfrag*)&Us[(w * 16 + ml) * KP_ + 32 + quad * 8];
            #pragma unroll
            for (int dt = 0; dt < 4; ++dt) {
                bfrag vb0 = *(const bfrag*)&VT[(dt * 16 + ml) * KP_ + quad * 8];
                bfrag vb1 = *(const bfrag*)&VT[(dt * 16 + ml) * KP_ + 32 + quad * 8];
                acc[mc][dt] = __builtin_amdgcn_mfma_f32_16x16x32_bf16(ua0, vb0, acc[mc][dt], 0, 0, 0);
                acc[mc][dt] = __builtin_amdgcn_mfma_f32_16x16x32_bf16(ua1, vb1, acc[mc][dt], 0, 0, 0);
            }
            __syncthreads();
        }
    }
    // epilogue: C_u partial, PLAIN stores (no atomics)
    #pragma unroll
    for (int mc = 0; mc < 5; ++mc)
        #pragma unroll
        for (int dt = 0; dt < 4; ++dt)
            #pragma unroll
            for (int r = 0; r < 4; ++r) {
                int m = mc * 64 + w * 16 + quad * 4 + r;
                if (m < M_)
                    dstC[((size_t)bh * M_ + m) * 64 + dt * 16 + ml] = acc[mc][dt][r];
            }
    __syncthreads();
    for (int m = tid; m < M_; m += 256)
        atomicAdd(S_u + bh * M_ + m, Ssum[m]);
    #pragma unroll
    for (int off = 32; off; off >>= 1) lmax = fmaxf(lmax, __shfl_xor(lmax, off));
    __syncthreads();
    if (lane == 0) redf[w] = lmax;
    __syncthreads();
    if (tid == 0) {
        float mxv = fmaxf(fmaxf(redf[0], redf[1]), fmaxf(redf[2], redf[3]));
        atomicMax(mxp + bh, f2ord(mxv));
    }
    for (int j = 0; j < 4; ++j) {
        __syncthreads();
        redf[tid] = vs[j];
        __syncthreads();
        if (tid < 16) {
            float ss = 0.f;
            #pragma unroll
            for (int p = 0; p < 16; ++p) ss += redf[tid + 16 * p];
            atomicAdd(Vsum + bh * 64 + tid * 4 + j, ss);
        }
    }
}

// ---------------- finalize: sum 16 partials, build ks + ctxT(split) + Cs + kss ----------------
// grid (5, 64): x = m-chunk, y = bh
__global__ __launch_bounds__(256) void finalize_kernel(
    const float* __restrict__ S_u, const float* __restrict__ Cpart, const float* __restrict__ C_u,
    const float* __restrict__ Vsum, const unsigned* __restrict__ mxp,
    float* __restrict__ ksum_f, unsigned short* __restrict__ ctxTh,
    unsigned short* __restrict__ ctxTl, float* __restrict__ Cs, float* __restrict__ kss)
{
    __shared__ float T[64 * 65];
    __shared__ float red[256];
    int mc = blockIdx.x, bh = blockIdx.y;
    int tid = threadIdx.x;
    float emx = __expf(-ord2f(mxp[bh]));

    float csacc = 0.f;   // dh = tid&63 fixed across iterations
    #pragma unroll
    for (int i = 0; i < 16; ++i) {
        int idx = i * 256 + tid;
        int dh = idx & 63, mloc = idx >> 6;
        int m = mc * 64 + mloc;
        float v = 0.f;
        if (m < M_) {
            size_t off = ((size_t)bh * M_ + m) * 64 + dh;
            float sacc = C_u[off];
            for (int sp = 0; sp < NSPLIT_ - 1; ++sp)
                sacc += Cpart[(size_t)sp * PARTSZ_ + off];
            v = RATIO_ * (emx * sacc + EPS_ * Vsum[bh * 64 + dh]);
        }
        T[mloc * 65 + dh] = v;
        csacc += v;
    }
    red[tid] = csacc;
    __syncthreads();
    if (tid < 64) atomicAdd(&Cs[bh * 64 + tid], red[tid] + red[tid + 64] + red[tid + 128] + red[tid + 192]);
    // ks + kss
    float ksl = 0.f;
    if (tid < 64) {
        int m = mc * 64 + tid;
        float kv = (m < M_) ? RATIO_ * (emx * S_u[bh * M_ + m] + EPS_ * (float)N_) : 0.f;
        ksum_f[bh * MP_ + m] = kv;
        ksl = kv;
    }
    __syncthreads();
    red[tid] = ksl;
    __syncthreads();
    if (tid == 0) {
        float ss = 0.f;
        for (int p = 0; p < 64; ++p) ss += red[p];
        atomicAdd(kss + bh, ss);
    }
    __syncthreads();
    // transposed split writes: ctxT[dh][m]
    #pragma unroll
    for (int i = 0; i < 8; ++i) {
        int idx = i * 256 + tid;
        int dh = idx >> 5, m2 = (idx & 31) * 2;
        float v0 = T[m2 * 65 + dh], v1 = T[(m2 + 1) * 65 + dh];
        unsigned u0 = __float_as_uint(v0), u1 = __float_as_uint(v1);
        float lo0 = v0 - __uint_as_float(u0 & 0xffff0000u);
        float lo1 = v1 - __uint_as_float(u1 & 0xffff0000u);
        size_t dst = ((size_t)(bh * 64 + dh)) * MP_ + mc * 64 + m2;
        *(unsigned*)&ctxTh[dst] = (u0 >> 16) | (u1 & 0xffff0000u);
        *(unsigned*)&ctxTl[dst] = (__float_as_uint(lo0) >> 16) | (__float_as_uint(lo1) & 0xffff0000u);
    }
}

// ---------------- MFMA query side: 8 waves, 128 Q-rows/block ----------------
// Same fragment math as R8 (T14 async-stage, dedicated ctx LDS, 2 barriers/chunk) but each
// block amortizes proj+ctx+ks+diag staging over 2x the Q-rows. Occupancy preserved:
// LDS ~110 KB -> 1 block/CU x 8 waves = same 8 waves/CU as before (2 blocks x 4 waves).
__global__ __launch_bounds__(512) void qattn(
    const float* __restrict__ Q, const unsigned short* __restrict__ projHg,
    const unsigned short* __restrict__ projLg,
    const float* __restrict__ ksum_f, const unsigned short* __restrict__ ctxTh,
    const unsigned short* __restrict__ ctxTl,
    const float* __restrict__ Cs, const float* __restrict__ kss,
    unsigned short* __restrict__ attnH, unsigned short* __restrict__ attnL)
{
    __shared__ __align__(16) unsigned short Qh[128 * KP_], Ql[128 * KP_];
    __shared__ __align__(16) unsigned short Ph[64 * KP_], Pl[64 * KP_];     // proj chunk
    __shared__ __align__(16) unsigned short Chs[64 * KP_], Cls[64 * KP_];   // ctx chunk
    __shared__ __align__(16) unsigned short Uh[128 * KP_], Ul[128 * KP_];
    __shared__ __align__(16) float ks[MP_];
    __shared__ float diag[128];
    float* redf = (float*)Uh;

    int bh = blockIdx.y, b = bh >> 4, h = bh & 15;
    int n0 = blockIdx.x * 128;
    int tid = threadIdx.x, lane = tid & 63, w = tid >> 6;   // w = 0..7
    int ml = lane & 15, quad = lane >> 4;

    // initial stage: Q split + sq-sums + ks + proj chunk 0 copy
    #pragma unroll
    for (int l = 0; l < 4; ++l) {
        int idx = tid + 512 * l;
        int r = idx >> 4, d4 = (idx & 15) * 4;
        size_t g = ((size_t)(b * N_ + n0 + r)) * D_ + h * DH_ + d4;
        const float4 qv = *(const float4*)(Q + g);
        redf[r * 17 + (idx & 15)] = qv.x * qv.x + qv.y * qv.y + qv.z * qv.z + qv.w * qv.w;
        unsigned h0, l0, h1, l1;
        split2pack(qv.x * DN_, qv.y * DN_, &h0, &l0);
        split2pack(qv.z * DN_, qv.w * DN_, &h1, &l1);
        *(uint2*)&Qh[r * KP_ + d4] = make_uint2(h0, h1);
        *(uint2*)&Ql[r * KP_ + d4] = make_uint2(l0, l1);
    }
    {
        int m = tid >> 3, d8 = (tid & 7) * 8;
        *(uint4*)&Ph[m * KP_ + d8] = *(const uint4*)(projHg + m * 64 + d8);
        *(uint4*)&Pl[m * KP_ + d8] = *(const uint4*)(projLg + m * 64 + d8);
    }
    for (int m = tid; m < MP_; m += 512) ks[m] = ksum_f[bh * MP_ + m];
    __syncthreads();
    if (tid < 128) {
        float s = 0.f;
        #pragma unroll
        for (int p = 0; p < 16; ++p) s += redf[tid * 17 + p];
        diag[tid] = s * 0.0625f;
    }
    __syncthreads();

    bfrag qh0 = *(const bfrag*)&Qh[(w * 16 + ml) * KP_ + quad * 8];
    bfrag ql0 = *(const bfrag*)&Ql[(w * 16 + ml) * KP_ + quad * 8];
    bfrag qh1 = *(const bfrag*)&Qh[(w * 16 + ml) * KP_ + 32 + quad * 8];
    bfrag ql1 = *(const bfrag*)&Ql[(w * 16 + ml) * KP_ + 32 + quad * 8];
    float dg = diag[w * 16 + ml];
    float dacc = 0.f, tmax = -1e30f;
    f4 oacc[4];
    #pragma unroll
    for (int i = 0; i < 4; ++i) oacc[i] = (f4){0.f, 0.f, 0.f, 0.f};

    int cdh = tid >> 3, cm8 = (tid & 7) * 8;     // 512 threads cover 64x64 chunk (1 uint4 each)

    for (int mc = 0; mc < 5; ++mc) {
        // 1. issue ctx[mc] global loads -> regs (latency hides under phase-1)
        size_t csrc = ((size_t)(bh * 64 + cdh)) * MP_ + mc * 64 + cm8;
        uint4 c0 = *(const uint4*)(ctxTh + csrc);
        uint4 c1 = *(const uint4*)(ctxTl + csrc);

        // 2. phase 1: td tiles (reads Ph/Pl + Q frags), writes U rows (wave-private)
        #pragma unroll
        for (int mt = 0; mt < 4; ++mt) {
            int mrow = mt * 16 + ml;
            bfrag ph0 = *(const bfrag*)&Ph[mrow * KP_ + quad * 8];
            bfrag pl0 = *(const bfrag*)&Pl[mrow * KP_ + quad * 8];
            bfrag ph1 = *(const bfrag*)&Ph[mrow * KP_ + 32 + quad * 8];
            bfrag pl1 = *(const bfrag*)&Pl[mrow * KP_ + 32 + quad * 8];
            f4 t = (f4){0.f, 0.f, 0.f, 0.f};
            t = __builtin_amdgcn_mfma_f32_16x16x32_bf16(ph0, qh0, t, 0, 0, 0);
            t = __builtin_amdgcn_mfma_f32_16x16x32_bf16(pl0, qh0, t, 0, 0, 0);
            t = __builtin_amdgcn_mfma_f32_16x16x32_bf16(ph0, ql0, t, 0, 0, 0);
            t = __builtin_amdgcn_mfma_f32_16x16x32_bf16(ph1, qh1, t, 0, 0, 0);
            t = __builtin_amdgcn_mfma_f32_16x16x32_bf16(pl1, qh1, t, 0, 0, 0);
            t = __builtin_amdgcn_mfma_f32_16x16x32_bf16(ph1, ql1, t, 0, 0, 0);
            const float4 ksv = *(const float4*)&ks[mc * 64 + mt * 16 + quad * 4];
            float ksa[4] = {ksv.x, ksv.y, ksv.z, ksv.w};
            unsigned short uh4[4], ul4[4];
            #pragma unroll
            for (int r = 0; r < 4; ++r) {
                int mg = mc * 64 + mt * 16 + quad * 4 + r;
                float tt = t[r];
                float u = __expf(tt - dg);
                if (mg < M_) tmax = fmaxf(tmax, tt);
                dacc = fmaf(u, ksa[r], dacc);
                unsigned uu = __float_as_uint(u);
                float lo = u - __uint_as_float(uu & 0xffff0000u);
                uh4[r] = (unsigned short)(uu >> 16);
                ul4[r] = (unsigned short)(__float_as_uint(lo) >> 16);
            }
            unsigned a0 = (unsigned)uh4[0] | ((unsigned)uh4[1] << 16);
            unsigned a1 = (unsigned)uh4[2] | ((unsigned)uh4[3] << 16);
            unsigned b0 = (unsigned)ul4[0] | ((unsigned)ul4[1] << 16);
            unsigned b1 = (unsigned)ul4[2] | ((unsigned)ul4[3] << 16);
            *(uint2*)&Uh[(w * 16 + ml) * KP_ + mt * 16 + quad * 4] = make_uint2(a0, a1);
            *(uint2*)&Ul[(w * 16 + ml) * KP_ + mt * 16 + quad * 4] = make_uint2(b0, b1);
        }
        // 3. ctx regs -> dedicated LDS
        *(uint4*)&Chs[cdh * KP_ + cm8] = c0;
        *(uint4*)&Cls[cdh * KP_ + cm8] = c1;
        __syncthreads();

        // 4. issue proj[mc+1] global loads -> regs (latency hides under phase-2)
        uint4 p0, p1;
        if (mc < 4) {
            int mg = (mc + 1) * 64 + (tid >> 3);
            p0 = *(const uint4*)(projHg + mg * 64 + cm8);
            p1 = *(const uint4*)(projLg + mg * 64 + cm8);
        }
        // 5. phase 2: oacc += U-tile @ ctx-tile
        bfrag ua0h = *(const bfrag*)&Uh[(w * 16 + ml) * KP_ + quad * 8];
        bfrag ua0l = *(const bfrag*)&Ul[(w * 16 + ml) * KP_ + quad * 8];
        bfrag ua1h = *(const bfrag*)&Uh[(w * 16 + ml) * KP_ + 32 + quad * 8];
        bfrag ua1l = *(const bfrag*)&Ul[(w * 16 + ml) * KP_ + 32 + quad * 8];
        #pragma unroll
        for (int dt = 0; dt < 4; ++dt) {
            bfrag cb0h = *(const bfrag*)&Chs[(dt * 16 + ml) * KP_ + quad * 8];
            bfrag cb0l = *(const bfrag*)&Cls[(dt * 16 + ml) * KP_ + quad * 8];
            bfrag cb1h = *(const bfrag*)&Chs[(dt * 16 + ml) * KP_ + 32 + quad * 8];
            bfrag cb1l = *(const bfrag*)&Cls[(dt * 16 + ml) * KP_ + 32 + quad * 8];
            oacc[dt] = __builtin_amdgcn_mfma_f32_16x16x32_bf16(ua0h, cb0h, oacc[dt], 0, 0, 0);
            oacc[dt] = __builtin_amdgcn_mfma_f32_16x16x32_bf16(ua0l, cb0h, oacc[dt], 0, 0, 0);
            oacc[dt] = __builtin_amdgcn_mfma_f32_16x16x32_bf16(ua0h, cb0l, oacc[dt], 0, 0, 0);
            oacc[dt] = __builtin_amdgcn_mfma_f32_16x16x32_bf16(ua1h, cb1h, oacc[dt], 0, 0, 0);
            oacc[dt] = __builtin_amdgcn_mfma_f32_16x16x32_bf16(ua1l, cb1h, oacc[dt], 0, 0, 0);
            oacc[dt] = __builtin_amdgcn_mfma_f32_16x16x32_bf16(ua1h, cb1l, oacc[dt], 0, 0, 0);
        }
        // 6. proj regs -> LDS (safe: barrier above means all waves finished phase-1 reads)
        if (mc < 4) {
            *(uint4*)&Ph[(tid >> 3) * KP_ + cm8] = p0;
            *(uint4*)&Pl[(tid >> 3) * KP_ + cm8] = p1;
        }
        __syncthreads();
    }
    dacc += __shfl_xor(dacc, 16); dacc += __shfl_xor(dacc, 32);
    tmax = fmaxf(tmax, __shfl_xor(tmax, 16));
    tmax = fmaxf(tmax, __shfl_xor(tmax, 32));
    float fac = EPS_ * __expf(tmax);
    float dinv = 1.f / (dacc + fac * kss[bh]);
    #pragma unroll
    for (int dt = 0; dt < 4; ++dt) {
        float csv = Cs[bh * 64 + dt * 16 + ml];
        #pragma unroll
        for (int r = 0; r < 4; ++r) {
            int srcl = quad * 4 + r;
            float dv = __shfl(dinv, srcl);
            float fv = __shfl(fac, srcl);
            float o = (oacc[dt][r] + fv * csv) * dv;
            int n = n0 + w * 16 + quad * 4 + r;
            size_t gi = ((size_t)(b * N_ + n)) * D_ + h * DH_ + dt * 16 + ml;
            unsigned u = __float_as_uint(o);
            float lo = o - __uint_as_float(u & 0xffff0000u);
            attnH[gi] = (unsigned short)(u >> 16);
            attnL[gi] = (unsigned short)(__float_as_uint(lo) >> 16);
        }
    }
}

// ---------------- launch ----------------
extern "C" void kernel_launch(void* const* d_in, const int* in_sizes, int n_in,
                              void* d_out, int out_size, void* d_ws, size_t ws_size,
                              hipStream_t stream)
{
    const float* x    = (const float*)d_in[0];
    const float* Wq   = (const float*)d_in[1];
    const float* bq   = (const float*)d_in[2];
    const float* Wk   = (const float*)d_in[3];
    const float* bk   = (const float*)d_in[4];
    const float* Wv   = (const float*)d_in[5];
    const float* bv   = (const float*)d_in[6];
    const float* Wo   = (const float*)d_in[7];
    const float* bo   = (const float*)d_in[8];
    const float* Wfc  = (const float*)d_in[9];
    const float* bfc  = (const float*)d_in[10];
    const float* proj = (const float*)d_in[11];
    float* out = (float*)d_out;

    float* ws = (float*)d_ws;
    const size_t nTok = (size_t)B_ * N_ * D_;
    const size_t nSu  = 64 * M_;
    const size_t nCu  = (size_t)64 * M_ * 64;
    const size_t nVs  = 64 * 64;
    const size_t nMx  = 64;
    const size_t nKsf = 64 * MP_;
    const size_t nCtx = (size_t)64 * MP_ * 64;
    const size_t nCs  = 64 * 64;

    const size_t offQ   = 0;
    const size_t offK   = nTok;
    const size_t offV   = nTok * 2;
    const size_t offSu  = nTok * 3;
    const size_t offCu  = offSu + nSu;
    const size_t offVs  = offCu + nCu;
    const size_t offMx  = offVs + nVs;
    const size_t offKsf = offMx + nMx;
    const size_t offCtx = offKsf + nKsf;
    const size_t offCs  = offCtx + nCtx;
    const size_t offKss = offCs + nCs;
    const size_t offWsp = offKss + 64;              // 5 weights split: 5 * 1048576 float-slots
    const size_t offPrj = offWsp + 5242880;         // proj pre-split: 3 * 20480 ushorts

    float* Q    = ws + offQ;
    float* Kb   = ws + offK;
    float* Vb   = ws + offV;
    float* S_u  = ws + offSu;
    float* C_u  = ws + offCu;
    float* Vsum = ws + offVs;
    unsigned* mx = (unsigned*)(ws + offMx);
    float* ksf  = ws + offKsf;
    unsigned short* ctxTh = (unsigned short*)(ws + offCtx);
    unsigned short* ctxTl = ctxTh + (size_t)64 * 64 * MP_;
    float* Cs   = ws + offCs;
    float* kss  = ws + offKss;
    unsigned short* Wsp = (unsigned short*)(ws + offWsp);
    unsigned short* projR  = (unsigned short*)(ws + offPrj);
    unsigned short* projHg = projR + (size_t)MP_ * 64;
    unsigned short* projLg = projHg + (size_t)MP_ * 64;

    // scratch overlays (stream-ordered lifetimes):
    unsigned short* xh = (unsigned short*)out;        // x split lives in d_out, dead before kside
    unsigned short* xl = xh + nTok;
    unsigned short* attnH = (unsigned short*)Kb;      // K dead after kside
    unsigned short* attnL = attnH + nTok;
    unsigned short* hbH = (unsigned short*)Vb;        // V dead after kside
    unsigned short* hbL = hbH + nTok;
    float* Cpart = out;                               // d_out as scratch for 15 C_u partials

    // zero S_u..kss (covers S_u, C_u, Vsum, mx, ksf, ctxT, Cs, kss)
    int nzero = (int)(nSu + nCu + nVs + nMx + nKsf + nCtx + nCs + 64);
    zero_kernel<<<dim3((nzero + 255) / 256), dim3(256), 0, stream>>>(S_u, nzero);

    // one-shot conversions
    split_f32<<<dim3(16384), dim3(256), 0, stream>>>(x, xh, xl, (int)(nTok / 4));
    split_w5<<<dim3(1024, 5), dim3(256), 0, stream>>>(Wq, Wk, Wv, Wo, Wfc, Wsp);
    presplit_proj<<<dim3(80), dim3(256), 0, stream>>>(proj, projR, projHg, projLg);

    gemm_qkv_s<<<dim3(24, (B_ * N_) / 128), dim3(256), 0, stream>>>(
        xh, xl, Wsp, bq, bk, bv, Q, Kb, Vb);

    kside<<<dim3(NSPLIT_, 64), dim3(256), 0, stream>>>(Kb, Vb, projR, S_u, Cpart, C_u, Vsum, mx);
    finalize_kernel<<<dim3(5, 64), dim3(256), 0, stream>>>(S_u, Cpart, C_u, Vsum, mx, ksf, ctxTh, ctxTl, Cs, kss);
    qattn<<<dim3(32, 64), dim3(512), 0, stream>>>(Q, projHg, projLg, ksf, ctxTh, ctxTl, Cs, kss, attnH, attnL);

    dim3 gg(D_ / 128, (B_ * N_) / 128);
    // Wo: split-bf16 A (attn) -> split-bf16 hbuf
    gemm_nt_s<<<gg, dim3(256), 0, stream>>>(attnH, attnL,
        Wsp + (size_t)3 * 2097152, Wsp + (size_t)3 * 2097152 + 1048576,
        bo, (float*)nullptr, hbH, hbL, 2);
    // Wfc: split-bf16 A (hbuf) -> fp32 out + relu
    gemm_nt_s<<<gg, dim3(256), 0, stream>>>(hbH, hbL,
        Wsp + (size_t)4 * 2097152, Wsp + (size_t)4 * 2097152 + 1048576,
        bfc, out, (unsigned short*)nullptr, (unsigned short*)nullptr, 1);
}

// Round 11
// 967.800 us; speedup vs baseline: 1.1367x; 1.0047x over previous
//
#include <hip/hip_runtime.h>
#include <math.h>

#define B_ 4
#define N_ 4096
#define D_ 1024
#define H_ 16
#define DH_ 64
#define M_ 266
#define MP_ 320   // M padded to 5 chunks of 64

#define DN_ 0.35355339059327373f      // 64^-0.25
#define RATIO_ 0.06131393394849658f   // 266^-0.5
#define EPS_ 1e-4f
#define KP_ 72    // ushort row stride
#define NSPLIT_ 16
#define PARTSZ_ ((size_t)64 * M_ * 64)   // one C_u partial (all bh)

typedef __attribute__((ext_vector_type(8))) short bfrag;
typedef __attribute__((ext_vector_type(4))) float f4;

__device__ __forceinline__ unsigned f2ord(float f) {
    unsigned u = __float_as_uint(f);
    return (u & 0x80000000u) ? ~u : (u | 0x80000000u);
}
__device__ __forceinline__ float ord2f(unsigned u) {
    unsigned b = (u & 0x80000000u) ? (u & 0x7fffffffu) : ~u;
    return __uint_as_float(b);
}

__global__ void zero_kernel(float* __restrict__ p, int n) {
    int i = blockIdx.x * 256 + threadIdx.x;
    if (i < n) p[i] = 0.f;
}

__device__ __forceinline__ void split2pack(float x, float y, unsigned* hp, unsigned* lp) {
    unsigned ux = __float_as_uint(x), uy = __float_as_uint(y);
    float hx = __uint_as_float(ux & 0xffff0000u);
    float hy = __uint_as_float(uy & 0xffff0000u);
    float lx = x - hx, ly = y - hy;
    *hp = (ux >> 16) | (uy & 0xffff0000u);
    *lp = (__float_as_uint(lx) >> 16) | (__float_as_uint(ly) & 0xffff0000u);
}
__device__ __forceinline__ unsigned short bf16rne(float x) {
    unsigned u = __float_as_uint(x);
    return (unsigned short)((u + 0x7fffu + ((u >> 16) & 1u)) >> 16);
}

// async global->LDS 16B (dwordx4). LDS dst must be wave-uniform; lane writes dst+lane*16.
__device__ __forceinline__ void async_cp16(const void* g, void* l) {
    __builtin_amdgcn_global_load_lds(
        (const __attribute__((address_space(1))) void*)g,
        (__attribute__((address_space(3))) void*)l, 16, 0, 0);
}

// ---------------- one-shot split conversions (each element converted exactly once) --------
__global__ __launch_bounds__(256) void split_f32(const float* __restrict__ X,
        unsigned short* __restrict__ Xh, unsigned short* __restrict__ Xl, int n4)
{
    int i = blockIdx.x * 256 + threadIdx.x;
    if (i >= n4) return;
    const float4 v = ((const float4*)X)[i];
    unsigned h0, l0, h1, l1;
    split2pack(v.x, v.y, &h0, &l0);
    split2pack(v.z, v.w, &h1, &l1);
    ((uint2*)Xh)[i] = make_uint2(h0, h1);
    ((uint2*)Xl)[i] = make_uint2(l0, l1);
}

// 5 weights (1024x1024 each) -> Wsp: per sel, h at sel*2097152, l at +1048576 (ushort units)
__global__ __launch_bounds__(256) void split_w5(const float* __restrict__ W0,
        const float* __restrict__ W1, const float* __restrict__ W2,
        const float* __restrict__ W3, const float* __restrict__ W4,
        unsigned short* __restrict__ Wsp)
{
    int sel = blockIdx.y;
    const float* W = (sel == 0) ? W0 : (sel == 1) ? W1 : (sel == 2) ? W2 : (sel == 3) ? W3 : W4;
    unsigned short* h = Wsp + (size_t)sel * 2097152;
    unsigned short* l = h + 1048576;
    int i = blockIdx.x * 256 + threadIdx.x;   // 1024*256 threads * 4 elems = 1048576
    const float4 v = ((const float4*)W)[i];
    unsigned h0, l0, h1, l1;
    split2pack(v.x, v.y, &h0, &l0);
    split2pack(v.z, v.w, &h1, &l1);
    ((uint2*)h)[i] = make_uint2(h0, h1);
    ((uint2*)l)[i] = make_uint2(l0, l1);
}

// proj (266x64) pre-converted ONCE, padded to MP_ rows with zeros.
__global__ __launch_bounds__(256) void presplit_proj(const float* __restrict__ proj,
        unsigned short* __restrict__ projR, unsigned short* __restrict__ projHg,
        unsigned short* __restrict__ projLg)
{
    int i = blockIdx.x * 256 + threadIdx.x;   // 80 blocks * 256 = 20480 = MP_*64
    int m = i >> 6, d = i & 63;
    float v = (m < M_) ? proj[m * 64 + d] : 0.f;
    projR[i] = bf16rne(v);
    unsigned u = __float_as_uint(v);
    float lo = v - __uint_as_float(u & 0xffff0000u);
    projHg[i] = (unsigned short)(u >> 16);
    projLg[i] = (unsigned short)(__float_as_uint(lo) >> 16);
}

// ---------------- fused QKV GEMM (128x128 stage-serial, proven 310us) ----------------------
__global__ __launch_bounds__(256) void gemm_qkv_s(
        const unsigned short* __restrict__ Ah, const unsigned short* __restrict__ Al,
        const unsigned short* __restrict__ Wsp,
        const float* __restrict__ b0, const float* __restrict__ b1, const float* __restrict__ b2,
        float* __restrict__ C0, float* __restrict__ C1, float* __restrict__ C2)
{
    __shared__ __align__(16) unsigned short Ahs[128 * 32];
    __shared__ __align__(16) unsigned short Als[128 * 32];
    __shared__ __align__(16) unsigned short Bhs[128 * 32];
    __shared__ __align__(16) unsigned short Bls[128 * 32];

    int tid = threadIdx.x;
    int sel = blockIdx.x >> 3;               // 0..2 -> q,k,v
    int bn = (blockIdx.x & 7) * 128;
    int bm = blockIdx.y * 128;
    const unsigned short* Bh = Wsp + (size_t)sel * 2097152;
    const unsigned short* Bl = Bh + 1048576;
    const float* bias = (sel == 0) ? b0 : (sel == 1) ? b1 : b2;
    float* C = (sel == 0) ? C0 : (sel == 1) ? C1 : C2;

    int lane = tid & 63;
    int w = tid >> 6;
    int wm = w >> 1, wn = w & 1;
    int ml = lane & 15, kq = lane >> 4;
    int rsub = lane >> 2;
    int ksw = (((lane & 3) ^ ((lane >> 3) & 3))) * 8;   // swizzled source K-slot (ushorts)
    int slot8 = ((kq ^ ((ml >> 1) & 3))) * 8;           // swizzled read K-slot (ushorts)

    f4 acc[4][4];
    #pragma unroll
    for (int i = 0; i < 4; ++i)
        #pragma unroll
        for (int j = 0; j < 4; ++j)
            acc[i][j] = (f4){0.f, 0.f, 0.f, 0.f};

    for (int kt = 0; kt < D_; kt += 32) {
        __syncthreads();
        #pragma unroll
        for (int j = 0; j < 2; ++j) {
            int row = w * 32 + j * 16;                        // wave-uniform
            size_t ga = (size_t)(bm + row + rsub) * D_ + kt + ksw;
            size_t gb = (size_t)(bn + row + rsub) * D_ + kt + ksw;
            async_cp16(Ah + ga, &Ahs[row * 32]);
            async_cp16(Al + ga, &Als[row * 32]);
            async_cp16(Bh + gb, &Bhs[row * 32]);
            async_cp16(Bl + gb, &Bls[row * 32]);
        }
        __syncthreads();
        bfrag ah[4], al[4], bh[4], bl[4];
        #pragma unroll
        for (int i = 0; i < 4; ++i) {
            int arow = wm * 64 + i * 16 + ml;
            ah[i] = *(const bfrag*)&Ahs[arow * 32 + slot8];
            al[i] = *(const bfrag*)&Als[arow * 32 + slot8];
            int brow = wn * 64 + i * 16 + ml;
            bh[i] = *(const bfrag*)&Bhs[brow * 32 + slot8];
            bl[i] = *(const bfrag*)&Bls[brow * 32 + slot8];
        }
        #pragma unroll
        for (int mi = 0; mi < 4; ++mi)
            #pragma unroll
            for (int ni = 0; ni < 4; ++ni) {
                acc[mi][ni] = __builtin_amdgcn_mfma_f32_16x16x32_bf16(ah[mi], bh[ni], acc[mi][ni], 0, 0, 0);
                acc[mi][ni] = __builtin_amdgcn_mfma_f32_16x16x32_bf16(al[mi], bh[ni], acc[mi][ni], 0, 0, 0);
                acc[mi][ni] = __builtin_amdgcn_mfma_f32_16x16x32_bf16(ah[mi], bl[ni], acc[mi][ni], 0, 0, 0);
            }
    }
    #pragma unroll
    for (int ni = 0; ni < 4; ++ni) {
        int col = bn + wn * 64 + ni * 16 + ml;
        float bv = bias[col];
        #pragma unroll
        for (int mi = 0; mi < 4; ++mi) {
            int row0 = bm + wm * 64 + mi * 16 + kq * 4;
            #pragma unroll
            for (int r = 0; r < 4; ++r)
                C[(size_t)(row0 + r) * D_ + col] = acc[mi][ni][r] + bv;
        }
    }
}

// ---------------- generic NT GEMM on pre-split operands (Wo / Wfc) ----------------
// mode 0: fp32+bias; mode 1: fp32+bias+relu; mode 2: split-bf16 write (+bias)
__global__ __launch_bounds__(256) void gemm_nt_s(
        const unsigned short* __restrict__ Ah, const unsigned short* __restrict__ Al,
        const unsigned short* __restrict__ Bh, const unsigned short* __restrict__ Bl,
        const float* __restrict__ bias, float* __restrict__ C,
        unsigned short* __restrict__ Ch, unsigned short* __restrict__ Cl, int mode)
{
    __shared__ __align__(16) unsigned short Ahs[128 * 32];
    __shared__ __align__(16) unsigned short Als[128 * 32];
    __shared__ __align__(16) unsigned short Bhs[128 * 32];
    __shared__ __align__(16) unsigned short Bls[128 * 32];

    int tid = threadIdx.x;
    int bn = blockIdx.x * 128;
    int bm = blockIdx.y * 128;
    int lane = tid & 63;
    int w = tid >> 6;
    int wm = w >> 1, wn = w & 1;
    int ml = lane & 15, kq = lane >> 4;
    int rsub = lane >> 2;
    int ksw = (((lane & 3) ^ ((lane >> 3) & 3))) * 8;
    int slot8 = ((kq ^ ((ml >> 1) & 3))) * 8;

    f4 acc[4][4];
    #pragma unroll
    for (int i = 0; i < 4; ++i)
        #pragma unroll
        for (int j = 0; j < 4; ++j)
            acc[i][j] = (f4){0.f, 0.f, 0.f, 0.f};

    for (int kt = 0; kt < D_; kt += 32) {
        __syncthreads();
        #pragma unroll
        for (int j = 0; j < 2; ++j) {
            int row = w * 32 + j * 16;
            size_t ga = (size_t)(bm + row + rsub) * D_ + kt + ksw;
            size_t gb = (size_t)(bn + row + rsub) * D_ + kt + ksw;
            async_cp16(Ah + ga, &Ahs[row * 32]);
            async_cp16(Al + ga, &Als[row * 32]);
            async_cp16(Bh + gb, &Bhs[row * 32]);
            async_cp16(Bl + gb, &Bls[row * 32]);
        }
        __syncthreads();
        bfrag ah[4], al[4], bh[4], bl[4];
        #pragma unroll
        for (int i = 0; i < 4; ++i) {
            int arow = wm * 64 + i * 16 + ml;
            ah[i] = *(const bfrag*)&Ahs[arow * 32 + slot8];
            al[i] = *(const bfrag*)&Als[arow * 32 + slot8];
            int brow = wn * 64 + i * 16 + ml;
            bh[i] = *(const bfrag*)&Bhs[brow * 32 + slot8];
            bl[i] = *(const bfrag*)&Bls[brow * 32 + slot8];
        }
        #pragma unroll
        for (int mi = 0; mi < 4; ++mi)
            #pragma unroll
            for (int ni = 0; ni < 4; ++ni) {
                acc[mi][ni] = __builtin_amdgcn_mfma_f32_16x16x32_bf16(ah[mi], bh[ni], acc[mi][ni], 0, 0, 0);
                acc[mi][ni] = __builtin_amdgcn_mfma_f32_16x16x32_bf16(al[mi], bh[ni], acc[mi][ni], 0, 0, 0);
                acc[mi][ni] = __builtin_amdgcn_mfma_f32_16x16x32_bf16(ah[mi], bl[ni], acc[mi][ni], 0, 0, 0);
            }
    }
    #pragma unroll
    for (int ni = 0; ni < 4; ++ni) {
        int col = bn + wn * 64 + ni * 16 + ml;
        float bv = bias[col];
        #pragma unroll
        for (int mi = 0; mi < 4; ++mi) {
            int row0 = bm + wm * 64 + mi * 16 + kq * 4;
            #pragma unroll
            for (int r = 0; r < 4; ++r) {
                float o = acc[mi][ni][r] + bv;
                size_t idx = (size_t)(row0 + r) * D_ + col;
                if (mode == 2) {
                    unsigned u = __float_as_uint(o);
                    float lo = o - __uint_as_float(u & 0xffff0000u);
                    Ch[idx] = (unsigned short)(u >> 16);
                    Cl[idx] = (unsigned short)(__float_as_uint(lo) >> 16);
                } else {
                    if (mode == 1) o = fmaxf(o, 0.f);
                    C[idx] = o;
                }
            }
        }
    }
}

// ---------------- MFMA key side, atomic-free C_u, single-bf16 phase1 ----------------
// grid (NSPLIT_=16, 64): x = n-split (256 rows), y = bh. 4 waves.
__global__ __launch_bounds__(256) void kside(
    const float* __restrict__ Kin, const float* __restrict__ Vin,
    const unsigned short* __restrict__ projR,
    float* __restrict__ S_u, float* __restrict__ Cpart, float* __restrict__ C_u,
    float* __restrict__ Vsum, unsigned int* __restrict__ mxp)
{
    __shared__ __align__(16) unsigned short Kh[64 * KP_];      // [n][d] bf16 RNE (pre-scaled by dn)
    __shared__ __align__(16) unsigned short VT[64 * KP_];      // [dh][n] bf16 RNE
    __shared__ __align__(16) unsigned short Ph[2][64 * KP_];   // proj [m][d] bf16 RNE, ping-pong
    __shared__ __align__(16) unsigned short Us[64 * KP_];      // [m][n] bf16 RNE
    __shared__ __align__(16) float Ssum[MP_];
    __shared__ float diag[64];
    float* redf = (float*)Us;   // overlay (lifetimes separated by barriers)

    int bh = blockIdx.y, b = bh >> 4, h = bh & 15;
    int s = blockIdx.x;
    int n0 = s * 256;
    int tid = threadIdx.x, lane = tid & 63, w = tid >> 6;
    int ml = lane & 15, quad = lane >> 4;

    float* dstC = (s < NSPLIT_ - 1) ? (Cpart + (size_t)s * PARTSZ_) : C_u;

    for (int i = tid; i < MP_; i += 256) Ssum[i] = 0.f;

    f4 acc[5][4];
    #pragma unroll
    for (int i = 0; i < 5; ++i)
        #pragma unroll
        for (int j = 0; j < 4; ++j) acc[i][j] = (f4){0.f, 0.f, 0.f, 0.f};
    float vs[4] = {0.f, 0.f, 0.f, 0.f};
    float lmax = -1e30f;

    for (int nc = 0; nc < 4; ++nc) {
        __syncthreads();
        // stage K (RNE, *dn), V^T (RNE), diag partials, and proj chunk 0 (copy)
        #pragma unroll
        for (int l = 0; l < 4; ++l) {
            int idx = tid + 256 * l;
            int r = idx >> 4;
            int d4 = (idx & 15) * 4;
            size_t g = ((size_t)(b * N_ + n0 + nc * 64 + r)) * D_ + h * DH_ + d4;
            const float4 kv = *(const float4*)(Kin + g);
            redf[r * 17 + (tid & 15)] = kv.x * kv.x + kv.y * kv.y + kv.z * kv.z + kv.w * kv.w;
            unsigned w0 = (unsigned)bf16rne(kv.x * DN_) | ((unsigned)bf16rne(kv.y * DN_) << 16);
            unsigned w1 = (unsigned)bf16rne(kv.z * DN_) | ((unsigned)bf16rne(kv.w * DN_) << 16);
            *(uint2*)&Kh[r * KP_ + d4] = make_uint2(w0, w1);
            const float4 vv = *(const float4*)(Vin + g);
            vs[0] += vv.x; vs[1] += vv.y; vs[2] += vv.z; vs[3] += vv.w;
            VT[(d4 + 0) * KP_ + r] = bf16rne(vv.x);
            VT[(d4 + 1) * KP_ + r] = bf16rne(vv.y);
            VT[(d4 + 2) * KP_ + r] = bf16rne(vv.z);
            VT[(d4 + 3) * KP_ + r] = bf16rne(vv.w);
        }
        {   // proj chunk 0 -> Ph[0] (pure copy)
            #pragma unroll
            for (int l = 0; l < 2; ++l) {
                int idx = tid + 256 * l;
                int m = idx >> 3, d8 = (idx & 7) * 8;
                *(uint4*)&Ph[0][m * KP_ + d8] = *(const uint4*)(projR + m * 64 + d8);
            }
        }
        __syncthreads();
        if (tid < 64) {
            float ss = 0.f;
            #pragma unroll
            for (int p = 0; p < 16; ++p) ss += redf[tid * 17 + p];
            diag[tid] = ss * 0.0625f;
        }
        __syncthreads();

        bfrag kh0 = *(const bfrag*)&Kh[(w * 16 + ml) * KP_ + quad * 8];
        bfrag kh1 = *(const bfrag*)&Kh[(w * 16 + ml) * KP_ + 32 + quad * 8];
        float dgv[4];
        #pragma unroll
        for (int r = 0; r < 4; ++r) dgv[r] = diag[w * 16 + quad * 4 + r];

        for (int mc = 0; mc < 5; ++mc) {
            int pb = mc & 1;
            // prefetch next proj chunk (copy; overlaps phase-1 MFMA)
            uint4 pf2[2];
            if (mc < 4) {
                #pragma unroll
                for (int l = 0; l < 2; ++l) {
                    int idx = tid + 256 * l;
                    int m = idx >> 3, d8 = (idx & 7) * 8;
                    int mg = (mc + 1) * 64 + m;      // < MP_, zero-padded
                    pf2[l] = *(const uint4*)(projR + mg * 64 + d8);
                }
            }
            // phase 1: td[n][m] tiles, single-bf16
            #pragma unroll
            for (int mt = 0; mt < 4; ++mt) {
                int mrow = mt * 16 + ml;
                bfrag ph0 = *(const bfrag*)&Ph[pb][mrow * KP_ + quad * 8];
                bfrag ph1 = *(const bfrag*)&Ph[pb][mrow * KP_ + 32 + quad * 8];
                f4 t = (f4){0.f, 0.f, 0.f, 0.f};
                t = __builtin_amdgcn_mfma_f32_16x16x32_bf16(kh0, ph0, t, 0, 0, 0);
                t = __builtin_amdgcn_mfma_f32_16x16x32_bf16(kh1, ph1, t, 0, 0, 0);
                bool mv = (mc * 64 + mrow) < M_;
                float su = 0.f;
                unsigned short up[4];
                #pragma unroll
                for (int r = 0; r < 4; ++r) {
                    float u = 0.f;
                    if (mv) {
                        float tt = t[r];
                        lmax = fmaxf(lmax, tt);
                        u = __expf(tt - dgv[r]);
                    }
                    su += u;
                    up[r] = bf16rne(u);
                }
                su += __shfl_xor(su, 16);
                su += __shfl_xor(su, 32);
                if (mv && quad == 0) atomicAdd(&Ssum[mc * 64 + mrow], su);
                unsigned w0 = (unsigned)up[0] | ((unsigned)up[1] << 16);
                unsigned w1 = (unsigned)up[2] | ((unsigned)up[3] << 16);
                *(uint2*)&Us[mrow * KP_ + w * 16 + quad * 4] = make_uint2(w0, w1);
            }
            // store prefetched proj
            if (mc < 4) {
                #pragma unroll
                for (int l = 0; l < 2; ++l) {
                    int idx = tid + 256 * l;
                    int m = idx >> 3, d8 = (idx & 7) * 8;
                    *(uint4*)&Ph[1 - pb][m * KP_ + d8] = pf2[l];
                }
            }
            __syncthreads();
            // phase 2: acc[mc] += Us^T-tile @ V
            bfrag ua0 = *(const bfrag*)&Us[(w * 16 + ml) * KP_ + quad * 8];
            bfrag ua1 = *(const bfrag*)&Us[(w * 16 + ml) * KP_ + 32 + quad * 8];
            #pragma unroll
            for (int dt = 0; dt < 4; ++dt) {
                bfrag vb0 = *(const bfrag*)&VT[(dt * 16 + ml) * KP_ + quad * 8];
                bfrag vb1 = *(const bfrag*)&VT[(dt * 16 + ml) * KP_ + 32 + quad * 8];
                acc[mc][dt] = __builtin_amdgcn_mfma_f32_16x16x32_bf16(ua0, vb0, acc[mc][dt], 0, 0, 0);
                acc[mc][dt] = __builtin_amdgcn_mfma_f32_16x16x32_bf16(ua1, vb1, acc[mc][dt], 0, 0, 0);
            }
            __syncthreads();
        }
    }
    // epilogue: C_u partial, PLAIN stores (no atomics)
    #pragma unroll
    for (int mc = 0; mc < 5; ++mc)
        #pragma unroll
        for (int dt = 0; dt < 4; ++dt)
            #pragma unroll
            for (int r = 0; r < 4; ++r) {
                int m = mc * 64 + w * 16 + quad * 4 + r;
                if (m < M_)
                    dstC[((size_t)bh * M_ + m) * 64 + dt * 16 + ml] = acc[mc][dt][r];
            }
    __syncthreads();
    for (int m = tid; m < M_; m += 256)
        atomicAdd(S_u + bh * M_ + m, Ssum[m]);
    #pragma unroll
    for (int off = 32; off; off >>= 1) lmax = fmaxf(lmax, __shfl_xor(lmax, off));
    __syncthreads();
    if (lane == 0) redf[w] = lmax;
    __syncthreads();
    if (tid == 0) {
        float mxv = fmaxf(fmaxf(redf[0], redf[1]), fmaxf(redf[2], redf[3]));
        atomicMax(mxp + bh, f2ord(mxv));
    }
    for (int j = 0; j < 4; ++j) {
        __syncthreads();
        redf[tid] = vs[j];
        __syncthreads();
        if (tid < 16) {
            float ss = 0.f;
            #pragma unroll
            for (int p = 0; p < 16; ++p) ss += redf[tid + 16 * p];
            atomicAdd(Vsum + bh * 64 + tid * 4 + j, ss);
        }
    }
}

// ---------------- finalize: sum 16 partials, build ks + ctxT(split) + Cs + kss ----------------
// grid (5, 64): x = m-chunk, y = bh
__global__ __launch_bounds__(256) void finalize_kernel(
    const float* __restrict__ S_u, const float* __restrict__ Cpart, const float* __restrict__ C_u,
    const float* __restrict__ Vsum, const unsigned* __restrict__ mxp,
    float* __restrict__ ksum_f, unsigned short* __restrict__ ctxTh,
    unsigned short* __restrict__ ctxTl, float* __restrict__ Cs, float* __restrict__ kss)
{
    __shared__ float T[64 * 65];
    __shared__ float red[256];
    int mc = blockIdx.x, bh = blockIdx.y;
    int tid = threadIdx.x;
    float emx = __expf(-ord2f(mxp[bh]));

    float csacc = 0.f;   // dh = tid&63 fixed across iterations
    #pragma unroll
    for (int i = 0; i < 16; ++i) {
        int idx = i * 256 + tid;
        int dh = idx & 63, mloc = idx >> 6;
        int m = mc * 64 + mloc;
        float v = 0.f;
        if (m < M_) {
            size_t off = ((size_t)bh * M_ + m) * 64 + dh;
            float sacc = C_u[off];
            for (int sp = 0; sp < NSPLIT_ - 1; ++sp)
                sacc += Cpart[(size_t)sp * PARTSZ_ + off];
            v = RATIO_ * (emx * sacc + EPS_ * Vsum[bh * 64 + dh]);
        }
        T[mloc * 65 + dh] = v;
        csacc += v;
    }
    red[tid] = csacc;
    __syncthreads();
    if (tid < 64) atomicAdd(&Cs[bh * 64 + tid], red[tid] + red[tid + 64] + red[tid + 128] + red[tid + 192]);
    // ks + kss
    float ksl = 0.f;
    if (tid < 64) {
        int m = mc * 64 + tid;
        float kv = (m < M_) ? RATIO_ * (emx * S_u[bh * M_ + m] + EPS_ * (float)N_) : 0.f;
        ksum_f[bh * MP_ + m] = kv;
        ksl = kv;
    }
    __syncthreads();
    red[tid] = ksl;
    __syncthreads();
    if (tid == 0) {
        float ss = 0.f;
        for (int p = 0; p < 64; ++p) ss += red[p];
        atomicAdd(kss + bh, ss);
    }
    __syncthreads();
    // transposed split writes: ctxT[dh][m]
    #pragma unroll
    for (int i = 0; i < 8; ++i) {
        int idx = i * 256 + tid;
        int dh = idx >> 5, m2 = (idx & 31) * 2;
        float v0 = T[m2 * 65 + dh], v1 = T[(m2 + 1) * 65 + dh];
        unsigned u0 = __float_as_uint(v0), u1 = __float_as_uint(v1);
        float lo0 = v0 - __uint_as_float(u0 & 0xffff0000u);
        float lo1 = v1 - __uint_as_float(u1 & 0xffff0000u);
        size_t dst = ((size_t)(bh * 64 + dh)) * MP_ + mc * 64 + m2;
        *(unsigned*)&ctxTh[dst] = (u0 >> 16) | (u1 & 0xffff0000u);
        *(unsigned*)&ctxTl[dst] = (__float_as_uint(lo0) >> 16) | (__float_as_uint(lo1) & 0xffff0000u);
    }
}

// ---------------- MFMA query side: T14 async-stage split, 2 barriers/chunk ----------------
__global__ __launch_bounds__(256) void qattn(
    const float* __restrict__ Q, const unsigned short* __restrict__ projHg,
    const unsigned short* __restrict__ projLg,
    const float* __restrict__ ksum_f, const unsigned short* __restrict__ ctxTh,
    const unsigned short* __restrict__ ctxTl,
    const float* __restrict__ Cs, const float* __restrict__ kss,
    unsigned short* __restrict__ attnH, unsigned short* __restrict__ attnL)
{
    __shared__ __align__(16) unsigned short Qh[64 * KP_], Ql[64 * KP_];
    __shared__ __align__(16) unsigned short Ph[64 * KP_], Pl[64 * KP_];     // proj chunk
    __shared__ __align__(16) unsigned short Chs[64 * KP_], Cls[64 * KP_];   // ctx chunk
    __shared__ __align__(16) unsigned short Uh[64 * KP_], Ul[64 * KP_];
    __shared__ __align__(16) float ks[MP_];
    __shared__ float diag[64];
    float* redf = (float*)Uh;

    int bh = blockIdx.y, b = bh >> 4, h = bh & 15;
    int n0 = blockIdx.x * 64;
    int tid = threadIdx.x, lane = tid & 63, w = tid >> 6;
    int ml = lane & 15, quad = lane >> 4;

    // initial stage: Q split + sq-sums + ks + proj chunk 0 copy
    #pragma unroll
    for (int l = 0; l < 4; ++l) {
        int idx = tid + 256 * l;
        int r = idx >> 4, d4 = (idx & 15) * 4;
        size_t g = ((size_t)(b * N_ + n0 + r)) * D_ + h * DH_ + d4;
        const float4 qv = *(const float4*)(Q + g);
        redf[r * 17 + (tid & 15)] = qv.x * qv.x + qv.y * qv.y + qv.z * qv.z + qv.w * qv.w;
        unsigned h0, l0, h1, l1;
        split2pack(qv.x * DN_, qv.y * DN_, &h0, &l0);
        split2pack(qv.z * DN_, qv.w * DN_, &h1, &l1);
        *(uint2*)&Qh[r * KP_ + d4] = make_uint2(h0, h1);
        *(uint2*)&Ql[r * KP_ + d4] = make_uint2(l0, l1);
    }
    #pragma unroll
    for (int l = 0; l < 2; ++l) {
        int idx = tid + 256 * l;
        int m = idx >> 3, d8 = (idx & 7) * 8;
        *(uint4*)&Ph[m * KP_ + d8] = *(const uint4*)(projHg + m * 64 + d8);
        *(uint4*)&Pl[m * KP_ + d8] = *(const uint4*)(projLg + m * 64 + d8);
    }
    for (int m = tid; m < MP_; m += 256) ks[m] = ksum_f[bh * MP_ + m];
    __syncthreads();
    if (tid < 64) {
        float s = 0.f;
        #pragma unroll
        for (int p = 0; p < 16; ++p) s += redf[tid * 17 + p];
        diag[tid] = s * 0.0625f;
    }
    __syncthreads();

    bfrag qh0 = *(const bfrag*)&Qh[(w * 16 + ml) * KP_ + quad * 8];
    bfrag ql0 = *(const bfrag*)&Ql[(w * 16 + ml) * KP_ + quad * 8];
    bfrag qh1 = *(const bfrag*)&Qh[(w * 16 + ml) * KP_ + 32 + quad * 8];
    bfrag ql1 = *(const bfrag*)&Ql[(w * 16 + ml) * KP_ + 32 + quad * 8];
    float dg = diag[w * 16 + ml];
    float dacc = 0.f, tmax = -1e30f;
    f4 oacc[4];
    #pragma unroll
    for (int i = 0; i < 4; ++i) oacc[i] = (f4){0.f, 0.f, 0.f, 0.f};

    int cidx0 = tid, cidx1 = tid + 256;
    int cdh0 = cidx0 >> 3, cm80 = (cidx0 & 7) * 8;
    int cdh1 = cidx1 >> 3, cm81 = (cidx1 & 7) * 8;

    for (int mc = 0; mc < 5; ++mc) {
        // 1. issue ctx[mc] global loads -> regs (latency hides under phase-1)
        size_t csrc0 = ((size_t)(bh * 64 + cdh0)) * MP_ + mc * 64 + cm80;
        size_t csrc1 = ((size_t)(bh * 64 + cdh1)) * MP_ + mc * 64 + cm81;
        uint4 c0 = *(const uint4*)(ctxTh + csrc0);
        uint4 c1 = *(const uint4*)(ctxTl + csrc0);
        uint4 c2 = *(const uint4*)(ctxTh + csrc1);
        uint4 c3 = *(const uint4*)(ctxTl + csrc1);

        // 2. phase 1: td tiles (reads Ph/Pl + Q frags), writes U rows (wave-private)
        #pragma unroll
        for (int mt = 0; mt < 4; ++mt) {
            int mrow = mt * 16 + ml;
            bfrag ph0 = *(const bfrag*)&Ph[mrow * KP_ + quad * 8];
            bfrag pl0 = *(const bfrag*)&Pl[mrow * KP_ + quad * 8];
            bfrag ph1 = *(const bfrag*)&Ph[mrow * KP_ + 32 + quad * 8];
            bfrag pl1 = *(const bfrag*)&Pl[mrow * KP_ + 32 + quad * 8];
            f4 t = (f4){0.f, 0.f, 0.f, 0.f};
            t = __builtin_amdgcn_mfma_f32_16x16x32_bf16(ph0, qh0, t, 0, 0, 0);
            t = __builtin_amdgcn_mfma_f32_16x16x32_bf16(pl0, qh0, t, 0, 0, 0);
            t = __builtin_amdgcn_mfma_f32_16x16x32_bf16(ph0, ql0, t, 0, 0, 0);
            t = __builtin_amdgcn_mfma_f32_16x16x32_bf16(ph1, qh1, t, 0, 0, 0);
            t = __builtin_amdgcn_mfma_f32_16x16x32_bf16(pl1, qh1, t, 0, 0, 0);
            t = __builtin_amdgcn_mfma_f32_16x16x32_bf16(ph1, ql1, t, 0, 0, 0);
            const float4 ksv = *(const float4*)&ks[mc * 64 + mt * 16 + quad * 4];
            float ksa[4] = {ksv.x, ksv.y, ksv.z, ksv.w};
            unsigned short uh4[4], ul4[4];
            #pragma unroll
            for (int r = 0; r < 4; ++r) {
                int mg = mc * 64 + mt * 16 + quad * 4 + r;
                float tt = t[r];
                float u = __expf(tt - dg);
                if (mg < M_) tmax = fmaxf(tmax, tt);
                dacc = fmaf(u, ksa[r], dacc);
                unsigned uu = __float_as_uint(u);
                float lo = u - __uint_as_float(uu & 0xffff0000u);
                uh4[r] = (unsigned short)(uu >> 16);
                ul4[r] = (unsigned short)(__float_as_uint(lo) >> 16);
            }
            unsigned a0 = (unsigned)uh4[0] | ((unsigned)uh4[1] << 16);
            unsigned a1 = (unsigned)uh4[2] | ((unsigned)uh4[3] << 16);
            unsigned b0 = (unsigned)ul4[0] | ((unsigned)ul4[1] << 16);
            unsigned b1 = (unsigned)ul4[2] | ((unsigned)ul4[3] << 16);
            *(uint2*)&Uh[(w * 16 + ml) * KP_ + mt * 16 + quad * 4] = make_uint2(a0, a1);
            *(uint2*)&Ul[(w * 16 + ml) * KP_ + mt * 16 + quad * 4] = make_uint2(b0, b1);
        }
        // 3. ctx regs -> dedicated LDS
        *(uint4*)&Chs[cdh0 * KP_ + cm80] = c0;
        *(uint4*)&Cls[cdh0 * KP_ + cm80] = c1;
        *(uint4*)&Chs[cdh1 * KP_ + cm81] = c2;
        *(uint4*)&Cls[cdh1 * KP_ + cm81] = c3;
        __syncthreads();

        // 4. issue proj[mc+1] global loads -> regs (latency hides under phase-2)
        uint4 p0, p1, p2, p3;
        if (mc < 4) {
            int mg0 = (mc + 1) * 64 + (cidx0 >> 3);
            int mg1 = (mc + 1) * 64 + (cidx1 >> 3);
            p0 = *(const uint4*)(projHg + mg0 * 64 + cm80);
            p1 = *(const uint4*)(projLg + mg0 * 64 + cm80);
            p2 = *(const uint4*)(projHg + mg1 * 64 + cm81);
            p3 = *(const uint4*)(projLg + mg1 * 64 + cm81);
        }
        // 5. phase 2: oacc += U-tile @ ctx-tile
        bfrag ua0h = *(const bfrag*)&Uh[(w * 16 + ml) * KP_ + quad * 8];
        bfrag ua0l = *(const bfrag*)&Ul[(w * 16 + ml) * KP_ + quad * 8];
        bfrag ua1h = *(const bfrag*)&Uh[(w * 16 + ml) * KP_ + 32 + quad * 8];
        bfrag ua1l = *(const bfrag*)&Ul[(w * 16 + ml) * KP_ + 32 + quad * 8];
        #pragma unroll
        for (int dt = 0; dt < 4; ++dt) {
            bfrag cb0h = *(const bfrag*)&Chs[(dt * 16 + ml) * KP_ + quad * 8];
            bfrag cb0l = *(const bfrag*)&Cls[(dt * 16 + ml) * KP_ + quad * 8];
            bfrag cb1h = *(const bfrag*)&Chs[(dt * 16 + ml) * KP_ + 32 + quad * 8];
            bfrag cb1l = *(const bfrag*)&Cls[(dt * 16 + ml) * KP_ + 32 + quad * 8];
            oacc[dt] = __builtin_amdgcn_mfma_f32_16x16x32_bf16(ua0h, cb0h, oacc[dt], 0, 0, 0);
            oacc[dt] = __builtin_amdgcn_mfma_f32_16x16x32_bf16(ua0l, cb0h, oacc[dt], 0, 0, 0);
            oacc[dt] = __builtin_amdgcn_mfma_f32_16x16x32_bf16(ua0h, cb0l, oacc[dt], 0, 0, 0);
            oacc[dt] = __builtin_amdgcn_mfma_f32_16x16x32_bf16(ua1h, cb1h, oacc[dt], 0, 0, 0);
            oacc[dt] = __builtin_amdgcn_mfma_f32_16x16x32_bf16(ua1l, cb1h, oacc[dt], 0, 0, 0);
            oacc[dt] = __builtin_amdgcn_mfma_f32_16x16x32_bf16(ua1h, cb1l, oacc[dt], 0, 0, 0);
        }
        // 6. proj regs -> LDS (safe: barrier above means all waves finished phase-1 reads)
        if (mc < 4) {
            *(uint4*)&Ph[(cidx0 >> 3) * KP_ + cm80] = p0;
            *(uint4*)&Pl[(cidx0 >> 3) * KP_ + cm80] = p1;
            *(uint4*)&Ph[(cidx1 >> 3) * KP_ + cm81] = p2;
            *(uint4*)&Pl[(cidx1 >> 3) * KP_ + cm81] = p3;
        }
        __syncthreads();
    }
    dacc += __shfl_xor(dacc, 16); dacc += __shfl_xor(dacc, 32);
    tmax = fmaxf(tmax, __shfl_xor(tmax, 16));
    tmax = fmaxf(tmax, __shfl_xor(tmax, 32));
    float fac = EPS_ * __expf(tmax);
    float dinv = 1.f / (dacc + fac * kss[bh]);
    #pragma unroll
    for (int dt = 0; dt < 4; ++dt) {
        float csv = Cs[bh * 64 + dt * 16 + ml];
        #pragma unroll
        for (int r = 0; r < 4; ++r) {
            int srcl = quad * 4 + r;
            float dv = __shfl(dinv, srcl);
            float fv = __shfl(fac, srcl);
            float o = (oacc[dt][r] + fv * csv) * dv;
            int n = n0 + w * 16 + quad * 4 + r;
            size_t gi = ((size_t)(b * N_ + n)) * D_ + h * DH_ + dt * 16 + ml;
            unsigned u = __float_as_uint(o);
            float lo = o - __uint_as_float(u & 0xffff0000u);
            attnH[gi] = (unsigned short)(u >> 16);
            attnL[gi] = (unsigned short)(__float_as_uint(lo) >> 16);
        }
    }
}

// ---------------- launch ----------------
extern "C" void kernel_launch(void* const* d_in, const int* in_sizes, int n_in,
                              void* d_out, int out_size, void* d_ws, size_t ws_size,
                              hipStream_t stream)
{
    const float* x    = (const float*)d_in[0];
    const float* Wq   = (const float*)d_in[1];
    const float* bq   = (const float*)d_in[2];
    const float* Wk   = (const float*)d_in[3];
    const float* bk   = (const float*)d_in[4];
    const float* Wv   = (const float*)d_in[5];
    const float* bv   = (const float*)d_in[6];
    const float* Wo   = (const float*)d_in[7];
    const float* bo   = (const float*)d_in[8];
    const float* Wfc  = (const float*)d_in[9];
    const float* bfc  = (const float*)d_in[10];
    const float* proj = (const float*)d_in[11];
    float* out = (float*)d_out;

    float* ws = (float*)d_ws;
    const size_t nTok = (size_t)B_ * N_ * D_;
    const size_t nSu  = 64 * M_;
    const size_t nCu  = (size_t)64 * M_ * 64;
    const size_t nVs  = 64 * 64;
    const size_t nMx  = 64;
    const size_t nKsf = 64 * MP_;
    const size_t nCtx = (size_t)64 * MP_ * 64;
    const size_t nCs  = 64 * 64;

    const size_t offQ   = 0;
    const size_t offK   = nTok;
    const size_t offV   = nTok * 2;
    const size_t offSu  = nTok * 3;
    const size_t offCu  = offSu + nSu;
    const size_t offVs  = offCu + nCu;
    const size_t offMx  = offVs + nVs;
    const size_t offKsf = offMx + nMx;
    const size_t offCtx = offKsf + nKsf;
    const size_t offCs  = offCtx + nCtx;
    const size_t offKss = offCs + nCs;
    const size_t offWsp = offKss + 64;              // 5 weights split: 5 * 1048576 float-slots
    const size_t offPrj = offWsp + 5242880;         // proj pre-split: 3 * 20480 ushorts

    float* Q    = ws + offQ;
    float* Kb   = ws + offK;
    float* Vb   = ws + offV;
    float* S_u  = ws + offSu;
    float* C_u  = ws + offCu;
    float* Vsum = ws + offVs;
    unsigned* mx = (unsigned*)(ws + offMx);
    float* ksf  = ws + offKsf;
    unsigned short* ctxTh = (unsigned short*)(ws + offCtx);
    unsigned short* ctxTl = ctxTh + (size_t)64 * 64 * MP_;
    float* Cs   = ws + offCs;
    float* kss  = ws + offKss;
    unsigned short* Wsp = (unsigned short*)(ws + offWsp);
    unsigned short* projR  = (unsigned short*)(ws + offPrj);
    unsigned short* projHg = projR + (size_t)MP_ * 64;
    unsigned short* projLg = projHg + (size_t)MP_ * 64;

    // scratch overlays (stream-ordered lifetimes):
    unsigned short* xh = (unsigned short*)out;        // x split lives in d_out, dead before kside
    unsigned short* xl = xh + nTok;
    unsigned short* attnH = (unsigned short*)Kb;      // K dead after kside
    unsigned short* attnL = attnH + nTok;
    unsigned short* hbH = (unsigned short*)Vb;        // V dead after kside
    unsigned short* hbL = hbH + nTok;
    float* Cpart = out;                               // d_out as scratch for 15 C_u partials

    // zero S_u..kss (covers S_u, C_u, Vsum, mx, ksf, ctxT, Cs, kss)
    int nzero = (int)(nSu + nCu + nVs + nMx + nKsf + nCtx + nCs + 64);
    zero_kernel<<<dim3((nzero + 255) / 256), dim3(256), 0, stream>>>(S_u, nzero);

    // one-shot conversions
    split_f32<<<dim3(16384), dim3(256), 0, stream>>>(x, xh, xl, (int)(nTok / 4));
    split_w5<<<dim3(1024, 5), dim3(256), 0, stream>>>(Wq, Wk, Wv, Wo, Wfc, Wsp);
    presplit_proj<<<dim3(80), dim3(256), 0, stream>>>(proj, projR, projHg, projLg);

    gemm_qkv_s<<<dim3(24, (B_ * N_) / 128), dim3(256), 0, stream>>>(
        xh, xl, Wsp, bq, bk, bv, Q, Kb, Vb);

    kside<<<dim3(NSPLIT_, 64), dim3(256), 0, stream>>>(Kb, Vb, projR, S_u, Cpart, C_u, Vsum, mx);
    finalize_kernel<<<dim3(5, 64), dim3(256), 0, stream>>>(S_u, Cpart, C_u, Vsum, mx, ksf, ctxTh, ctxTl, Cs, kss);
    qattn<<<dim3(64, 64), dim3(256), 0, stream>>>(Q, projHg, projLg, ksf, ctxTh, ctxTl, Cs, kss, attnH, attnL);

    dim3 gg(D_ / 128, (B_ * N_) / 128);
    // Wo: split-bf16 A (attn) -> split-bf16 hbuf
    gemm_nt_s<<<gg, dim3(256), 0, stream>>>(attnH, attnL,
        Wsp + (size_t)3 * 2097152, Wsp + (size_t)3 * 2097152 + 1048576,
        bo, (float*)nullptr, hbH, hbL, 2);
    // Wfc: split-bf16 A (hbuf) -> fp32 out + relu
    gemm_nt_s<<<gg, dim3(256), 0, stream>>>(hbH, hbL,
        Wsp + (size_t)4 * 2097152, Wsp + (size_t)4 * 2097152 + 1048576,
        bfc, out, (unsigned short*)nullptr, (unsigned short*)nullptr, 1);
}